// Round 1
// baseline (771.337 us; speedup 1.0000x reference)
//
#include <hip/hip_runtime.h>
#include <cstdint>
#include <cstddef>

#define NSLOPE 0.2f

// ---------------------------------------------------------------- utilities
__global__ void zero_int_kernel(int* __restrict__ p, int n) {
    int i = blockIdx.x * blockDim.x + threadIdx.x;
    if (i < n) p[i] = 0;
}

// s_vec[c] = sum_k sent[k] * W1[768+k][c]   (sentence half of GEMM1)
__global__ void svec_kernel(const float* __restrict__ sent,
                            const float* __restrict__ W1,
                            float* __restrict__ svec) {
    int c = blockIdx.x * blockDim.x + threadIdx.x;
    if (c >= 512) return;
    float acc = 0.f;
    for (int k = 0; k < 768; ++k)
        acc += sent[k] * W1[(size_t)(768 + k) * 512 + c];
    svec[c] = acc;
}

// ---------------------------------------------------------------- fp32 GEMM
// C[M,N] = A[M,K] * B[K,N] (+ bias[N] broadcast per row, optional)
// 64x64 tile, BK=16, 256 threads, 4x4 micro-tile.
__global__ __launch_bounds__(256) void gemm_kernel(
    const float* __restrict__ A, const float* __restrict__ B,
    const float* __restrict__ bias, float* __restrict__ C,
    int M, int N, int K)
{
    const int BM = 64, BN = 64, BK = 16;
    __shared__ float As[BK][BM + 1];
    __shared__ float Bs[BK][BN + 1];
    int tid = threadIdx.x;
    int tx = tid & 15;   // column group (x4)
    int ty = tid >> 4;   // row group (x4)
    int row0 = blockIdx.y * BM;
    int col0 = blockIdx.x * BN;
    float acc[4][4] = {};
    int ar = tid >> 2, ak = (tid & 3) << 2;   // A loader: 64 rows x 16 k
    int br = tid >> 4, bc = (tid & 15) << 2;  // B loader: 16 k x 64 cols

    for (int k0 = 0; k0 < K; k0 += BK) {
        float4 av = make_float4(0.f, 0.f, 0.f, 0.f);
        int r = row0 + ar;
        if (r < M) av = *(const float4*)(A + (size_t)r * K + k0 + ak);
        float4 bv = *(const float4*)(B + (size_t)(k0 + br) * N + col0 + bc);
        As[ak + 0][ar] = av.x; As[ak + 1][ar] = av.y;
        As[ak + 2][ar] = av.z; As[ak + 3][ar] = av.w;
        Bs[br][bc + 0] = bv.x; Bs[br][bc + 1] = bv.y;
        Bs[br][bc + 2] = bv.z; Bs[br][bc + 3] = bv.w;
        __syncthreads();
#pragma unroll
        for (int kk = 0; kk < BK; ++kk) {
            float a0 = As[kk][ty * 4 + 0], a1 = As[kk][ty * 4 + 1];
            float a2 = As[kk][ty * 4 + 2], a3 = As[kk][ty * 4 + 3];
            float b0 = Bs[kk][tx * 4 + 0], b1 = Bs[kk][tx * 4 + 1];
            float b2 = Bs[kk][tx * 4 + 2], b3 = Bs[kk][tx * 4 + 3];
            acc[0][0] += a0 * b0; acc[0][1] += a0 * b1; acc[0][2] += a0 * b2; acc[0][3] += a0 * b3;
            acc[1][0] += a1 * b0; acc[1][1] += a1 * b1; acc[1][2] += a1 * b2; acc[1][3] += a1 * b3;
            acc[2][0] += a2 * b0; acc[2][1] += a2 * b1; acc[2][2] += a2 * b2; acc[2][3] += a2 * b3;
            acc[3][0] += a3 * b0; acc[3][1] += a3 * b1; acc[3][2] += a3 * b2; acc[3][3] += a3 * b3;
        }
        __syncthreads();
    }
    float4 bb = make_float4(0.f, 0.f, 0.f, 0.f);
    if (bias) bb = *(const float4*)(bias + col0 + tx * 4);
#pragma unroll
    for (int i = 0; i < 4; ++i) {
        int r = row0 + ty * 4 + i;
        if (r < M) {
            float4 v = make_float4(acc[i][0] + bb.x, acc[i][1] + bb.y,
                                   acc[i][2] + bb.z, acc[i][3] + bb.w);
            *(float4*)(C + (size_t)r * N + col0 + tx * 4) = v;
        }
    }
}

// ---------------------------------------------------------------- CSR build
__global__ void count_kernel(const int* __restrict__ ei, int* __restrict__ indeg, int E) {
    int e = blockIdx.x * blockDim.x + threadIdx.x;
    if (e < E) atomicAdd(&indeg[ei[E + e]], 1);
}

// single-block exclusive scan over indeg[N] -> offsets[N+1], cursor[N]
__global__ __launch_bounds__(1024) void scan_kernel(const int* __restrict__ indeg,
                                                    int* __restrict__ offsets,
                                                    int* __restrict__ cursor, int N) {
    __shared__ int partial[1024];
    int tid = threadIdx.x;
    int per = (N + 1023) / 1024;
    int start = tid * per;
    int end = min(start + per, N);
    int sum = 0;
    for (int i = start; i < end; ++i) sum += indeg[i];
    partial[tid] = sum;
    __syncthreads();
    for (int st = 1; st < 1024; st <<= 1) {
        int v = (tid >= st) ? partial[tid - st] : 0;
        __syncthreads();
        partial[tid] += v;
        __syncthreads();
    }
    int run = (tid == 0) ? 0 : partial[tid - 1];
    for (int i = start; i < end; ++i) {
        offsets[i] = run; cursor[i] = run;
        run += indeg[i];
    }
    if (tid == 1023) offsets[N] = run;
}

__global__ void scatter_kernel(const int* __restrict__ ei, int* __restrict__ cursor,
                               int* __restrict__ csr_src, int E) {
    int e = blockIdx.x * blockDim.x + threadIdx.x;
    if (e < E) {
        int d = ei[E + e];
        int p = atomicAdd(&cursor[d], 1);
        csr_src[p] = ei[e];
    }
}

// ---------------------------------------------------------------- e_src/e_dst
// layer 1: one wave per (node, head); 4 heads x 128 channels
__global__ void e1_kernel(const float* __restrict__ h1,
                          const float* __restrict__ a_src, const float* __restrict__ a_dst,
                          float* __restrict__ e_src, float* __restrict__ e_dst, int N) {
    int gw = (blockIdx.x * blockDim.x + threadIdx.x) >> 6;
    int lane = threadIdx.x & 63;
    if (gw >= N * 4) return;
    int node = gw >> 2, h = gw & 3;
    const float* row = h1 + (size_t)node * 512 + h * 128;
    const float* as = a_src + h * 128;
    const float* ad = a_dst + h * 128;
    float vs = row[lane] * as[lane] + row[lane + 64] * as[lane + 64];
    float vd = row[lane] * ad[lane] + row[lane + 64] * ad[lane + 64];
#pragma unroll
    for (int st = 32; st >= 1; st >>= 1) {
        vs += __shfl_xor(vs, st);
        vd += __shfl_xor(vd, st);
    }
    if (lane == 0) { e_src[gw] = vs; e_dst[gw] = vd; }
}

// layer 2: one wave per node; 1 head x 128 channels
__global__ void e2_kernel(const float* __restrict__ h2,
                          const float* __restrict__ a_src, const float* __restrict__ a_dst,
                          float* __restrict__ e_src, float* __restrict__ e_dst, int N) {
    int gw = (blockIdx.x * blockDim.x + threadIdx.x) >> 6;
    int lane = threadIdx.x & 63;
    if (gw >= N) return;
    const float* row = h2 + (size_t)gw * 128;
    float vs = row[lane] * a_src[lane] + row[lane + 64] * a_src[lane + 64];
    float vd = row[lane] * a_dst[lane] + row[lane + 64] * a_dst[lane + 64];
#pragma unroll
    for (int st = 32; st >= 1; st >>= 1) {
        vs += __shfl_xor(vs, st);
        vd += __shfl_xor(vd, st);
    }
    if (lane == 0) { e_src[gw] = vs; e_dst[gw] = vd; }
}

// ---------------------------------------------------------------- aggregation
// Layer 1: H=4, C=128. One block (512 thr) per dst node; online softmax over
// incoming-edge chunks of 128; fused +b1 and ELU.
__global__ __launch_bounds__(512) void agg1_kernel(
    const float* __restrict__ h1, const float* __restrict__ e_src,
    const float* __restrict__ e_dst, const int* __restrict__ offsets,
    const int* __restrict__ csr_src, const float* __restrict__ bias,
    float* __restrict__ out, int N)
{
    int node = blockIdx.x;
    int beg = offsets[node], end = offsets[node + 1];
    int tid = threadIdx.x;
    int h = tid >> 7;                 // accumulator head (0..3), c = tid&127
    int eedge = tid >> 2, ehead = tid & 3;  // e-compute mapping (128 edges x 4 heads)
    __shared__ int s_src[128];
    __shared__ float s_w[512];        // [edge*4 + head]
    __shared__ float s_red[512];
    __shared__ float s_m[4], s_s[4], s_scale[4];
    if (tid < 4) { s_m[tid] = -1e30f; s_s[tid] = 0.f; }
    float acc = 0.f;
    float edst_e = e_dst[node * 4 + ehead];
    __syncthreads();

    for (int base = beg; base < end; base += 128) {
        int n = min(128, end - base);
        float e = -1e30f;
        int sid = 0;
        if (eedge < n) {
            sid = csr_src[base + eedge];
            float v = e_src[sid * 4 + ehead] + edst_e;
            e = (v > 0.f) ? v : NSLOPE * v;
        }
        if (ehead == 0 && eedge < n) s_src[eedge] = sid;
        s_red[tid] = e;
        __syncthreads();
#pragma unroll
        for (int st = 256; st >= 4; st >>= 1) {   // per-head max over edges
            if (tid < st) s_red[tid] = fmaxf(s_red[tid], s_red[tid + st]);
            __syncthreads();
        }
        if (tid < 4) {
            float m_old = s_m[tid];
            float m_new = fmaxf(m_old, s_red[tid]);
            s_scale[tid] = __expf(m_old - m_new);   // -1e30 - finite -> 0
            s_m[tid] = m_new;
        }
        __syncthreads();
        float w = (eedge < n) ? __expf(e - s_m[ehead]) : 0.f;
        s_w[tid] = w;
        s_red[tid] = w;
        __syncthreads();
#pragma unroll
        for (int st = 256; st >= 4; st >>= 1) {   // per-head sum
            if (tid < st) s_red[tid] += s_red[tid + st];
            __syncthreads();
        }
        if (tid < 4) s_s[tid] = s_s[tid] * s_scale[tid] + s_red[tid];
        acc *= s_scale[h];
        __syncthreads();
#pragma unroll 4
        for (int j = 0; j < n; ++j) {
            acc += s_w[j * 4 + h] * h1[(size_t)s_src[j] * 512 + tid];
        }
        __syncthreads();
    }
    float r = acc / (s_s[h] + 1e-16f) + bias[tid];
    out[(size_t)node * 512 + tid] = (r > 0.f) ? r : (__expf(r) - 1.f);  // ELU
}

// Layer 2: H=1, C=128. One block (128 thr) per dst node; +b2, no ELU.
__global__ __launch_bounds__(128) void agg2_kernel(
    const float* __restrict__ h2, const float* __restrict__ e_src,
    const float* __restrict__ e_dst, const int* __restrict__ offsets,
    const int* __restrict__ csr_src, const float* __restrict__ bias,
    float* __restrict__ out, int N)
{
    int node = blockIdx.x;
    int tid = threadIdx.x;
    int beg = offsets[node], end = offsets[node + 1];
    __shared__ int s_src[128];
    __shared__ float s_w[128];
    __shared__ float s_red[128];
    __shared__ float s_m, s_s, s_scale;
    if (tid == 0) { s_m = -1e30f; s_s = 0.f; }
    float acc = 0.f;
    float edst = e_dst[node];
    __syncthreads();

    for (int base = beg; base < end; base += 128) {
        int n = min(128, end - base);
        float e = -1e30f;
        if (tid < n) {
            int sid = csr_src[base + tid];
            s_src[tid] = sid;
            float v = e_src[sid] + edst;
            e = (v > 0.f) ? v : NSLOPE * v;
        }
        s_red[tid] = e;
        __syncthreads();
#pragma unroll
        for (int st = 64; st >= 1; st >>= 1) {
            if (tid < st) s_red[tid] = fmaxf(s_red[tid], s_red[tid + st]);
            __syncthreads();
        }
        if (tid == 0) {
            float m_old = s_m, m_new = fmaxf(m_old, s_red[0]);
            s_scale = __expf(m_old - m_new);
            s_m = m_new;
        }
        __syncthreads();
        float w = (tid < n) ? __expf(e - s_m) : 0.f;
        s_w[tid] = w;
        s_red[tid] = w;
        __syncthreads();
#pragma unroll
        for (int st = 64; st >= 1; st >>= 1) {
            if (tid < st) s_red[tid] += s_red[tid + st];
            __syncthreads();
        }
        if (tid == 0) s_s = s_s * s_scale + s_red[0];
        acc *= s_scale;
        __syncthreads();
#pragma unroll 4
        for (int j = 0; j < n; ++j) {
            acc += s_w[j] * h2[(size_t)s_src[j] * 128 + tid];
        }
        __syncthreads();
    }
    out[(size_t)node * 128 + tid] = acc / (s_s + 1e-16f) + bias[tid];
}

// ---------------------------------------------------------------- launch
extern "C" void kernel_launch(void* const* d_in, const int* in_sizes, int n_in,
                              void* d_out, int out_size, void* d_ws, size_t ws_size,
                              hipStream_t stream) {
    const float* x      = (const float*)d_in[0];
    const int*   ei     = (const int*)  d_in[1];
    const float* sent   = (const float*)d_in[2];
    const float* W1     = (const float*)d_in[3];
    const float* a1_src = (const float*)d_in[4];
    const float* a1_dst = (const float*)d_in[5];
    const float* b1     = (const float*)d_in[6];
    const float* W2     = (const float*)d_in[7];
    const float* a2_src = (const float*)d_in[8];
    const float* a2_dst = (const float*)d_in[9];
    const float* b2     = (const float*)d_in[10];
    float* out = (float*)d_out;

    const int N = in_sizes[0] / 768;   // 20000
    const int E = in_sizes[1] / 2;     // 320000

    // workspace carve (aligned to 256B)
    char* p = (char*)d_ws;
    auto carve = [&](size_t bytes) {
        char* q = p;
        p += (bytes + 255) & ~(size_t)255;
        return q;
    };
    float* h1     = (float*)carve((size_t)N * 512 * 4);
    float* h_elu  = (float*)carve((size_t)N * 512 * 4);
    float* h2     = (float*)carve((size_t)N * 128 * 4);
    float* svec   = (float*)carve(512 * 4);
    float* e_src1 = (float*)carve((size_t)N * 4 * 4);
    float* e_dst1 = (float*)carve((size_t)N * 4 * 4);
    float* e_src2 = (float*)carve((size_t)N * 4);
    float* e_dst2 = (float*)carve((size_t)N * 4);
    int*   indeg  = (int*)carve((size_t)N * 4);
    int*   offs   = (int*)carve((size_t)(N + 1) * 4);
    int*   cursor = (int*)carve((size_t)N * 4);
    int*   csrsrc = (int*)carve((size_t)E * 4);

    // CSR build (independent of GEMM; launch early)
    zero_int_kernel<<<(N + 255) / 256, 256, 0, stream>>>(indeg, N);
    count_kernel<<<(E + 255) / 256, 256, 0, stream>>>(ei, indeg, E);
    scan_kernel<<<1, 1024, 0, stream>>>(indeg, offs, cursor, N);
    scatter_kernel<<<(E + 255) / 256, 256, 0, stream>>>(ei, cursor, csrsrc, E);

    // sentence half of GEMM1
    svec_kernel<<<2, 256, 0, stream>>>(sent, W1, svec);

    // GEMM1: h1 = x @ W1[:768] + svec    [N,512]
    gemm_kernel<<<dim3(512 / 64, (N + 63) / 64), 256, 0, stream>>>(
        x, W1, svec, h1, N, 512, 768);

    // layer-1 attention coefficients
    e1_kernel<<<(N * 4 * 64 + 255) / 256, 256, 0, stream>>>(
        h1, a1_src, a1_dst, e_src1, e_dst1, N);

    // layer-1 aggregate + b1 + ELU -> h_elu [N,512]
    agg1_kernel<<<N, 512, 0, stream>>>(h1, e_src1, e_dst1, offs, csrsrc, b1, h_elu, N);

    // GEMM2: h2 = h_elu @ W2   [N,128]
    gemm_kernel<<<dim3(128 / 64, (N + 63) / 64), 256, 0, stream>>>(
        h_elu, W2, nullptr, h2, N, 128, 512);

    // layer-2 attention coefficients
    e2_kernel<<<(N * 64 + 255) / 256, 256, 0, stream>>>(
        h2, a2_src, a2_dst, e_src2, e_dst2, N);

    // layer-2 aggregate + b2 -> out [N,128]
    agg2_kernel<<<N, 128, 0, stream>>>(h2, e_src2, e_dst2, offs, csrsrc, b2, out, N);
}

// Round 2
// 501.311 us; speedup vs baseline: 1.5386x; 1.5386x over previous
//
#include <hip/hip_runtime.h>
#include <cstdint>
#include <cstddef>

#define NSLOPE 0.2f

typedef __attribute__((ext_vector_type(8))) short bf16x8;
typedef __attribute__((ext_vector_type(4))) float f32x4;
typedef unsigned short ushort_t;

// ---------------------------------------------------------------- utilities
__global__ void zero_int_kernel(int* __restrict__ p, int n) {
    int i = blockIdx.x * blockDim.x + threadIdx.x;
    if (i < n) p[i] = 0;
}

__device__ inline ushort_t f2bf(float f) {
    union { float f; unsigned u; } v; v.f = f;
    unsigned u = v.u;
    unsigned r = (u + 0x7fffu + ((u >> 16) & 1u)) >> 16;   // RNE
    return (ushort_t)r;
}

// fp32 -> bf16 flat cast (n divisible by 8)
__global__ void cast_bf16_kernel(const float* __restrict__ in,
                                 ushort_t* __restrict__ out, size_t n) {
    size_t i = ((size_t)blockIdx.x * blockDim.x + threadIdx.x) * 8;
    if (i >= n) return;
    float4 v0 = *(const float4*)(in + i);
    float4 v1 = *(const float4*)(in + i + 4);
    ushort_t r[8] = { f2bf(v0.x), f2bf(v0.y), f2bf(v0.z), f2bf(v0.w),
                      f2bf(v1.x), f2bf(v1.y), f2bf(v1.z), f2bf(v1.w) };
    *(uint4*)(out + i) = *(uint4*)r;
}

// W1[0:768][0:512] fp32 -> BT[512][768] bf16 (transpose + cast)
__global__ __launch_bounds__(256) void transpose_cast_kernel(
    const float* __restrict__ W1, ushort_t* __restrict__ BT) {
    __shared__ float tile[32][33];
    int k0 = blockIdx.x * 32;   // 24 blocks
    int n0 = blockIdx.y * 32;   // 16 blocks
    int tx = threadIdx.x & 31;
    int ty = threadIdx.x >> 5;  // 0..7
#pragma unroll
    for (int i = 0; i < 4; ++i)
        tile[ty + i * 8][tx] = W1[(size_t)(k0 + ty + i * 8) * 512 + n0 + tx];
    __syncthreads();
#pragma unroll
    for (int i = 0; i < 4; ++i)
        BT[(size_t)(n0 + ty + i * 8) * 768 + k0 + tx] = f2bf(tile[tx][ty + i * 8]);
}

// s_vec[c] = sum_k sent[k] * W1[768+k][c]   (sentence half of GEMM1, fp32)
__global__ void svec_kernel(const float* __restrict__ sent,
                            const float* __restrict__ W1,
                            float* __restrict__ svec) {
    int c = blockIdx.x * blockDim.x + threadIdx.x;
    if (c >= 512) return;
    float acc = 0.f;
    for (int k = 0; k < 768; ++k)
        acc += sent[k] * W1[(size_t)(768 + k) * 512 + c];
    svec[c] = acc;
}

// ---------------------------------------------------------------- MFMA GEMM1
// C[M,512] = A_bf16[M,768] @ BT_bf16[512,768]^T + bias[512]
// 128x128 tile, BK=32, 256 threads (4 waves, 2x2 wave grid, 4x4 16x16 tiles each).
__device__ inline void async_copy16(const void* g, void* l) {
    __builtin_amdgcn_global_load_lds(
        (const __attribute__((address_space(1))) unsigned int*)g,
        (__attribute__((address_space(3))) unsigned int*)l, 16, 0, 0);
}

__global__ __launch_bounds__(256) void mfma_gemm1_kernel(
    const ushort_t* __restrict__ A,   // [M][768] bf16
    const ushort_t* __restrict__ BT,  // [512][768] bf16
    const float* __restrict__ bias,   // [512]
    float* __restrict__ C,            // [M][512] fp32
    int M)
{
    const int K = 768;
    __shared__ __align__(16) ushort_t lA[128 * 32];
    __shared__ __align__(16) ushort_t lB[128 * 32];
    const int tid = threadIdx.x;
    const int wave = tid >> 6;
    const int lane = tid & 63;
    const int row0 = blockIdx.x * 128;
    const int col0 = blockIdx.y * 128;
    const int wm = (wave & 1) * 64;
    const int wn = (wave >> 1) * 64;
    const int q = lane >> 4;       // quad 0..3
    const int ml = lane & 15;

    f32x4 acc[4][4] = {};

    // staging map: slot p in [0,512): row = p>>2, stored-chunk s = p&3,
    // holds global k-chunk g = s ^ ((row>>1)&3)  (XOR swizzle, keeps 64B coalescing)
    int rowS[2], gS[2];
#pragma unroll
    for (int i = 0; i < 2; ++i) {
        int p = wave * 128 + i * 64 + lane;
        int r = p >> 2, s = p & 3;
        rowS[i] = r;
        gS[i] = s ^ ((r >> 1) & 3);
    }

    for (int k0 = 0; k0 < K; k0 += 32) {
#pragma unroll
        for (int i = 0; i < 2; ++i) {
            int pb = wave * 128 + i * 64;           // wave-uniform LDS slot base
            int r = rowS[i];
            int ga = min(row0 + r, M - 1);          // clamp (dup rows, discarded)
            async_copy16(A + (size_t)ga * K + k0 + gS[i] * 8, &lA[(size_t)pb * 8]);
            async_copy16(BT + (size_t)(col0 + r) * K + k0 + gS[i] * 8, &lB[(size_t)pb * 8]);
        }
        __syncthreads();   // drains vmcnt before barrier
        bf16x8 af[4], bfr[4];
#pragma unroll
        for (int t = 0; t < 4; ++t) {
            int m = wm + t * 16 + ml;
            af[t] = *(const bf16x8*)&lA[(size_t)(m * 4 + (q ^ ((m >> 1) & 3))) * 8];
            int n = wn + t * 16 + ml;
            bfr[t] = *(const bf16x8*)&lB[(size_t)(n * 4 + (q ^ ((n >> 1) & 3))) * 8];
        }
#pragma unroll
        for (int tm = 0; tm < 4; ++tm)
#pragma unroll
            for (int tn = 0; tn < 4; ++tn)
                acc[tm][tn] = __builtin_amdgcn_mfma_f32_16x16x32_bf16(
                    af[tm], bfr[tn], acc[tm][tn], 0, 0, 0);
        __syncthreads();
    }
    // epilogue: C/D layout col=lane&15, row=quad*4+reg
#pragma unroll
    for (int tm = 0; tm < 4; ++tm) {
        int rbase = row0 + wm + tm * 16 + q * 4;
#pragma unroll
        for (int tn = 0; tn < 4; ++tn) {
            int col = col0 + wn + tn * 16 + ml;
            float bb = bias[col];
#pragma unroll
            for (int r = 0; r < 4; ++r) {
                int row = rbase + r;
                if (row < M)
                    C[(size_t)row * 512 + col] = acc[tm][tn][r] + bb;
            }
        }
    }
}

// ---------------------------------------------------------------- fp32 GEMM (layer 2)
__global__ __launch_bounds__(256) void gemm_kernel(
    const float* __restrict__ A, const float* __restrict__ B,
    const float* __restrict__ bias, float* __restrict__ C,
    int M, int N, int K)
{
    const int BM = 64, BN = 64, BK = 16;
    __shared__ float As[BK][BM + 1];
    __shared__ float Bs[BK][BN + 1];
    int tid = threadIdx.x;
    int tx = tid & 15;
    int ty = tid >> 4;
    int row0 = blockIdx.y * BM;
    int col0 = blockIdx.x * BN;
    float acc[4][4] = {};
    int ar = tid >> 2, ak = (tid & 3) << 2;
    int br = tid >> 4, bc = (tid & 15) << 2;

    for (int k0 = 0; k0 < K; k0 += BK) {
        float4 av = make_float4(0.f, 0.f, 0.f, 0.f);
        int r = row0 + ar;
        if (r < M) av = *(const float4*)(A + (size_t)r * K + k0 + ak);
        float4 bv = *(const float4*)(B + (size_t)(k0 + br) * N + col0 + bc);
        As[ak + 0][ar] = av.x; As[ak + 1][ar] = av.y;
        As[ak + 2][ar] = av.z; As[ak + 3][ar] = av.w;
        Bs[br][bc + 0] = bv.x; Bs[br][bc + 1] = bv.y;
        Bs[br][bc + 2] = bv.z; Bs[br][bc + 3] = bv.w;
        __syncthreads();
#pragma unroll
        for (int kk = 0; kk < BK; ++kk) {
            float a0 = As[kk][ty * 4 + 0], a1 = As[kk][ty * 4 + 1];
            float a2 = As[kk][ty * 4 + 2], a3 = As[kk][ty * 4 + 3];
            float b0 = Bs[kk][tx * 4 + 0], b1 = Bs[kk][tx * 4 + 1];
            float b2 = Bs[kk][tx * 4 + 2], b3 = Bs[kk][tx * 4 + 3];
            acc[0][0] += a0 * b0; acc[0][1] += a0 * b1; acc[0][2] += a0 * b2; acc[0][3] += a0 * b3;
            acc[1][0] += a1 * b0; acc[1][1] += a1 * b1; acc[1][2] += a1 * b2; acc[1][3] += a1 * b3;
            acc[2][0] += a2 * b0; acc[2][1] += a2 * b1; acc[2][2] += a2 * b2; acc[2][3] += a2 * b3;
            acc[3][0] += a3 * b0; acc[3][1] += a3 * b1; acc[3][2] += a3 * b2; acc[3][3] += a3 * b3;
        }
        __syncthreads();
    }
    float4 bb = make_float4(0.f, 0.f, 0.f, 0.f);
    if (bias) bb = *(const float4*)(bias + col0 + tx * 4);
#pragma unroll
    for (int i = 0; i < 4; ++i) {
        int r = row0 + ty * 4 + i;
        if (r < M) {
            float4 v = make_float4(acc[i][0] + bb.x, acc[i][1] + bb.y,
                                   acc[i][2] + bb.z, acc[i][3] + bb.w);
            *(float4*)(C + (size_t)r * N + col0 + tx * 4) = v;
        }
    }
}

// ---------------------------------------------------------------- CSR build
__global__ void count_kernel(const int* __restrict__ ei, int* __restrict__ indeg, int E) {
    int e = blockIdx.x * blockDim.x + threadIdx.x;
    if (e < E) atomicAdd(&indeg[ei[E + e]], 1);
}

__global__ __launch_bounds__(1024) void scan_kernel(const int* __restrict__ indeg,
                                                    int* __restrict__ offsets,
                                                    int* __restrict__ cursor, int N) {
    __shared__ int partial[1024];
    int tid = threadIdx.x;
    int per = (N + 1023) / 1024;
    int start = tid * per;
    int end = min(start + per, N);
    int sum = 0;
    for (int i = start; i < end; ++i) sum += indeg[i];
    partial[tid] = sum;
    __syncthreads();
    for (int st = 1; st < 1024; st <<= 1) {
        int v = (tid >= st) ? partial[tid - st] : 0;
        __syncthreads();
        partial[tid] += v;
        __syncthreads();
    }
    int run = (tid == 0) ? 0 : partial[tid - 1];
    for (int i = start; i < end; ++i) {
        offsets[i] = run; cursor[i] = run;
        run += indeg[i];
    }
    if (tid == 1023) offsets[N] = run;
}

__global__ void scatter_kernel(const int* __restrict__ ei, int* __restrict__ cursor,
                               int* __restrict__ csr_src, int E) {
    int e = blockIdx.x * blockDim.x + threadIdx.x;
    if (e < E) {
        int d = ei[E + e];
        int p = atomicAdd(&cursor[d], 1);
        csr_src[p] = ei[e];
    }
}

// ---------------------------------------------------------------- e_src/e_dst
__global__ void e1_kernel(const float* __restrict__ h1,
                          const float* __restrict__ a_src, const float* __restrict__ a_dst,
                          float* __restrict__ e_src, float* __restrict__ e_dst, int N) {
    int gw = (blockIdx.x * blockDim.x + threadIdx.x) >> 6;
    int lane = threadIdx.x & 63;
    if (gw >= N * 4) return;
    int node = gw >> 2, h = gw & 3;
    const float* row = h1 + (size_t)node * 512 + h * 128;
    const float* as = a_src + h * 128;
    const float* ad = a_dst + h * 128;
    float vs = row[lane] * as[lane] + row[lane + 64] * as[lane + 64];
    float vd = row[lane] * ad[lane] + row[lane + 64] * ad[lane + 64];
#pragma unroll
    for (int st = 32; st >= 1; st >>= 1) {
        vs += __shfl_xor(vs, st);
        vd += __shfl_xor(vd, st);
    }
    if (lane == 0) { e_src[gw] = vs; e_dst[gw] = vd; }
}

__global__ void e2_kernel(const float* __restrict__ h2,
                          const float* __restrict__ a_src, const float* __restrict__ a_dst,
                          float* __restrict__ e_src, float* __restrict__ e_dst, int N) {
    int gw = (blockIdx.x * blockDim.x + threadIdx.x) >> 6;
    int lane = threadIdx.x & 63;
    if (gw >= N) return;
    const float* row = h2 + (size_t)gw * 128;
    float vs = row[lane] * a_src[lane] + row[lane + 64] * a_src[lane + 64];
    float vd = row[lane] * a_dst[lane] + row[lane + 64] * a_dst[lane + 64];
#pragma unroll
    for (int st = 32; st >= 1; st >>= 1) {
        vs += __shfl_xor(vs, st);
        vd += __shfl_xor(vd, st);
    }
    if (lane == 0) { e_src[gw] = vs; e_dst[gw] = vd; }
}

// ---------------------------------------------------------------- aggregation
__global__ __launch_bounds__(512) void agg1_kernel(
    const float* __restrict__ h1, const float* __restrict__ e_src,
    const float* __restrict__ e_dst, const int* __restrict__ offsets,
    const int* __restrict__ csr_src, const float* __restrict__ bias,
    float* __restrict__ out, int N)
{
    int node = blockIdx.x;
    int beg = offsets[node], end = offsets[node + 1];
    int tid = threadIdx.x;
    int h = tid >> 7;
    int eedge = tid >> 2, ehead = tid & 3;
    __shared__ int s_src[128];
    __shared__ float s_w[512];
    __shared__ float s_red[512];
    __shared__ float s_m[4], s_s[4], s_scale[4];
    if (tid < 4) { s_m[tid] = -1e30f; s_s[tid] = 0.f; }
    float acc = 0.f;
    float edst_e = e_dst[node * 4 + ehead];
    __syncthreads();

    for (int base = beg; base < end; base += 128) {
        int n = min(128, end - base);
        float e = -1e30f;
        int sid = 0;
        if (eedge < n) {
            sid = csr_src[base + eedge];
            float v = e_src[sid * 4 + ehead] + edst_e;
            e = (v > 0.f) ? v : NSLOPE * v;
        }
        if (ehead == 0 && eedge < n) s_src[eedge] = sid;
        s_red[tid] = e;
        __syncthreads();
#pragma unroll
        for (int st = 256; st >= 4; st >>= 1) {
            if (tid < st) s_red[tid] = fmaxf(s_red[tid], s_red[tid + st]);
            __syncthreads();
        }
        if (tid < 4) {
            float m_old = s_m[tid];
            float m_new = fmaxf(m_old, s_red[tid]);
            s_scale[tid] = __expf(m_old - m_new);
            s_m[tid] = m_new;
        }
        __syncthreads();
        float w = (eedge < n) ? __expf(e - s_m[ehead]) : 0.f;
        s_w[tid] = w;
        s_red[tid] = w;
        __syncthreads();
#pragma unroll
        for (int st = 256; st >= 4; st >>= 1) {
            if (tid < st) s_red[tid] += s_red[tid + st];
            __syncthreads();
        }
        if (tid < 4) s_s[tid] = s_s[tid] * s_scale[tid] + s_red[tid];
        acc *= s_scale[h];
        __syncthreads();
#pragma unroll 4
        for (int j = 0; j < n; ++j) {
            acc += s_w[j * 4 + h] * h1[(size_t)s_src[j] * 512 + tid];
        }
        __syncthreads();
    }
    float r = acc / (s_s[h] + 1e-16f) + bias[tid];
    out[(size_t)node * 512 + tid] = (r > 0.f) ? r : (__expf(r) - 1.f);
}

__global__ __launch_bounds__(128) void agg2_kernel(
    const float* __restrict__ h2, const float* __restrict__ e_src,
    const float* __restrict__ e_dst, const int* __restrict__ offsets,
    const int* __restrict__ csr_src, const float* __restrict__ bias,
    float* __restrict__ out, int N)
{
    int node = blockIdx.x;
    int tid = threadIdx.x;
    int beg = offsets[node], end = offsets[node + 1];
    __shared__ int s_src[128];
    __shared__ float s_w[128];
    __shared__ float s_red[128];
    __shared__ float s_m, s_s, s_scale;
    if (tid == 0) { s_m = -1e30f; s_s = 0.f; }
    float acc = 0.f;
    float edst = e_dst[node];
    __syncthreads();

    for (int base = beg; base < end; base += 128) {
        int n = min(128, end - base);
        float e = -1e30f;
        if (tid < n) {
            int sid = csr_src[base + tid];
            s_src[tid] = sid;
            float v = e_src[sid] + edst;
            e = (v > 0.f) ? v : NSLOPE * v;
        }
        s_red[tid] = e;
        __syncthreads();
#pragma unroll
        for (int st = 64; st >= 1; st >>= 1) {
            if (tid < st) s_red[tid] = fmaxf(s_red[tid], s_red[tid + st]);
            __syncthreads();
        }
        if (tid == 0) {
            float m_old = s_m, m_new = fmaxf(m_old, s_red[0]);
            s_scale = __expf(m_old - m_new);
            s_m = m_new;
        }
        __syncthreads();
        float w = (tid < n) ? __expf(e - s_m) : 0.f;
        s_w[tid] = w;
        s_red[tid] = w;
        __syncthreads();
#pragma unroll
        for (int st = 64; st >= 1; st >>= 1) {
            if (tid < st) s_red[tid] += s_red[tid + st];
            __syncthreads();
        }
        if (tid == 0) s_s = s_s * s_scale + s_red[0];
        acc *= s_scale;
        __syncthreads();
#pragma unroll 4
        for (int j = 0; j < n; ++j) {
            acc += s_w[j] * h2[(size_t)s_src[j] * 128 + tid];
        }
        __syncthreads();
    }
    out[(size_t)node * 128 + tid] = acc / (s_s + 1e-16f) + bias[tid];
}

// ---------------------------------------------------------------- launch
extern "C" void kernel_launch(void* const* d_in, const int* in_sizes, int n_in,
                              void* d_out, int out_size, void* d_ws, size_t ws_size,
                              hipStream_t stream) {
    const float* x      = (const float*)d_in[0];
    const int*   ei     = (const int*)  d_in[1];
    const float* sent   = (const float*)d_in[2];
    const float* W1     = (const float*)d_in[3];
    const float* a1_src = (const float*)d_in[4];
    const float* a1_dst = (const float*)d_in[5];
    const float* b1     = (const float*)d_in[6];
    const float* W2     = (const float*)d_in[7];
    const float* a2_src = (const float*)d_in[8];
    const float* a2_dst = (const float*)d_in[9];
    const float* b2     = (const float*)d_in[10];
    float* out = (float*)d_out;

    const int N = in_sizes[0] / 768;   // 20000
    const int E = in_sizes[1] / 2;     // 320000

    char* p = (char*)d_ws;
    auto carve = [&](size_t bytes) {
        char* q = p;
        p += (bytes + 255) & ~(size_t)255;
        return q;
    };
    float* h1     = (float*)carve((size_t)N * 512 * 4);
    // h_elu aliases x_bf16: x_bf16 (N*768*2 = 30.7MB) dead before agg1 writes h_elu
    char*  shared_region = carve((size_t)N * 512 * 4);     // 41 MB >= 30.7 MB
    ushort_t* x_bf16 = (ushort_t*)shared_region;
    float*    h_elu  = (float*)shared_region;
    float* h2     = (float*)carve((size_t)N * 128 * 4);
    ushort_t* W1T = (ushort_t*)carve((size_t)512 * 768 * 2);
    float* svec   = (float*)carve(512 * 4);
    float* e_src1 = (float*)carve((size_t)N * 4 * 4);
    float* e_dst1 = (float*)carve((size_t)N * 4 * 4);
    float* e_src2 = (float*)carve((size_t)N * 4);
    float* e_dst2 = (float*)carve((size_t)N * 4);
    int*   indeg  = (int*)carve((size_t)N * 4);
    int*   offs   = (int*)carve((size_t)(N + 1) * 4);
    int*   cursor = (int*)carve((size_t)N * 4);
    int*   csrsrc = (int*)carve((size_t)E * 4);

    // CSR build
    zero_int_kernel<<<(N + 255) / 256, 256, 0, stream>>>(indeg, N);
    count_kernel<<<(E + 255) / 256, 256, 0, stream>>>(ei, indeg, E);
    scan_kernel<<<1, 1024, 0, stream>>>(indeg, offs, cursor, N);
    scatter_kernel<<<(E + 255) / 256, 256, 0, stream>>>(ei, cursor, csrsrc, E);

    // bf16 casts for GEMM1
    size_t nx = (size_t)N * 768;
    cast_bf16_kernel<<<(int)((nx / 8 + 255) / 256), 256, 0, stream>>>(x, x_bf16, nx);
    transpose_cast_kernel<<<dim3(24, 16), 256, 0, stream>>>(W1, W1T);
    svec_kernel<<<2, 256, 0, stream>>>(sent, W1, svec);

    // GEMM1 (bf16 MFMA): h1 = x @ W1[:768] + svec
    mfma_gemm1_kernel<<<dim3((N + 127) / 128, 4), 256, 0, stream>>>(
        x_bf16, W1T, svec, h1, N);

    // layer-1 attention
    e1_kernel<<<(N * 4 * 64 + 255) / 256, 256, 0, stream>>>(
        h1, a1_src, a1_dst, e_src1, e_dst1, N);
    agg1_kernel<<<N, 512, 0, stream>>>(h1, e_src1, e_dst1, offs, csrsrc, b1, h_elu, N);

    // GEMM2 (fp32): h2 = h_elu @ W2
    gemm_kernel<<<dim3(128 / 64, (N + 63) / 64), 256, 0, stream>>>(
        h_elu, W2, nullptr, h2, N, 128, 512);

    // layer-2 attention
    e2_kernel<<<(N * 64 + 255) / 256, 256, 0, stream>>>(
        h2, a2_src, a2_dst, e_src2, e_dst2, N);
    agg2_kernel<<<N, 128, 0, stream>>>(h2, e_src2, e_dst2, offs, csrsrc, b2, out, N);
}

// Round 3
// 416.707 us; speedup vs baseline: 1.8510x; 1.2030x over previous
//
#include <hip/hip_runtime.h>
#include <cstdint>
#include <cstddef>

#define NSLOPE 0.2f

typedef __attribute__((ext_vector_type(8))) short bf16x8;
typedef __attribute__((ext_vector_type(4))) float f32x4;
typedef unsigned short ushort_t;

// ---------------------------------------------------------------- utilities
__global__ void zero_int_kernel(int* __restrict__ p, int n) {
    int i = blockIdx.x * blockDim.x + threadIdx.x;
    if (i < n) p[i] = 0;
}

__device__ inline ushort_t f2bf(float f) {
    union { float f; unsigned u; } v; v.f = f;
    unsigned u = v.u;
    unsigned r = (u + 0x7fffu + ((u >> 16) & 1u)) >> 16;   // RNE
    return (ushort_t)r;
}
__device__ inline float bf2f(ushort_t u) {
    union { unsigned u; float f; } v; v.u = ((unsigned)u) << 16;
    return v.f;
}
__device__ inline float2 unpack_bf2(unsigned u) {
    return make_float2(bf2f((ushort_t)(u & 0xffffu)), bf2f((ushort_t)(u >> 16)));
}

// fp32 -> bf16 flat cast (n divisible by 8)
__global__ void cast_bf16_kernel(const float* __restrict__ in,
                                 ushort_t* __restrict__ out, size_t n) {
    size_t i = ((size_t)blockIdx.x * blockDim.x + threadIdx.x) * 8;
    if (i >= n) return;
    float4 v0 = *(const float4*)(in + i);
    float4 v1 = *(const float4*)(in + i + 4);
    ushort_t r[8] = { f2bf(v0.x), f2bf(v0.y), f2bf(v0.z), f2bf(v0.w),
                      f2bf(v1.x), f2bf(v1.y), f2bf(v1.z), f2bf(v1.w) };
    *(uint4*)(out + i) = *(uint4*)r;
}

// W[R][C] fp32 (ld=C) -> WT[C][R] bf16. grid (R/32, C/32), 256 thr.
__global__ __launch_bounds__(256) void transpose_cast_kernel(
    const float* __restrict__ W, ushort_t* __restrict__ WT, int R, int C) {
    __shared__ float tile[32][33];
    int k0 = blockIdx.x * 32;
    int n0 = blockIdx.y * 32;
    int tx = threadIdx.x & 31;
    int ty = threadIdx.x >> 5;
#pragma unroll
    for (int i = 0; i < 4; ++i)
        tile[ty + i * 8][tx] = W[(size_t)(k0 + ty + i * 8) * C + n0 + tx];
    __syncthreads();
#pragma unroll
    for (int i = 0; i < 4; ++i)
        WT[(size_t)(n0 + ty + i * 8) * R + k0 + tx] = f2bf(tile[tx][ty + i * 8]);
}

// s_vec[c] = sum_k sent[k] * W1[768+k][c]
__global__ void svec_kernel(const float* __restrict__ sent,
                            const float* __restrict__ W1,
                            float* __restrict__ svec) {
    int c = blockIdx.x * blockDim.x + threadIdx.x;
    if (c >= 512) return;
    float acc = 0.f;
    for (int k = 0; k < 768; ++k)
        acc += sent[k] * W1[(size_t)(768 + k) * 512 + c];
    svec[c] = acc;
}

// ---------------------------------------------------------------- MFMA GEMM
// Cb[M,Nc](bf16) = A_bf16[M,K] @ BT_bf16[Nc,K]^T (+ bias[Nc] fp32)
// 128x128 tile, BK=32, 256 threads.
__device__ inline void async_copy16(const void* g, void* l) {
    __builtin_amdgcn_global_load_lds(
        (const __attribute__((address_space(1))) unsigned int*)g,
        (__attribute__((address_space(3))) unsigned int*)l, 16, 0, 0);
}

__global__ __launch_bounds__(256) void mfma_gemm_kernel(
    const ushort_t* __restrict__ A,   // [M][K] bf16
    const ushort_t* __restrict__ BT,  // [Nc][K] bf16
    const float* __restrict__ bias,   // [Nc] or null
    ushort_t* __restrict__ Cb,        // [M][Nc] bf16
    int M, int K, int Nc)
{
    __shared__ __align__(16) ushort_t lA[128 * 32];
    __shared__ __align__(16) ushort_t lB[128 * 32];
    const int tid = threadIdx.x;
    const int wave = tid >> 6;
    const int lane = tid & 63;
    const int row0 = blockIdx.x * 128;
    const int col0 = blockIdx.y * 128;
    const int wm = (wave & 1) * 64;
    const int wn = (wave >> 1) * 64;
    const int q = lane >> 4;
    const int ml = lane & 15;

    f32x4 acc[4][4] = {};

    int rowS[2], gS[2];
#pragma unroll
    for (int i = 0; i < 2; ++i) {
        int p = wave * 128 + i * 64 + lane;
        int r = p >> 2, s = p & 3;
        rowS[i] = r;
        gS[i] = s ^ ((r >> 1) & 3);
    }

    for (int k0 = 0; k0 < K; k0 += 32) {
#pragma unroll
        for (int i = 0; i < 2; ++i) {
            int pb = wave * 128 + i * 64;
            int r = rowS[i];
            int ga = min(row0 + r, M - 1);
            async_copy16(A + (size_t)ga * K + k0 + gS[i] * 8, &lA[(size_t)pb * 8]);
            async_copy16(BT + (size_t)(col0 + r) * K + k0 + gS[i] * 8, &lB[(size_t)pb * 8]);
        }
        __syncthreads();
        bf16x8 af[4], bfr[4];
#pragma unroll
        for (int t = 0; t < 4; ++t) {
            int m = wm + t * 16 + ml;
            af[t] = *(const bf16x8*)&lA[(size_t)(m * 4 + (q ^ ((m >> 1) & 3))) * 8];
            int n = wn + t * 16 + ml;
            bfr[t] = *(const bf16x8*)&lB[(size_t)(n * 4 + (q ^ ((n >> 1) & 3))) * 8];
        }
#pragma unroll
        for (int tm = 0; tm < 4; ++tm)
#pragma unroll
            for (int tn = 0; tn < 4; ++tn)
                acc[tm][tn] = __builtin_amdgcn_mfma_f32_16x16x32_bf16(
                    af[tm], bfr[tn], acc[tm][tn], 0, 0, 0);
        __syncthreads();
    }
    // C/D layout: col=lane&15, row=quad*4+reg
#pragma unroll
    for (int tm = 0; tm < 4; ++tm) {
        int rbase = row0 + wm + tm * 16 + q * 4;
#pragma unroll
        for (int tn = 0; tn < 4; ++tn) {
            int col = col0 + wn + tn * 16 + ml;
            float bb = bias ? bias[col] : 0.f;
#pragma unroll
            for (int r = 0; r < 4; ++r) {
                int row = rbase + r;
                if (row < M)
                    Cb[(size_t)row * Nc + col] = f2bf(acc[tm][tn][r] + bb);
            }
        }
    }
}

// ---------------------------------------------------------------- CSR build
__global__ void count_kernel(const int* __restrict__ ei, int* __restrict__ indeg, int E) {
    int e = blockIdx.x * blockDim.x + threadIdx.x;
    if (e < E) atomicAdd(&indeg[ei[E + e]], 1);
}

__global__ __launch_bounds__(1024) void scan_kernel(const int* __restrict__ indeg,
                                                    int* __restrict__ offsets,
                                                    int* __restrict__ cursor, int N) {
    __shared__ int partial[1024];
    int tid = threadIdx.x;
    int per = (N + 1023) / 1024;
    int start = tid * per;
    int end = min(start + per, N);
    int sum = 0;
    for (int i = start; i < end; ++i) sum += indeg[i];
    partial[tid] = sum;
    __syncthreads();
    for (int st = 1; st < 1024; st <<= 1) {
        int v = (tid >= st) ? partial[tid - st] : 0;
        __syncthreads();
        partial[tid] += v;
        __syncthreads();
    }
    int run = (tid == 0) ? 0 : partial[tid - 1];
    for (int i = start; i < end; ++i) {
        offsets[i] = run; cursor[i] = run;
        run += indeg[i];
    }
    if (tid == 1023) offsets[N] = run;
}

__global__ void scatter_kernel(const int* __restrict__ ei, int* __restrict__ cursor,
                               int* __restrict__ csr_src, int E) {
    int e = blockIdx.x * blockDim.x + threadIdx.x;
    if (e < E) {
        int d = ei[E + e];
        int p = atomicAdd(&cursor[d], 1);
        csr_src[p] = ei[e];
    }
}

// ---------------------------------------------------------------- e_src/e_dst
// layer 1: wave per node, bf16 h1, 4 heads. e_src1/e_dst1 stored [N][4].
__global__ __launch_bounds__(256) void e1_kernel(
    const ushort_t* __restrict__ h1b,
    const float* __restrict__ a_src, const float* __restrict__ a_dst,
    float* __restrict__ e_src, float* __restrict__ e_dst, int N) {
    int node = blockIdx.x * 4 + (threadIdx.x >> 6);
    int lane = threadIdx.x & 63;
    if (node >= N) return;
    float vs[4], vd[4];
#pragma unroll
    for (int h = 0; h < 4; ++h) {
        unsigned u = *(const unsigned*)&h1b[(size_t)node * 512 + h * 128 + lane * 2];
        float2 f = unpack_bf2(u);
        float as0 = a_src[h * 128 + lane * 2], as1 = a_src[h * 128 + lane * 2 + 1];
        float ad0 = a_dst[h * 128 + lane * 2], ad1 = a_dst[h * 128 + lane * 2 + 1];
        vs[h] = f.x * as0 + f.y * as1;
        vd[h] = f.x * ad0 + f.y * ad1;
    }
#pragma unroll
    for (int st = 32; st >= 1; st >>= 1) {
#pragma unroll
        for (int h = 0; h < 4; ++h) {
            vs[h] += __shfl_xor(vs[h], st);
            vd[h] += __shfl_xor(vd[h], st);
        }
    }
    if (lane == 0) {
        *(float4*)&e_src[node * 4] = make_float4(vs[0], vs[1], vs[2], vs[3]);
        *(float4*)&e_dst[node * 4] = make_float4(vd[0], vd[1], vd[2], vd[3]);
    }
}

// layer 2: wave per node, bf16 h2, 1 head.
__global__ __launch_bounds__(256) void e2_kernel(
    const ushort_t* __restrict__ h2b,
    const float* __restrict__ a_src, const float* __restrict__ a_dst,
    float* __restrict__ e_src, float* __restrict__ e_dst, int N) {
    int node = blockIdx.x * 4 + (threadIdx.x >> 6);
    int lane = threadIdx.x & 63;
    if (node >= N) return;
    unsigned u = *(const unsigned*)&h2b[(size_t)node * 128 + lane * 2];
    float2 f = unpack_bf2(u);
    float vs = f.x * a_src[lane * 2] + f.y * a_src[lane * 2 + 1];
    float vd = f.x * a_dst[lane * 2] + f.y * a_dst[lane * 2 + 1];
#pragma unroll
    for (int st = 32; st >= 1; st >>= 1) {
        vs += __shfl_xor(vs, st);
        vd += __shfl_xor(vd, st);
    }
    if (lane == 0) { e_src[node] = vs; e_dst[node] = vd; }
}

// ---------------------------------------------------------------- alpha (softmax)
// layer 1: wave per node; writes normalized alpha [E][4] (float4 per edge pos).
__global__ __launch_bounds__(256) void alpha1_kernel(
    const float* __restrict__ e_src, const float* __restrict__ e_dst,
    const int* __restrict__ offsets, const int* __restrict__ csr_src,
    float* __restrict__ alpha, int N) {
    int node = blockIdx.x * 4 + (threadIdx.x >> 6);
    int lane = threadIdx.x & 63;
    if (node >= N) return;
    int beg = offsets[node], end = offsets[node + 1];
    if (beg == end) return;
    float4 ed = *(const float4*)&e_dst[node * 4];
    // pass 1: max
    float m[4] = { -1e30f, -1e30f, -1e30f, -1e30f };
    for (int base = beg; base < end; base += 64) {
        float e[4] = { -1e30f, -1e30f, -1e30f, -1e30f };
        if (base + lane < end) {
            int sid = csr_src[base + lane];
            float4 es = *(const float4*)&e_src[sid * 4];
            float v0 = es.x + ed.x, v1 = es.y + ed.y, v2 = es.z + ed.z, v3 = es.w + ed.w;
            e[0] = (v0 > 0.f) ? v0 : NSLOPE * v0;
            e[1] = (v1 > 0.f) ? v1 : NSLOPE * v1;
            e[2] = (v2 > 0.f) ? v2 : NSLOPE * v2;
            e[3] = (v3 > 0.f) ? v3 : NSLOPE * v3;
        }
#pragma unroll
        for (int st = 32; st >= 1; st >>= 1)
#pragma unroll
            for (int h = 0; h < 4; ++h)
                e[h] = fmaxf(e[h], __shfl_xor(e[h], st));
#pragma unroll
        for (int h = 0; h < 4; ++h) m[h] = fmaxf(m[h], e[h]);
    }
    // pass 2: sum of exp
    float s[4] = { 0.f, 0.f, 0.f, 0.f };
    for (int base = beg; base < end; base += 64) {
        float w[4] = { 0.f, 0.f, 0.f, 0.f };
        if (base + lane < end) {
            int sid = csr_src[base + lane];
            float4 es = *(const float4*)&e_src[sid * 4];
            float v0 = es.x + ed.x, v1 = es.y + ed.y, v2 = es.z + ed.z, v3 = es.w + ed.w;
            w[0] = __expf(((v0 > 0.f) ? v0 : NSLOPE * v0) - m[0]);
            w[1] = __expf(((v1 > 0.f) ? v1 : NSLOPE * v1) - m[1]);
            w[2] = __expf(((v2 > 0.f) ? v2 : NSLOPE * v2) - m[2]);
            w[3] = __expf(((v3 > 0.f) ? v3 : NSLOPE * v3) - m[3]);
        }
#pragma unroll
        for (int st = 32; st >= 1; st >>= 1)
#pragma unroll
            for (int h = 0; h < 4; ++h)
                w[h] += __shfl_xor(w[h], st);
#pragma unroll
        for (int h = 0; h < 4; ++h) s[h] += w[h];
    }
    float r0 = 1.f / (s[0] + 1e-16f), r1 = 1.f / (s[1] + 1e-16f);
    float r2 = 1.f / (s[2] + 1e-16f), r3 = 1.f / (s[3] + 1e-16f);
    // pass 3: write normalized alpha
    for (int base = beg; base < end; base += 64) {
        if (base + lane < end) {
            int sid = csr_src[base + lane];
            float4 es = *(const float4*)&e_src[sid * 4];
            float v0 = es.x + ed.x, v1 = es.y + ed.y, v2 = es.z + ed.z, v3 = es.w + ed.w;
            float4 a;
            a.x = __expf(((v0 > 0.f) ? v0 : NSLOPE * v0) - m[0]) * r0;
            a.y = __expf(((v1 > 0.f) ? v1 : NSLOPE * v1) - m[1]) * r1;
            a.z = __expf(((v2 > 0.f) ? v2 : NSLOPE * v2) - m[2]) * r2;
            a.w = __expf(((v3 > 0.f) ? v3 : NSLOPE * v3) - m[3]) * r3;
            *(float4*)&alpha[(size_t)(base + lane) * 4] = a;
        }
    }
}

// layer 2: wave per node; writes normalized alpha [E].
__global__ __launch_bounds__(256) void alpha2_kernel(
    const float* __restrict__ e_src, const float* __restrict__ e_dst,
    const int* __restrict__ offsets, const int* __restrict__ csr_src,
    float* __restrict__ alpha, int N) {
    int node = blockIdx.x * 4 + (threadIdx.x >> 6);
    int lane = threadIdx.x & 63;
    if (node >= N) return;
    int beg = offsets[node], end = offsets[node + 1];
    if (beg == end) return;
    float ed = e_dst[node];
    float m = -1e30f;
    for (int base = beg; base < end; base += 64) {
        float e = -1e30f;
        if (base + lane < end) {
            float v = e_src[csr_src[base + lane]] + ed;
            e = (v > 0.f) ? v : NSLOPE * v;
        }
#pragma unroll
        for (int st = 32; st >= 1; st >>= 1)
            e = fmaxf(e, __shfl_xor(e, st));
        m = fmaxf(m, e);
    }
    float s = 0.f;
    for (int base = beg; base < end; base += 64) {
        float w = 0.f;
        if (base + lane < end) {
            float v = e_src[csr_src[base + lane]] + ed;
            w = __expf(((v > 0.f) ? v : NSLOPE * v) - m);
        }
#pragma unroll
        for (int st = 32; st >= 1; st >>= 1)
            w += __shfl_xor(w, st);
        s += w;
    }
    float rs = 1.f / (s + 1e-16f);
    for (int base = beg; base < end; base += 64) {
        if (base + lane < end) {
            float v = e_src[csr_src[base + lane]] + ed;
            alpha[base + lane] = __expf(((v > 0.f) ? v : NSLOPE * v) - m) * rs;
        }
    }
}

// ---------------------------------------------------------------- gather-agg
// layer 1: block(256) per node; thread -> 2 channels (col=2*tid, head=tid>>6).
// out = bf16(ELU(sum alpha*h1 + b1))  [N][512]
__global__ __launch_bounds__(256) void gather1_kernel(
    const ushort_t* __restrict__ h1b, const float* __restrict__ alpha,
    const int* __restrict__ offsets, const int* __restrict__ csr_src,
    const float* __restrict__ bias, ushort_t* __restrict__ outb, int N)
{
    int node = blockIdx.x;
    int tid = threadIdx.x;
    int beg = offsets[node], end = offsets[node + 1];
    __shared__ int s_src[64];
    __shared__ float s_alpha[256];
    int h = tid >> 6;
    float2 acc = make_float2(0.f, 0.f);

    for (int base = beg; base < end; base += 64) {
        int n = min(64, end - base);
        if (tid < 64 && tid < n) s_src[tid] = csr_src[base + tid];
        if (tid < 4 * n) s_alpha[tid] = alpha[(size_t)base * 4 + tid];
        __syncthreads();
#pragma unroll 2
        for (int j = 0; j < n; ++j) {
            float w = s_alpha[j * 4 + h];
            unsigned u = *(const unsigned*)&h1b[(size_t)s_src[j] * 512 + tid * 2];
            float2 f = unpack_bf2(u);
            acc.x += w * f.x;
            acc.y += w * f.y;
        }
        __syncthreads();
    }
    float r0 = acc.x + bias[tid * 2];
    float r1 = acc.y + bias[tid * 2 + 1];
    r0 = (r0 > 0.f) ? r0 : (__expf(r0) - 1.f);
    r1 = (r1 > 0.f) ? r1 : (__expf(r1) - 1.f);
    unsigned o = (unsigned)f2bf(r0) | ((unsigned)f2bf(r1) << 16);
    *(unsigned*)&outb[(size_t)node * 512 + tid * 2] = o;
}

// layer 2: wave per node; lane -> 2 channels. out fp32 [N][128] (final output).
__global__ __launch_bounds__(256) void gather2_kernel(
    const ushort_t* __restrict__ h2b, const float* __restrict__ alpha,
    const int* __restrict__ offsets, const int* __restrict__ csr_src,
    const float* __restrict__ bias, float* __restrict__ out, int N)
{
    int node = blockIdx.x * 4 + (threadIdx.x >> 6);
    int lane = threadIdx.x & 63;
    if (node >= N) return;
    int beg = offsets[node], end = offsets[node + 1];
    float2 acc = make_float2(0.f, 0.f);
    for (int j = beg; j < end; ++j) {
        int src = csr_src[j];
        float w = alpha[j];
        unsigned u = *(const unsigned*)&h2b[(size_t)src * 128 + lane * 2];
        float2 f = unpack_bf2(u);
        acc.x += w * f.x;
        acc.y += w * f.y;
    }
    float2 o = make_float2(acc.x + bias[lane * 2], acc.y + bias[lane * 2 + 1]);
    *(float2*)&out[(size_t)node * 128 + lane * 2] = o;
}

// ---------------------------------------------------------------- launch
extern "C" void kernel_launch(void* const* d_in, const int* in_sizes, int n_in,
                              void* d_out, int out_size, void* d_ws, size_t ws_size,
                              hipStream_t stream) {
    const float* x      = (const float*)d_in[0];
    const int*   ei     = (const int*)  d_in[1];
    const float* sent   = (const float*)d_in[2];
    const float* W1     = (const float*)d_in[3];
    const float* a1_src = (const float*)d_in[4];
    const float* a1_dst = (const float*)d_in[5];
    const float* b1     = (const float*)d_in[6];
    const float* W2     = (const float*)d_in[7];
    const float* a2_src = (const float*)d_in[8];
    const float* a2_dst = (const float*)d_in[9];
    const float* b2     = (const float*)d_in[10];
    float* out = (float*)d_out;

    const int N = in_sizes[0] / 768;   // 20000
    const int E = in_sizes[1] / 2;     // 320000

    char* p = (char*)d_ws;
    auto carve = [&](size_t bytes) {
        char* q = p;
        p += (bytes + 255) & ~(size_t)255;
        return q;
    };
    ushort_t* h1b = (ushort_t*)carve((size_t)N * 512 * 2);       // bf16 h1
    // x_bf16 (30.7MB) dead after GEMM1; h_elu_b (20.5MB) aliases it
    char* shared_region = carve((size_t)N * 768 * 2);
    ushort_t* x_bf16 = (ushort_t*)shared_region;
    ushort_t* h_elu_b = (ushort_t*)shared_region;
    ushort_t* h2b = (ushort_t*)carve((size_t)N * 128 * 2);
    ushort_t* W1T = (ushort_t*)carve((size_t)512 * 768 * 2);
    ushort_t* W2T = (ushort_t*)carve((size_t)128 * 512 * 2);
    float* svec   = (float*)carve(512 * 4);
    float* e_src1 = (float*)carve((size_t)N * 4 * 4);
    float* e_dst1 = (float*)carve((size_t)N * 4 * 4);
    float* e_src2 = (float*)carve((size_t)N * 4);
    float* e_dst2 = (float*)carve((size_t)N * 4);
    float* alpha1 = (float*)carve((size_t)E * 4 * 4);
    float* alpha2 = (float*)carve((size_t)E * 4);
    int*   indeg  = (int*)carve((size_t)N * 4);
    int*   offs   = (int*)carve((size_t)(N + 1) * 4);
    int*   cursor = (int*)carve((size_t)N * 4);
    int*   csrsrc = (int*)carve((size_t)E * 4);

    // CSR build
    zero_int_kernel<<<(N + 255) / 256, 256, 0, stream>>>(indeg, N);
    count_kernel<<<(E + 255) / 256, 256, 0, stream>>>(ei, indeg, E);
    scan_kernel<<<1, 1024, 0, stream>>>(indeg, offs, cursor, N);
    scatter_kernel<<<(E + 255) / 256, 256, 0, stream>>>(ei, cursor, csrsrc, E);

    // bf16 casts
    size_t nx = (size_t)N * 768;
    cast_bf16_kernel<<<(int)((nx / 8 + 255) / 256), 256, 0, stream>>>(x, x_bf16, nx);
    transpose_cast_kernel<<<dim3(24, 16), 256, 0, stream>>>(W1, W1T, 768, 512);
    transpose_cast_kernel<<<dim3(16, 4), 256, 0, stream>>>(W2, W2T, 512, 128);
    svec_kernel<<<2, 256, 0, stream>>>(sent, W1, svec);

    // GEMM1: h1b = bf16(x @ W1[:768] + svec)   [N,512]
    mfma_gemm_kernel<<<dim3((N + 127) / 128, 4), 256, 0, stream>>>(
        x_bf16, W1T, svec, h1b, N, 768, 512);

    // layer-1 attention
    e1_kernel<<<(N + 3) / 4, 256, 0, stream>>>(h1b, a1_src, a1_dst, e_src1, e_dst1, N);
    alpha1_kernel<<<(N + 3) / 4, 256, 0, stream>>>(e_src1, e_dst1, offs, csrsrc, alpha1, N);
    gather1_kernel<<<N, 256, 0, stream>>>(h1b, alpha1, offs, csrsrc, b1, h_elu_b, N);

    // GEMM2: h2b = bf16(h_elu @ W2)   [N,128]
    mfma_gemm_kernel<<<dim3((N + 127) / 128, 1), 256, 0, stream>>>(
        h_elu_b, W2T, nullptr, h2b, N, 512, 128);

    // layer-2 attention
    e2_kernel<<<(N + 3) / 4, 256, 0, stream>>>(h2b, a2_src, a2_dst, e_src2, e_dst2, N);
    alpha2_kernel<<<(N + 3) / 4, 256, 0, stream>>>(e_src2, e_dst2, offs, csrsrc, alpha2, N);
    gather2_kernel<<<(N + 3) / 4, 256, 0, stream>>>(h2b, alpha2, offs, csrsrc, b2, out, N);
}

// Round 4
// 392.155 us; speedup vs baseline: 1.9669x; 1.0626x over previous
//
#include <hip/hip_runtime.h>
#include <cstdint>
#include <cstddef>

#define NSLOPE 0.2f

typedef __attribute__((ext_vector_type(8))) short bf16x8;
typedef __attribute__((ext_vector_type(4))) float f32x4;
typedef unsigned short ushort_t;

// ---------------------------------------------------------------- utilities
__global__ void zero_int_kernel(int* __restrict__ p, int n) {
    int i = blockIdx.x * blockDim.x + threadIdx.x;
    if (i < n) p[i] = 0;
}

__device__ inline ushort_t f2bf(float f) {
    union { float f; unsigned u; } v; v.f = f;
    unsigned u = v.u;
    unsigned r = (u + 0x7fffu + ((u >> 16) & 1u)) >> 16;   // RNE
    return (ushort_t)r;
}
__device__ inline float bf2f(ushort_t u) {
    union { unsigned u; float f; } v; v.u = ((unsigned)u) << 16;
    return v.f;
}
__device__ inline float2 unpack_bf2(unsigned u) {
    return make_float2(bf2f((ushort_t)(u & 0xffffu)), bf2f((ushort_t)(u >> 16)));
}

// fp32 -> bf16 flat cast (n divisible by 8)
__global__ void cast_bf16_kernel(const float* __restrict__ in,
                                 ushort_t* __restrict__ out, size_t n) {
    size_t i = ((size_t)blockIdx.x * blockDim.x + threadIdx.x) * 8;
    if (i >= n) return;
    float4 v0 = *(const float4*)(in + i);
    float4 v1 = *(const float4*)(in + i + 4);
    ushort_t r[8] = { f2bf(v0.x), f2bf(v0.y), f2bf(v0.z), f2bf(v0.w),
                      f2bf(v1.x), f2bf(v1.y), f2bf(v1.z), f2bf(v1.w) };
    *(uint4*)(out + i) = *(uint4*)r;
}

// W[R][C] fp32 (ld=C) -> WT[C][R] bf16. grid (R/32, C/32), 256 thr.
__global__ __launch_bounds__(256) void transpose_cast_kernel(
    const float* __restrict__ W, ushort_t* __restrict__ WT, int R, int C) {
    __shared__ float tile[32][33];
    int k0 = blockIdx.x * 32;
    int n0 = blockIdx.y * 32;
    int tx = threadIdx.x & 31;
    int ty = threadIdx.x >> 5;
#pragma unroll
    for (int i = 0; i < 4; ++i)
        tile[ty + i * 8][tx] = W[(size_t)(k0 + ty + i * 8) * C + n0 + tx];
    __syncthreads();
#pragma unroll
    for (int i = 0; i < 4; ++i)
        WT[(size_t)(n0 + ty + i * 8) * R + k0 + tx] = f2bf(tile[tx][ty + i * 8]);
}

// s_vec[c] = sum_k sent[k] * W1[768+k][c]
__global__ void svec_kernel(const float* __restrict__ sent,
                            const float* __restrict__ W1,
                            float* __restrict__ svec) {
    int c = blockIdx.x * blockDim.x + threadIdx.x;
    if (c >= 512) return;
    float acc = 0.f;
    for (int k = 0; k < 768; ++k)
        acc += sent[k] * W1[(size_t)(768 + k) * 512 + c];
    svec[c] = acc;
}

// ---------------------------------------------------------------- MFMA GEMM
__device__ inline void async_copy16(const void* g, void* l) {
    __builtin_amdgcn_global_load_lds(
        (const __attribute__((address_space(1))) unsigned int*)g,
        (__attribute__((address_space(3))) unsigned int*)l, 16, 0, 0);
}

__global__ __launch_bounds__(256) void mfma_gemm_kernel(
    const ushort_t* __restrict__ A,   // [M][K] bf16
    const ushort_t* __restrict__ BT,  // [Nc][K] bf16
    const float* __restrict__ bias,   // [Nc] or null
    ushort_t* __restrict__ Cb,        // [M][Nc] bf16
    int M, int K, int Nc)
{
    __shared__ __align__(16) ushort_t lA[128 * 32];
    __shared__ __align__(16) ushort_t lB[128 * 32];
    const int tid = threadIdx.x;
    const int wave = tid >> 6;
    const int lane = tid & 63;
    const int row0 = blockIdx.x * 128;
    const int col0 = blockIdx.y * 128;
    const int wm = (wave & 1) * 64;
    const int wn = (wave >> 1) * 64;
    const int q = lane >> 4;
    const int ml = lane & 15;

    f32x4 acc[4][4] = {};

    int rowS[2], gS[2];
#pragma unroll
    for (int i = 0; i < 2; ++i) {
        int p = wave * 128 + i * 64 + lane;
        int r = p >> 2, s = p & 3;
        rowS[i] = r;
        gS[i] = s ^ ((r >> 1) & 3);
    }

    for (int k0 = 0; k0 < K; k0 += 32) {
#pragma unroll
        for (int i = 0; i < 2; ++i) {
            int pb = wave * 128 + i * 64;
            int r = rowS[i];
            int ga = min(row0 + r, M - 1);
            async_copy16(A + (size_t)ga * K + k0 + gS[i] * 8, &lA[(size_t)pb * 8]);
            async_copy16(BT + (size_t)(col0 + r) * K + k0 + gS[i] * 8, &lB[(size_t)pb * 8]);
        }
        __syncthreads();
        bf16x8 af[4], bfr[4];
#pragma unroll
        for (int t = 0; t < 4; ++t) {
            int m = wm + t * 16 + ml;
            af[t] = *(const bf16x8*)&lA[(size_t)(m * 4 + (q ^ ((m >> 1) & 3))) * 8];
            int n = wn + t * 16 + ml;
            bfr[t] = *(const bf16x8*)&lB[(size_t)(n * 4 + (q ^ ((n >> 1) & 3))) * 8];
        }
#pragma unroll
        for (int tm = 0; tm < 4; ++tm)
#pragma unroll
            for (int tn = 0; tn < 4; ++tn)
                acc[tm][tn] = __builtin_amdgcn_mfma_f32_16x16x32_bf16(
                    af[tm], bfr[tn], acc[tm][tn], 0, 0, 0);
        __syncthreads();
    }
#pragma unroll
    for (int tm = 0; tm < 4; ++tm) {
        int rbase = row0 + wm + tm * 16 + q * 4;
#pragma unroll
        for (int tn = 0; tn < 4; ++tn) {
            int col = col0 + wn + tn * 16 + ml;
            float bb = bias ? bias[col] : 0.f;
#pragma unroll
            for (int r = 0; r < 4; ++r) {
                int row = rbase + r;
                if (row < M)
                    Cb[(size_t)row * Nc + col] = f2bf(acc[tm][tn][r] + bb);
            }
        }
    }
}

// ---------------------------------------------------------------- CSR build
__global__ void count_kernel(const int* __restrict__ ei, int* __restrict__ indeg, int E) {
    int e = blockIdx.x * blockDim.x + threadIdx.x;
    if (e < E) atomicAdd(&indeg[ei[E + e]], 1);
}

__global__ __launch_bounds__(1024) void scan_kernel(const int* __restrict__ indeg,
                                                    int* __restrict__ offsets,
                                                    int* __restrict__ cursor, int N) {
    __shared__ int partial[1024];
    int tid = threadIdx.x;
    int per = (N + 1023) / 1024;
    int start = tid * per;
    int end = min(start + per, N);
    int sum = 0;
    for (int i = start; i < end; ++i) sum += indeg[i];
    partial[tid] = sum;
    __syncthreads();
    for (int st = 1; st < 1024; st <<= 1) {
        int v = (tid >= st) ? partial[tid - st] : 0;
        __syncthreads();
        partial[tid] += v;
        __syncthreads();
    }
    int run = (tid == 0) ? 0 : partial[tid - 1];
    for (int i = start; i < end; ++i) {
        offsets[i] = run; cursor[i] = run;
        run += indeg[i];
    }
    if (tid == 1023) offsets[N] = run;
}

__global__ void scatter_kernel(const int* __restrict__ ei, int* __restrict__ cursor,
                               int* __restrict__ csr_src, int E) {
    int e = blockIdx.x * blockDim.x + threadIdx.x;
    if (e < E) {
        int d = ei[E + e];
        int p = atomicAdd(&cursor[d], 1);
        csr_src[p] = ei[e];
    }
}

// ---------------------------------------------------------------- e_src/e_dst
__global__ __launch_bounds__(256) void e1_kernel(
    const ushort_t* __restrict__ h1b,
    const float* __restrict__ a_src, const float* __restrict__ a_dst,
    float* __restrict__ e_src, float* __restrict__ e_dst, int N) {
    int node = blockIdx.x * 4 + (threadIdx.x >> 6);
    int lane = threadIdx.x & 63;
    if (node >= N) return;
    float vs[4], vd[4];
#pragma unroll
    for (int h = 0; h < 4; ++h) {
        unsigned u = *(const unsigned*)&h1b[(size_t)node * 512 + h * 128 + lane * 2];
        float2 f = unpack_bf2(u);
        float as0 = a_src[h * 128 + lane * 2], as1 = a_src[h * 128 + lane * 2 + 1];
        float ad0 = a_dst[h * 128 + lane * 2], ad1 = a_dst[h * 128 + lane * 2 + 1];
        vs[h] = f.x * as0 + f.y * as1;
        vd[h] = f.x * ad0 + f.y * ad1;
    }
#pragma unroll
    for (int st = 32; st >= 1; st >>= 1) {
#pragma unroll
        for (int h = 0; h < 4; ++h) {
            vs[h] += __shfl_xor(vs[h], st);
            vd[h] += __shfl_xor(vd[h], st);
        }
    }
    if (lane == 0) {
        *(float4*)&e_src[node * 4] = make_float4(vs[0], vs[1], vs[2], vs[3]);
        *(float4*)&e_dst[node * 4] = make_float4(vd[0], vd[1], vd[2], vd[3]);
    }
}

__global__ __launch_bounds__(256) void e2_kernel(
    const ushort_t* __restrict__ h2b,
    const float* __restrict__ a_src, const float* __restrict__ a_dst,
    float* __restrict__ e_src, float* __restrict__ e_dst, int N) {
    int node = blockIdx.x * 4 + (threadIdx.x >> 6);
    int lane = threadIdx.x & 63;
    if (node >= N) return;
    unsigned u = *(const unsigned*)&h2b[(size_t)node * 128 + lane * 2];
    float2 f = unpack_bf2(u);
    float vs = f.x * a_src[lane * 2] + f.y * a_src[lane * 2 + 1];
    float vd = f.x * a_dst[lane * 2] + f.y * a_dst[lane * 2 + 1];
#pragma unroll
    for (int st = 32; st >= 1; st >>= 1) {
        vs += __shfl_xor(vs, st);
        vd += __shfl_xor(vd, st);
    }
    if (lane == 0) { e_src[node] = vs; e_dst[node] = vd; }
}

// ---------------------------------------------------------------- alpha (softmax)
// layer 1: wave per node; writes normalized alpha HEAD-MAJOR [4][E].
__global__ __launch_bounds__(256) void alpha1_kernel(
    const float* __restrict__ e_src, const float* __restrict__ e_dst,
    const int* __restrict__ offsets, const int* __restrict__ csr_src,
    float* __restrict__ alpha, int N, int E) {
    int node = blockIdx.x * 4 + (threadIdx.x >> 6);
    int lane = threadIdx.x & 63;
    if (node >= N) return;
    int beg = offsets[node], end = offsets[node + 1];
    if (beg == end) return;
    float4 ed = *(const float4*)&e_dst[node * 4];
    float m[4] = { -1e30f, -1e30f, -1e30f, -1e30f };
    for (int base = beg; base < end; base += 64) {
        float e[4] = { -1e30f, -1e30f, -1e30f, -1e30f };
        if (base + lane < end) {
            int sid = csr_src[base + lane];
            float4 es = *(const float4*)&e_src[sid * 4];
            float v0 = es.x + ed.x, v1 = es.y + ed.y, v2 = es.z + ed.z, v3 = es.w + ed.w;
            e[0] = (v0 > 0.f) ? v0 : NSLOPE * v0;
            e[1] = (v1 > 0.f) ? v1 : NSLOPE * v1;
            e[2] = (v2 > 0.f) ? v2 : NSLOPE * v2;
            e[3] = (v3 > 0.f) ? v3 : NSLOPE * v3;
        }
#pragma unroll
        for (int st = 32; st >= 1; st >>= 1)
#pragma unroll
            for (int h = 0; h < 4; ++h)
                e[h] = fmaxf(e[h], __shfl_xor(e[h], st));
#pragma unroll
        for (int h = 0; h < 4; ++h) m[h] = fmaxf(m[h], e[h]);
    }
    float s[4] = { 0.f, 0.f, 0.f, 0.f };
    for (int base = beg; base < end; base += 64) {
        float w[4] = { 0.f, 0.f, 0.f, 0.f };
        if (base + lane < end) {
            int sid = csr_src[base + lane];
            float4 es = *(const float4*)&e_src[sid * 4];
            float v0 = es.x + ed.x, v1 = es.y + ed.y, v2 = es.z + ed.z, v3 = es.w + ed.w;
            w[0] = __expf(((v0 > 0.f) ? v0 : NSLOPE * v0) - m[0]);
            w[1] = __expf(((v1 > 0.f) ? v1 : NSLOPE * v1) - m[1]);
            w[2] = __expf(((v2 > 0.f) ? v2 : NSLOPE * v2) - m[2]);
            w[3] = __expf(((v3 > 0.f) ? v3 : NSLOPE * v3) - m[3]);
        }
#pragma unroll
        for (int st = 32; st >= 1; st >>= 1)
#pragma unroll
            for (int h = 0; h < 4; ++h)
                w[h] += __shfl_xor(w[h], st);
#pragma unroll
        for (int h = 0; h < 4; ++h) s[h] += w[h];
    }
    float r[4];
#pragma unroll
    for (int h = 0; h < 4; ++h) r[h] = 1.f / (s[h] + 1e-16f);
    for (int base = beg; base < end; base += 64) {
        if (base + lane < end) {
            int j = base + lane;
            int sid = csr_src[j];
            float4 es = *(const float4*)&e_src[sid * 4];
            float v0 = es.x + ed.x, v1 = es.y + ed.y, v2 = es.z + ed.z, v3 = es.w + ed.w;
            alpha[0 * (size_t)E + j] = __expf(((v0 > 0.f) ? v0 : NSLOPE * v0) - m[0]) * r[0];
            alpha[1 * (size_t)E + j] = __expf(((v1 > 0.f) ? v1 : NSLOPE * v1) - m[1]) * r[1];
            alpha[2 * (size_t)E + j] = __expf(((v2 > 0.f) ? v2 : NSLOPE * v2) - m[2]) * r[2];
            alpha[3 * (size_t)E + j] = __expf(((v3 > 0.f) ? v3 : NSLOPE * v3) - m[3]) * r[3];
        }
    }
}

// layer 2: wave per node; writes normalized alpha [E].
__global__ __launch_bounds__(256) void alpha2_kernel(
    const float* __restrict__ e_src, const float* __restrict__ e_dst,
    const int* __restrict__ offsets, const int* __restrict__ csr_src,
    float* __restrict__ alpha, int N) {
    int node = blockIdx.x * 4 + (threadIdx.x >> 6);
    int lane = threadIdx.x & 63;
    if (node >= N) return;
    int beg = offsets[node], end = offsets[node + 1];
    if (beg == end) return;
    float ed = e_dst[node];
    float m = -1e30f;
    for (int base = beg; base < end; base += 64) {
        float e = -1e30f;
        if (base + lane < end) {
            float v = e_src[csr_src[base + lane]] + ed;
            e = (v > 0.f) ? v : NSLOPE * v;
        }
#pragma unroll
        for (int st = 32; st >= 1; st >>= 1)
            e = fmaxf(e, __shfl_xor(e, st));
        m = fmaxf(m, e);
    }
    float s = 0.f;
    for (int base = beg; base < end; base += 64) {
        float w = 0.f;
        if (base + lane < end) {
            float v = e_src[csr_src[base + lane]] + ed;
            w = __expf(((v > 0.f) ? v : NSLOPE * v) - m);
        }
#pragma unroll
        for (int st = 32; st >= 1; st >>= 1)
            w += __shfl_xor(w, st);
        s += w;
    }
    float rs = 1.f / (s + 1e-16f);
    for (int base = beg; base < end; base += 64) {
        if (base + lane < end) {
            float v = e_src[csr_src[base + lane]] + ed;
            alpha[base + lane] = __expf(((v > 0.f) ? v : NSLOPE * v) - m) * rs;
        }
    }
}

// ---------------------------------------------------------------- gather-agg
// layer 1: wave per (node, head-slice). blockIdx.y = head; lane -> 2 channels
// within the head's 128. 4-edge batched gather loads. alpha head-major [4][E].
__global__ __launch_bounds__(256) void gather1_kernel(
    const ushort_t* __restrict__ h1b, const float* __restrict__ alpha,
    const int* __restrict__ offsets, const int* __restrict__ csr_src,
    const float* __restrict__ bias, ushort_t* __restrict__ outb, int N, int E)
{
    int node = blockIdx.x * 4 + (threadIdx.x >> 6);
    int h = blockIdx.y;
    int lane = threadIdx.x & 63;
    if (node >= N) return;
    int beg = offsets[node], end = offsets[node + 1];
    const float* al = alpha + (size_t)h * E;
    const ushort_t* hb = h1b + h * 128 + lane * 2;
    float2 acc = make_float2(0.f, 0.f);
    int j = beg;
#pragma unroll 2
    for (; j + 4 <= end; j += 4) {
        int s0 = csr_src[j], s1 = csr_src[j + 1], s2 = csr_src[j + 2], s3 = csr_src[j + 3];
        float w0 = al[j], w1 = al[j + 1], w2 = al[j + 2], w3 = al[j + 3];
        unsigned u0 = *(const unsigned*)&hb[(size_t)s0 * 512];
        unsigned u1 = *(const unsigned*)&hb[(size_t)s1 * 512];
        unsigned u2 = *(const unsigned*)&hb[(size_t)s2 * 512];
        unsigned u3 = *(const unsigned*)&hb[(size_t)s3 * 512];
        float2 f0 = unpack_bf2(u0), f1 = unpack_bf2(u1);
        float2 f2 = unpack_bf2(u2), f3 = unpack_bf2(u3);
        acc.x += w0 * f0.x + w1 * f1.x + w2 * f2.x + w3 * f3.x;
        acc.y += w0 * f0.y + w1 * f1.y + w2 * f2.y + w3 * f3.y;
    }
    for (; j < end; ++j) {
        int s0 = csr_src[j];
        float w0 = al[j];
        float2 f0 = unpack_bf2(*(const unsigned*)&hb[(size_t)s0 * 512]);
        acc.x += w0 * f0.x;
        acc.y += w0 * f0.y;
    }
    int c = h * 128 + lane * 2;
    float r0 = acc.x + bias[c];
    float r1 = acc.y + bias[c + 1];
    r0 = (r0 > 0.f) ? r0 : (__expf(r0) - 1.f);
    r1 = (r1 > 0.f) ? r1 : (__expf(r1) - 1.f);
    unsigned o = (unsigned)f2bf(r0) | ((unsigned)f2bf(r1) << 16);
    *(unsigned*)&outb[(size_t)node * 512 + c] = o;
}

// layer 2: wave per node; lane -> 2 channels; 4-edge batching. out fp32.
__global__ __launch_bounds__(256) void gather2_kernel(
    const ushort_t* __restrict__ h2b, const float* __restrict__ alpha,
    const int* __restrict__ offsets, const int* __restrict__ csr_src,
    const float* __restrict__ bias, float* __restrict__ out, int N)
{
    int node = blockIdx.x * 4 + (threadIdx.x >> 6);
    int lane = threadIdx.x & 63;
    if (node >= N) return;
    int beg = offsets[node], end = offsets[node + 1];
    const ushort_t* hb = h2b + lane * 2;
    float2 acc = make_float2(0.f, 0.f);
    int j = beg;
#pragma unroll 2
    for (; j + 4 <= end; j += 4) {
        int s0 = csr_src[j], s1 = csr_src[j + 1], s2 = csr_src[j + 2], s3 = csr_src[j + 3];
        float w0 = alpha[j], w1 = alpha[j + 1], w2 = alpha[j + 2], w3 = alpha[j + 3];
        unsigned u0 = *(const unsigned*)&hb[(size_t)s0 * 128];
        unsigned u1 = *(const unsigned*)&hb[(size_t)s1 * 128];
        unsigned u2 = *(const unsigned*)&hb[(size_t)s2 * 128];
        unsigned u3 = *(const unsigned*)&hb[(size_t)s3 * 128];
        float2 f0 = unpack_bf2(u0), f1 = unpack_bf2(u1);
        float2 f2 = unpack_bf2(u2), f3 = unpack_bf2(u3);
        acc.x += w0 * f0.x + w1 * f1.x + w2 * f2.x + w3 * f3.x;
        acc.y += w0 * f0.y + w1 * f1.y + w2 * f2.y + w3 * f3.y;
    }
    for (; j < end; ++j) {
        int s0 = csr_src[j];
        float w0 = alpha[j];
        float2 f0 = unpack_bf2(*(const unsigned*)&hb[(size_t)s0 * 128]);
        acc.x += w0 * f0.x;
        acc.y += w0 * f0.y;
    }
    float2 o = make_float2(acc.x + bias[lane * 2], acc.y + bias[lane * 2 + 1]);
    *(float2*)&out[(size_t)node * 128 + lane * 2] = o;
}

// ---------------------------------------------------------------- launch
extern "C" void kernel_launch(void* const* d_in, const int* in_sizes, int n_in,
                              void* d_out, int out_size, void* d_ws, size_t ws_size,
                              hipStream_t stream) {
    const float* x      = (const float*)d_in[0];
    const int*   ei     = (const int*)  d_in[1];
    const float* sent   = (const float*)d_in[2];
    const float* W1     = (const float*)d_in[3];
    const float* a1_src = (const float*)d_in[4];
    const float* a1_dst = (const float*)d_in[5];
    const float* b1     = (const float*)d_in[6];
    const float* W2     = (const float*)d_in[7];
    const float* a2_src = (const float*)d_in[8];
    const float* a2_dst = (const float*)d_in[9];
    const float* b2     = (const float*)d_in[10];
    float* out = (float*)d_out;

    const int N = in_sizes[0] / 768;   // 20000
    const int E = in_sizes[1] / 2;     // 320000

    char* p = (char*)d_ws;
    auto carve = [&](size_t bytes) {
        char* q = p;
        p += (bytes + 255) & ~(size_t)255;
        return q;
    };
    ushort_t* h1b = (ushort_t*)carve((size_t)N * 512 * 2);
    char* shared_region = carve((size_t)N * 768 * 2);   // x_bf16 dead after GEMM1
    ushort_t* x_bf16 = (ushort_t*)shared_region;
    ushort_t* h_elu_b = (ushort_t*)shared_region;
    ushort_t* h2b = (ushort_t*)carve((size_t)N * 128 * 2);
    ushort_t* W1T = (ushort_t*)carve((size_t)512 * 768 * 2);
    ushort_t* W2T = (ushort_t*)carve((size_t)128 * 512 * 2);
    float* svec   = (float*)carve(512 * 4);
    float* e_src1 = (float*)carve((size_t)N * 4 * 4);
    float* e_dst1 = (float*)carve((size_t)N * 4 * 4);
    float* e_src2 = (float*)carve((size_t)N * 4);
    float* e_dst2 = (float*)carve((size_t)N * 4);
    float* alpha1 = (float*)carve((size_t)E * 4 * 4);   // head-major [4][E]
    float* alpha2 = (float*)carve((size_t)E * 4);
    int*   indeg  = (int*)carve((size_t)N * 4);
    int*   offs   = (int*)carve((size_t)(N + 1) * 4);
    int*   cursor = (int*)carve((size_t)N * 4);
    int*   csrsrc = (int*)carve((size_t)E * 4);

    // CSR build
    zero_int_kernel<<<(N + 255) / 256, 256, 0, stream>>>(indeg, N);
    count_kernel<<<(E + 255) / 256, 256, 0, stream>>>(ei, indeg, E);
    scan_kernel<<<1, 1024, 0, stream>>>(indeg, offs, cursor, N);
    scatter_kernel<<<(E + 255) / 256, 256, 0, stream>>>(ei, cursor, csrsrc, E);

    // bf16 casts
    size_t nx = (size_t)N * 768;
    cast_bf16_kernel<<<(int)((nx / 8 + 255) / 256), 256, 0, stream>>>(x, x_bf16, nx);
    transpose_cast_kernel<<<dim3(24, 16), 256, 0, stream>>>(W1, W1T, 768, 512);
    transpose_cast_kernel<<<dim3(16, 4), 256, 0, stream>>>(W2, W2T, 512, 128);
    svec_kernel<<<2, 256, 0, stream>>>(sent, W1, svec);

    // GEMM1: h1b = bf16(x @ W1[:768] + svec)   [N,512]
    mfma_gemm_kernel<<<dim3((N + 127) / 128, 4), 256, 0, stream>>>(
        x_bf16, W1T, svec, h1b, N, 768, 512);

    // layer-1 attention
    e1_kernel<<<(N + 3) / 4, 256, 0, stream>>>(h1b, a1_src, a1_dst, e_src1, e_dst1, N);
    alpha1_kernel<<<(N + 3) / 4, 256, 0, stream>>>(e_src1, e_dst1, offs, csrsrc, alpha1, N, E);
    gather1_kernel<<<dim3((N + 3) / 4, 4), 256, 0, stream>>>(
        h1b, alpha1, offs, csrsrc, b1, h_elu_b, N, E);

    // GEMM2: h2b = bf16(h_elu @ W2)   [N,128]
    mfma_gemm_kernel<<<dim3((N + 127) / 128, 1), 256, 0, stream>>>(
        h_elu_b, W2T, nullptr, h2b, N, 512, 128);

    // layer-2 attention
    e2_kernel<<<(N + 3) / 4, 256, 0, stream>>>(h2b, a2_src, a2_dst, e_src2, e_dst2, N);
    alpha2_kernel<<<(N + 3) / 4, 256, 0, stream>>>(e_src2, e_dst2, offs, csrsrc, alpha2, N);
    gather2_kernel<<<(N + 3) / 4, 256, 0, stream>>>(h2b, alpha2, offs, csrsrc, b2, out, N);
}

// Round 5
// 383.666 us; speedup vs baseline: 2.0104x; 1.0221x over previous
//
#include <hip/hip_runtime.h>
#include <cstdint>
#include <cstddef>

#define NSLOPE 0.2f

typedef __attribute__((ext_vector_type(8))) short bf16x8;
typedef __attribute__((ext_vector_type(4))) float f32x4;
typedef unsigned short ushort_t;

// ---------------------------------------------------------------- utilities
__global__ void zero_int_kernel(int* __restrict__ p, int n) {
    int i = blockIdx.x * blockDim.x + threadIdx.x;
    if (i < n) p[i] = 0;
}

__device__ inline ushort_t f2bf(float f) {
    union { float f; unsigned u; } v; v.f = f;
    unsigned u = v.u;
    unsigned r = (u + 0x7fffu + ((u >> 16) & 1u)) >> 16;   // RNE
    return (ushort_t)r;
}
__device__ inline float bf2f(ushort_t u) {
    union { unsigned u; float f; } v; v.u = ((unsigned)u) << 16;
    return v.f;
}
__device__ inline float2 unpack_bf2(unsigned u) {
    return make_float2(bf2f((ushort_t)(u & 0xffffu)), bf2f((ushort_t)(u >> 16)));
}
__device__ inline void fma_bf8(float acc[8], uint4 u, float w) {
    float2 f;
    f = unpack_bf2(u.x); acc[0] += w * f.x; acc[1] += w * f.y;
    f = unpack_bf2(u.y); acc[2] += w * f.x; acc[3] += w * f.y;
    f = unpack_bf2(u.z); acc[4] += w * f.x; acc[5] += w * f.y;
    f = unpack_bf2(u.w); acc[6] += w * f.x; acc[7] += w * f.y;
}

// fp32 -> bf16 flat cast (n divisible by 8)
__global__ void cast_bf16_kernel(const float* __restrict__ in,
                                 ushort_t* __restrict__ out, size_t n) {
    size_t i = ((size_t)blockIdx.x * blockDim.x + threadIdx.x) * 8;
    if (i >= n) return;
    float4 v0 = *(const float4*)(in + i);
    float4 v1 = *(const float4*)(in + i + 4);
    ushort_t r[8] = { f2bf(v0.x), f2bf(v0.y), f2bf(v0.z), f2bf(v0.w),
                      f2bf(v1.x), f2bf(v1.y), f2bf(v1.z), f2bf(v1.w) };
    *(uint4*)(out + i) = *(uint4*)r;
}

// W[R][C] fp32 (ld=C) -> WT[C][R] bf16. grid (R/32, C/32), 256 thr.
__global__ __launch_bounds__(256) void transpose_cast_kernel(
    const float* __restrict__ W, ushort_t* __restrict__ WT, int R, int C) {
    __shared__ float tile[32][33];
    int k0 = blockIdx.x * 32;
    int n0 = blockIdx.y * 32;
    int tx = threadIdx.x & 31;
    int ty = threadIdx.x >> 5;
#pragma unroll
    for (int i = 0; i < 4; ++i)
        tile[ty + i * 8][tx] = W[(size_t)(k0 + ty + i * 8) * C + n0 + tx];
    __syncthreads();
#pragma unroll
    for (int i = 0; i < 4; ++i)
        WT[(size_t)(n0 + ty + i * 8) * R + k0 + tx] = f2bf(tile[tx][ty + i * 8]);
}

// s_vec[c] = sum_k sent[k] * W1[768+k][c]
__global__ void svec_kernel(const float* __restrict__ sent,
                            const float* __restrict__ W1,
                            float* __restrict__ svec) {
    int c = blockIdx.x * blockDim.x + threadIdx.x;
    if (c >= 512) return;
    float acc = 0.f;
    for (int k = 0; k < 768; ++k)
        acc += sent[k] * W1[(size_t)(768 + k) * 512 + c];
    svec[c] = acc;
}

// ---------------------------------------------------------------- MFMA GEMM
__device__ inline void async_copy16(const void* g, void* l) {
    __builtin_amdgcn_global_load_lds(
        (const __attribute__((address_space(1))) unsigned int*)g,
        (__attribute__((address_space(3))) unsigned int*)l, 16, 0, 0);
}

__global__ __launch_bounds__(256) void mfma_gemm_kernel(
    const ushort_t* __restrict__ A,   // [M][K] bf16
    const ushort_t* __restrict__ BT,  // [Nc][K] bf16
    const float* __restrict__ bias,   // [Nc] or null
    ushort_t* __restrict__ Cb,        // [M][Nc] bf16
    int M, int K, int Nc)
{
    __shared__ __align__(16) ushort_t lA[128 * 32];
    __shared__ __align__(16) ushort_t lB[128 * 32];
    const int tid = threadIdx.x;
    const int wave = tid >> 6;
    const int lane = tid & 63;
    const int row0 = blockIdx.x * 128;
    const int col0 = blockIdx.y * 128;
    const int wm = (wave & 1) * 64;
    const int wn = (wave >> 1) * 64;
    const int q = lane >> 4;
    const int ml = lane & 15;

    f32x4 acc[4][4] = {};

    int rowS[2], gS[2];
#pragma unroll
    for (int i = 0; i < 2; ++i) {
        int p = wave * 128 + i * 64 + lane;
        int r = p >> 2, s = p & 3;
        rowS[i] = r;
        gS[i] = s ^ ((r >> 1) & 3);
    }

    for (int k0 = 0; k0 < K; k0 += 32) {
#pragma unroll
        for (int i = 0; i < 2; ++i) {
            int pb = wave * 128 + i * 64;
            int r = rowS[i];
            int ga = min(row0 + r, M - 1);
            async_copy16(A + (size_t)ga * K + k0 + gS[i] * 8, &lA[(size_t)pb * 8]);
            async_copy16(BT + (size_t)(col0 + r) * K + k0 + gS[i] * 8, &lB[(size_t)pb * 8]);
        }
        __syncthreads();
        bf16x8 af[4], bfr[4];
#pragma unroll
        for (int t = 0; t < 4; ++t) {
            int m = wm + t * 16 + ml;
            af[t] = *(const bf16x8*)&lA[(size_t)(m * 4 + (q ^ ((m >> 1) & 3))) * 8];
            int n = wn + t * 16 + ml;
            bfr[t] = *(const bf16x8*)&lB[(size_t)(n * 4 + (q ^ ((n >> 1) & 3))) * 8];
        }
#pragma unroll
        for (int tm = 0; tm < 4; ++tm)
#pragma unroll
            for (int tn = 0; tn < 4; ++tn)
                acc[tm][tn] = __builtin_amdgcn_mfma_f32_16x16x32_bf16(
                    af[tm], bfr[tn], acc[tm][tn], 0, 0, 0);
        __syncthreads();
    }
#pragma unroll
    for (int tm = 0; tm < 4; ++tm) {
        int rbase = row0 + wm + tm * 16 + q * 4;
#pragma unroll
        for (int tn = 0; tn < 4; ++tn) {
            int col = col0 + wn + tn * 16 + ml;
            float bb = bias ? bias[col] : 0.f;
#pragma unroll
            for (int r = 0; r < 4; ++r) {
                int row = rbase + r;
                if (row < M)
                    Cb[(size_t)row * Nc + col] = f2bf(acc[tm][tn][r] + bb);
            }
        }
    }
}

// ---------------------------------------------------------------- CSR build
__global__ void count_kernel(const int* __restrict__ ei, int* __restrict__ indeg, int E) {
    int e = blockIdx.x * blockDim.x + threadIdx.x;
    if (e < E) atomicAdd(&indeg[ei[E + e]], 1);
}

__global__ __launch_bounds__(1024) void scan_kernel(const int* __restrict__ indeg,
                                                    int* __restrict__ offsets,
                                                    int* __restrict__ cursor, int N) {
    __shared__ int partial[1024];
    int tid = threadIdx.x;
    int per = (N + 1023) / 1024;
    int start = tid * per;
    int end = min(start + per, N);
    int sum = 0;
    for (int i = start; i < end; ++i) sum += indeg[i];
    partial[tid] = sum;
    __syncthreads();
    for (int st = 1; st < 1024; st <<= 1) {
        int v = (tid >= st) ? partial[tid - st] : 0;
        __syncthreads();
        partial[tid] += v;
        __syncthreads();
    }
    int run = (tid == 0) ? 0 : partial[tid - 1];
    for (int i = start; i < end; ++i) {
        offsets[i] = run; cursor[i] = run;
        run += indeg[i];
    }
    if (tid == 1023) offsets[N] = run;
}

__global__ void scatter_kernel(const int* __restrict__ ei, int* __restrict__ cursor,
                               int* __restrict__ csr_src, int E) {
    int e = blockIdx.x * blockDim.x + threadIdx.x;
    if (e < E) {
        int d = ei[E + e];
        int p = atomicAdd(&cursor[d], 1);
        csr_src[p] = ei[e];
    }
}

// ---------------------------------------------------------------- e_src/e_dst
__global__ __launch_bounds__(256) void e1_kernel(
    const ushort_t* __restrict__ h1b,
    const float* __restrict__ a_src, const float* __restrict__ a_dst,
    float* __restrict__ e_src, float* __restrict__ e_dst, int N) {
    int node = blockIdx.x * 4 + (threadIdx.x >> 6);
    int lane = threadIdx.x & 63;
    if (node >= N) return;
    float vs[4], vd[4];
#pragma unroll
    for (int h = 0; h < 4; ++h) {
        unsigned u = *(const unsigned*)&h1b[(size_t)node * 512 + h * 128 + lane * 2];
        float2 f = unpack_bf2(u);
        float as0 = a_src[h * 128 + lane * 2], as1 = a_src[h * 128 + lane * 2 + 1];
        float ad0 = a_dst[h * 128 + lane * 2], ad1 = a_dst[h * 128 + lane * 2 + 1];
        vs[h] = f.x * as0 + f.y * as1;
        vd[h] = f.x * ad0 + f.y * ad1;
    }
#pragma unroll
    for (int st = 32; st >= 1; st >>= 1) {
#pragma unroll
        for (int h = 0; h < 4; ++h) {
            vs[h] += __shfl_xor(vs[h], st);
            vd[h] += __shfl_xor(vd[h], st);
        }
    }
    if (lane == 0) {
        *(float4*)&e_src[node * 4] = make_float4(vs[0], vs[1], vs[2], vs[3]);
        *(float4*)&e_dst[node * 4] = make_float4(vd[0], vd[1], vd[2], vd[3]);
    }
}

__global__ __launch_bounds__(256) void e2_kernel(
    const ushort_t* __restrict__ h2b,
    const float* __restrict__ a_src, const float* __restrict__ a_dst,
    float* __restrict__ e_src, float* __restrict__ e_dst, int N) {
    int node = blockIdx.x * 4 + (threadIdx.x >> 6);
    int lane = threadIdx.x & 63;
    if (node >= N) return;
    unsigned u = *(const unsigned*)&h2b[(size_t)node * 128 + lane * 2];
    float2 f = unpack_bf2(u);
    float vs = f.x * a_src[lane * 2] + f.y * a_src[lane * 2 + 1];
    float vd = f.x * a_dst[lane * 2] + f.y * a_dst[lane * 2 + 1];
#pragma unroll
    for (int st = 32; st >= 1; st >>= 1) {
        vs += __shfl_xor(vs, st);
        vd += __shfl_xor(vd, st);
    }
    if (lane == 0) { e_src[node] = vs; e_dst[node] = vd; }
}

// ---------------------------------------------------------------- alpha (softmax)
// layer 1: wave per node; writes normalized alpha HEAD-MAJOR [4][E].
__global__ __launch_bounds__(256) void alpha1_kernel(
    const float* __restrict__ e_src, const float* __restrict__ e_dst,
    const int* __restrict__ offsets, const int* __restrict__ csr_src,
    float* __restrict__ alpha, int N, int E) {
    int node = blockIdx.x * 4 + (threadIdx.x >> 6);
    int lane = threadIdx.x & 63;
    if (node >= N) return;
    int beg = offsets[node], end = offsets[node + 1];
    if (beg == end) return;
    float4 ed = *(const float4*)&e_dst[node * 4];
    float m[4] = { -1e30f, -1e30f, -1e30f, -1e30f };
    for (int base = beg; base < end; base += 64) {
        float e[4] = { -1e30f, -1e30f, -1e30f, -1e30f };
        if (base + lane < end) {
            int sid = csr_src[base + lane];
            float4 es = *(const float4*)&e_src[sid * 4];
            float v0 = es.x + ed.x, v1 = es.y + ed.y, v2 = es.z + ed.z, v3 = es.w + ed.w;
            e[0] = (v0 > 0.f) ? v0 : NSLOPE * v0;
            e[1] = (v1 > 0.f) ? v1 : NSLOPE * v1;
            e[2] = (v2 > 0.f) ? v2 : NSLOPE * v2;
            e[3] = (v3 > 0.f) ? v3 : NSLOPE * v3;
        }
#pragma unroll
        for (int st = 32; st >= 1; st >>= 1)
#pragma unroll
            for (int h = 0; h < 4; ++h)
                e[h] = fmaxf(e[h], __shfl_xor(e[h], st));
#pragma unroll
        for (int h = 0; h < 4; ++h) m[h] = fmaxf(m[h], e[h]);
    }
    float s[4] = { 0.f, 0.f, 0.f, 0.f };
    for (int base = beg; base < end; base += 64) {
        float w[4] = { 0.f, 0.f, 0.f, 0.f };
        if (base + lane < end) {
            int sid = csr_src[base + lane];
            float4 es = *(const float4*)&e_src[sid * 4];
            float v0 = es.x + ed.x, v1 = es.y + ed.y, v2 = es.z + ed.z, v3 = es.w + ed.w;
            w[0] = __expf(((v0 > 0.f) ? v0 : NSLOPE * v0) - m[0]);
            w[1] = __expf(((v1 > 0.f) ? v1 : NSLOPE * v1) - m[1]);
            w[2] = __expf(((v2 > 0.f) ? v2 : NSLOPE * v2) - m[2]);
            w[3] = __expf(((v3 > 0.f) ? v3 : NSLOPE * v3) - m[3]);
        }
#pragma unroll
        for (int st = 32; st >= 1; st >>= 1)
#pragma unroll
            for (int h = 0; h < 4; ++h)
                w[h] += __shfl_xor(w[h], st);
#pragma unroll
        for (int h = 0; h < 4; ++h) s[h] += w[h];
    }
    float r[4];
#pragma unroll
    for (int h = 0; h < 4; ++h) r[h] = 1.f / (s[h] + 1e-16f);
    for (int base = beg; base < end; base += 64) {
        if (base + lane < end) {
            int j = base + lane;
            int sid = csr_src[j];
            float4 es = *(const float4*)&e_src[sid * 4];
            float v0 = es.x + ed.x, v1 = es.y + ed.y, v2 = es.z + ed.z, v3 = es.w + ed.w;
            alpha[0 * (size_t)E + j] = __expf(((v0 > 0.f) ? v0 : NSLOPE * v0) - m[0]) * r[0];
            alpha[1 * (size_t)E + j] = __expf(((v1 > 0.f) ? v1 : NSLOPE * v1) - m[1]) * r[1];
            alpha[2 * (size_t)E + j] = __expf(((v2 > 0.f) ? v2 : NSLOPE * v2) - m[2]) * r[2];
            alpha[3 * (size_t)E + j] = __expf(((v3 > 0.f) ? v3 : NSLOPE * v3) - m[3]) * r[3];
        }
    }
}

// layer 2: wave per node; writes normalized alpha [E].
__global__ __launch_bounds__(256) void alpha2_kernel(
    const float* __restrict__ e_src, const float* __restrict__ e_dst,
    const int* __restrict__ offsets, const int* __restrict__ csr_src,
    float* __restrict__ alpha, int N) {
    int node = blockIdx.x * 4 + (threadIdx.x >> 6);
    int lane = threadIdx.x & 63;
    if (node >= N) return;
    int beg = offsets[node], end = offsets[node + 1];
    if (beg == end) return;
    float ed = e_dst[node];
    float m = -1e30f;
    for (int base = beg; base < end; base += 64) {
        float e = -1e30f;
        if (base + lane < end) {
            float v = e_src[csr_src[base + lane]] + ed;
            e = (v > 0.f) ? v : NSLOPE * v;
        }
#pragma unroll
        for (int st = 32; st >= 1; st >>= 1)
            e = fmaxf(e, __shfl_xor(e, st));
        m = fmaxf(m, e);
    }
    float s = 0.f;
    for (int base = beg; base < end; base += 64) {
        float w = 0.f;
        if (base + lane < end) {
            float v = e_src[csr_src[base + lane]] + ed;
            w = __expf(((v > 0.f) ? v : NSLOPE * v) - m);
        }
#pragma unroll
        for (int st = 32; st >= 1; st >>= 1)
            w += __shfl_xor(w, st);
        s += w;
    }
    float rs = 1.f / (s + 1e-16f);
    for (int base = beg; base < end; base += 64) {
        if (base + lane < end) {
            float v = e_src[csr_src[base + lane]] + ed;
            alpha[base + lane] = __expf(((v > 0.f) ? v : NSLOPE * v) - m) * rs;
        }
    }
}

// ---------------------------------------------------------------- gather-agg
// layer 1: wave per (node, head). lane = (edge-group g = lane>>4, channel
// slot cl = lane&15 -> 8 bf16 ch via uint4). 4 edges in flight across groups,
// 2-edge batch per group => up to 8 outstanding 16B loads per wave.
__global__ __launch_bounds__(256) void gather1_kernel(
    const ushort_t* __restrict__ h1b, const float* __restrict__ alpha,
    const int* __restrict__ offsets, const int* __restrict__ csr_src,
    const float* __restrict__ bias, ushort_t* __restrict__ outb, int N, int E)
{
    int node = blockIdx.x * 4 + (threadIdx.x >> 6);
    int h = blockIdx.y;
    int lane = threadIdx.x & 63;
    int g = lane >> 4, cl = lane & 15;
    if (node >= N) return;
    int beg = offsets[node], end = offsets[node + 1];
    const float* al = alpha + (size_t)h * E;
    const ushort_t* hb = h1b + h * 128 + cl * 8;
    float acc[8] = {};
    int j = beg + g;
    for (; j + 4 < end; j += 8) {
        int s0 = csr_src[j], s1 = csr_src[j + 4];
        float w0 = al[j], w1 = al[j + 4];
        uint4 u0 = *(const uint4*)&hb[(size_t)s0 * 512];
        uint4 u1 = *(const uint4*)&hb[(size_t)s1 * 512];
        fma_bf8(acc, u0, w0);
        fma_bf8(acc, u1, w1);
    }
    if (j < end) {
        int s0 = csr_src[j];
        float w0 = al[j];
        uint4 u0 = *(const uint4*)&hb[(size_t)s0 * 512];
        fma_bf8(acc, u0, w0);
    }
#pragma unroll
    for (int i = 0; i < 8; ++i) {
        acc[i] += __shfl_xor(acc[i], 16);
        acc[i] += __shfl_xor(acc[i], 32);
    }
    if (g == 0) {
        int c = h * 128 + cl * 8;
        ushort_t o[8];
#pragma unroll
        for (int i = 0; i < 8; ++i) {
            float r = acc[i] + bias[c + i];
            r = (r > 0.f) ? r : (__expf(r) - 1.f);   // ELU
            o[i] = f2bf(r);
        }
        *(uint4*)&outb[(size_t)node * 512 + c] = *(uint4*)o;
    }
}

// layer 2: wave per node; same group structure; fp32 output.
__global__ __launch_bounds__(256) void gather2_kernel(
    const ushort_t* __restrict__ h2b, const float* __restrict__ alpha,
    const int* __restrict__ offsets, const int* __restrict__ csr_src,
    const float* __restrict__ bias, float* __restrict__ out, int N)
{
    int node = blockIdx.x * 4 + (threadIdx.x >> 6);
    int lane = threadIdx.x & 63;
    int g = lane >> 4, cl = lane & 15;
    if (node >= N) return;
    int beg = offsets[node], end = offsets[node + 1];
    const ushort_t* hb = h2b + cl * 8;
    float acc[8] = {};
    int j = beg + g;
    for (; j + 4 < end; j += 8) {
        int s0 = csr_src[j], s1 = csr_src[j + 4];
        float w0 = alpha[j], w1 = alpha[j + 4];
        uint4 u0 = *(const uint4*)&hb[(size_t)s0 * 128];
        uint4 u1 = *(const uint4*)&hb[(size_t)s1 * 128];
        fma_bf8(acc, u0, w0);
        fma_bf8(acc, u1, w1);
    }
    if (j < end) {
        int s0 = csr_src[j];
        float w0 = alpha[j];
        uint4 u0 = *(const uint4*)&hb[(size_t)s0 * 128];
        fma_bf8(acc, u0, w0);
    }
#pragma unroll
    for (int i = 0; i < 8; ++i) {
        acc[i] += __shfl_xor(acc[i], 16);
        acc[i] += __shfl_xor(acc[i], 32);
    }
    if (g == 0) {
        int c = cl * 8;
        float4 o0, o1;
        o0.x = acc[0] + bias[c + 0]; o0.y = acc[1] + bias[c + 1];
        o0.z = acc[2] + bias[c + 2]; o0.w = acc[3] + bias[c + 3];
        o1.x = acc[4] + bias[c + 4]; o1.y = acc[5] + bias[c + 5];
        o1.z = acc[6] + bias[c + 6]; o1.w = acc[7] + bias[c + 7];
        *(float4*)&out[(size_t)node * 128 + c] = o0;
        *(float4*)&out[(size_t)node * 128 + c + 4] = o1;
    }
}

// ---------------------------------------------------------------- launch
extern "C" void kernel_launch(void* const* d_in, const int* in_sizes, int n_in,
                              void* d_out, int out_size, void* d_ws, size_t ws_size,
                              hipStream_t stream) {
    const float* x      = (const float*)d_in[0];
    const int*   ei     = (const int*)  d_in[1];
    const float* sent   = (const float*)d_in[2];
    const float* W1     = (const float*)d_in[3];
    const float* a1_src = (const float*)d_in[4];
    const float* a1_dst = (const float*)d_in[5];
    const float* b1     = (const float*)d_in[6];
    const float* W2     = (const float*)d_in[7];
    const float* a2_src = (const float*)d_in[8];
    const float* a2_dst = (const float*)d_in[9];
    const float* b2     = (const float*)d_in[10];
    float* out = (float*)d_out;

    const int N = in_sizes[0] / 768;   // 20000
    const int E = in_sizes[1] / 2;     // 320000

    char* p = (char*)d_ws;
    auto carve = [&](size_t bytes) {
        char* q = p;
        p += (bytes + 255) & ~(size_t)255;
        return q;
    };
    ushort_t* h1b = (ushort_t*)carve((size_t)N * 512 * 2);
    char* shared_region = carve((size_t)N * 768 * 2);   // x_bf16 dead after GEMM1
    ushort_t* x_bf16 = (ushort_t*)shared_region;
    ushort_t* h_elu_b = (ushort_t*)shared_region;
    ushort_t* h2b = (ushort_t*)carve((size_t)N * 128 * 2);
    ushort_t* W1T = (ushort_t*)carve((size_t)512 * 768 * 2);
    ushort_t* W2T = (ushort_t*)carve((size_t)128 * 512 * 2);
    float* svec   = (float*)carve(512 * 4);
    float* e_src1 = (float*)carve((size_t)N * 4 * 4);
    float* e_dst1 = (float*)carve((size_t)N * 4 * 4);
    float* e_src2 = (float*)carve((size_t)N * 4);
    float* e_dst2 = (float*)carve((size_t)N * 4);
    float* alpha1 = (float*)carve((size_t)E * 4 * 4);   // head-major [4][E]
    float* alpha2 = (float*)carve((size_t)E * 4);
    int*   indeg  = (int*)carve((size_t)N * 4);
    int*   offs   = (int*)carve((size_t)(N + 1) * 4);
    int*   cursor = (int*)carve((size_t)N * 4);
    int*   csrsrc = (int*)carve((size_t)E * 4);

    // CSR build
    zero_int_kernel<<<(N + 255) / 256, 256, 0, stream>>>(indeg, N);
    count_kernel<<<(E + 255) / 256, 256, 0, stream>>>(ei, indeg, E);
    scan_kernel<<<1, 1024, 0, stream>>>(indeg, offs, cursor, N);
    scatter_kernel<<<(E + 255) / 256, 256, 0, stream>>>(ei, cursor, csrsrc, E);

    // bf16 casts
    size_t nx = (size_t)N * 768;
    cast_bf16_kernel<<<(int)((nx / 8 + 255) / 256), 256, 0, stream>>>(x, x_bf16, nx);
    transpose_cast_kernel<<<dim3(24, 16), 256, 0, stream>>>(W1, W1T, 768, 512);
    transpose_cast_kernel<<<dim3(16, 4), 256, 0, stream>>>(W2, W2T, 512, 128);
    svec_kernel<<<2, 256, 0, stream>>>(sent, W1, svec);

    // GEMM1: h1b = bf16(x @ W1[:768] + svec)   [N,512]
    mfma_gemm_kernel<<<dim3((N + 127) / 128, 4), 256, 0, stream>>>(
        x_bf16, W1T, svec, h1b, N, 768, 512);

    // layer-1 attention
    e1_kernel<<<(N + 3) / 4, 256, 0, stream>>>(h1b, a1_src, a1_dst, e_src1, e_dst1, N);
    alpha1_kernel<<<(N + 3) / 4, 256, 0, stream>>>(e_src1, e_dst1, offs, csrsrc, alpha1, N, E);
    gather1_kernel<<<dim3((N + 3) / 4, 4), 256, 0, stream>>>(
        h1b, alpha1, offs, csrsrc, b1, h_elu_b, N, E);

    // GEMM2: h2b = bf16(h_elu @ W2)   [N,128]
    mfma_gemm_kernel<<<dim3((N + 127) / 128, 1), 256, 0, stream>>>(
        h_elu_b, W2T, nullptr, h2b, N, 512, 128);

    // layer-2 attention
    e2_kernel<<<(N + 3) / 4, 256, 0, stream>>>(h2b, a2_src, a2_dst, e_src2, e_dst2, N);
    alpha2_kernel<<<(N + 3) / 4, 256, 0, stream>>>(e_src2, e_dst2, offs, csrsrc, alpha2, N);
    gather2_kernel<<<(N + 3) / 4, 256, 0, stream>>>(h2b, alpha2, offs, csrsrc, b2, out, N);
}

// Round 6
// 365.042 us; speedup vs baseline: 2.1130x; 1.0510x over previous
//
#include <hip/hip_runtime.h>
#include <cstdint>
#include <cstddef>

#define NSLOPE 0.2f

typedef __attribute__((ext_vector_type(8))) short bf16x8;
typedef __attribute__((ext_vector_type(4))) float f32x4;
typedef __attribute__((ext_vector_type(2))) float f32x2;
typedef unsigned short ushort_t;

// ---------------------------------------------------------------- utilities
__device__ inline ushort_t f2bf(float f) {
    union { float f; unsigned u; } v; v.f = f;
    unsigned u = v.u;
    unsigned r = (u + 0x7fffu + ((u >> 16) & 1u)) >> 16;   // RNE
    return (ushort_t)r;
}
__device__ inline float bf2f(ushort_t u) {
    union { unsigned u; float f; } v; v.u = ((unsigned)u) << 16;
    return v.f;
}
__device__ inline float2 unpack_bf2(unsigned u) {
    return make_float2(bf2f((ushort_t)(u & 0xffffu)), bf2f((ushort_t)(u >> 16)));
}
// optimal 2-op unpack: lo = u<<16, hi = u & 0xffff0000
__device__ inline f32x2 unpack2(unsigned u) {
    union { unsigned u; float f; } lo, hi;
    lo.u = u << 16;
    hi.u = u & 0xffff0000u;
    f32x2 r; r.x = lo.f; r.y = hi.f;
    return r;
}

// ---------------------------------------------------------------- fused prep
// sections: [0,nbCast) cast x->bf16 | [.. +384) transpose W1 | [.. +64)
// transpose W2 | [.. +2) svec | [.. +nbZero) zero indeg
__global__ __launch_bounds__(256) void prep_kernel(
    const float* __restrict__ x, ushort_t* __restrict__ x_bf16, size_t nx,
    const float* __restrict__ W1, ushort_t* __restrict__ W1T,
    const float* __restrict__ W2, ushort_t* __restrict__ W2T,
    const float* __restrict__ sent, float* __restrict__ svec,
    int* __restrict__ indeg, int N, int nbCast, int nbZero)
{
    __shared__ float tile[32][33];
    int bid = blockIdx.x;
    int tid = threadIdx.x;
    if (bid < nbCast) {
        size_t i = ((size_t)bid * 256 + tid) * 8;
        if (i < nx) {
            float4 v0 = *(const float4*)(x + i);
            float4 v1 = *(const float4*)(x + i + 4);
            ushort_t r[8] = { f2bf(v0.x), f2bf(v0.y), f2bf(v0.z), f2bf(v0.w),
                              f2bf(v1.x), f2bf(v1.y), f2bf(v1.z), f2bf(v1.w) };
            *(uint4*)(x_bf16 + i) = *(uint4*)r;
        }
        return;
    }
    bid -= nbCast;
    if (bid < 384) {   // W1[768][512] -> W1T[512][768]
        int k0 = (bid % 24) * 32, n0 = (bid / 24) * 32;
        int tx = tid & 31, ty = tid >> 5;
#pragma unroll
        for (int i = 0; i < 4; ++i)
            tile[ty + i * 8][tx] = W1[(size_t)(k0 + ty + i * 8) * 512 + n0 + tx];
        __syncthreads();
#pragma unroll
        for (int i = 0; i < 4; ++i)
            W1T[(size_t)(n0 + ty + i * 8) * 768 + k0 + tx] = f2bf(tile[tx][ty + i * 8]);
        return;
    }
    bid -= 384;
    if (bid < 64) {    // W2[512][128] -> W2T[128][512]
        int k0 = (bid % 16) * 32, n0 = (bid / 16) * 32;
        int tx = tid & 31, ty = tid >> 5;
#pragma unroll
        for (int i = 0; i < 4; ++i)
            tile[ty + i * 8][tx] = W2[(size_t)(k0 + ty + i * 8) * 128 + n0 + tx];
        __syncthreads();
#pragma unroll
        for (int i = 0; i < 4; ++i)
            W2T[(size_t)(n0 + ty + i * 8) * 512 + k0 + tx] = f2bf(tile[tx][ty + i * 8]);
        return;
    }
    bid -= 64;
    if (bid < 2) {     // svec[c] = sum_k sent[k]*W1[768+k][c]
        int c = bid * 256 + tid;
        if (c < 512) {
            float acc = 0.f;
            for (int k = 0; k < 768; ++k)
                acc += sent[k] * W1[(size_t)(768 + k) * 512 + c];
            svec[c] = acc;
        }
        return;
    }
    bid -= 2;
    {                  // zero indeg
        int i = bid * 256 + tid;
        if (i < N) indeg[i] = 0;
    }
}

// ---------------------------------------------------------------- MFMA GEMM
__device__ inline void async_copy16(const void* g, void* l) {
    __builtin_amdgcn_global_load_lds(
        (const __attribute__((address_space(1))) unsigned int*)g,
        (__attribute__((address_space(3))) unsigned int*)l, 16, 0, 0);
}

__global__ __launch_bounds__(256) void mfma_gemm_kernel(
    const ushort_t* __restrict__ A,   // [M][K] bf16
    const ushort_t* __restrict__ BT,  // [Nc][K] bf16
    const float* __restrict__ bias,   // [Nc] or null
    ushort_t* __restrict__ Cb,        // [M][Nc] bf16
    int M, int K, int Nc)
{
    __shared__ __align__(16) ushort_t lA[128 * 32];
    __shared__ __align__(16) ushort_t lB[128 * 32];
    const int tid = threadIdx.x;
    const int wave = tid >> 6;
    const int lane = tid & 63;
    const int row0 = blockIdx.x * 128;
    const int col0 = blockIdx.y * 128;
    const int wm = (wave & 1) * 64;
    const int wn = (wave >> 1) * 64;
    const int q = lane >> 4;
    const int ml = lane & 15;

    f32x4 acc[4][4] = {};

    int rowS[2], gS[2];
#pragma unroll
    for (int i = 0; i < 2; ++i) {
        int p = wave * 128 + i * 64 + lane;
        int r = p >> 2, s = p & 3;
        rowS[i] = r;
        gS[i] = s ^ ((r >> 1) & 3);
    }

    for (int k0 = 0; k0 < K; k0 += 32) {
#pragma unroll
        for (int i = 0; i < 2; ++i) {
            int pb = wave * 128 + i * 64;
            int r = rowS[i];
            int ga = min(row0 + r, M - 1);
            async_copy16(A + (size_t)ga * K + k0 + gS[i] * 8, &lA[(size_t)pb * 8]);
            async_copy16(BT + (size_t)(col0 + r) * K + k0 + gS[i] * 8, &lB[(size_t)pb * 8]);
        }
        __syncthreads();
        bf16x8 af[4], bfr[4];
#pragma unroll
        for (int t = 0; t < 4; ++t) {
            int m = wm + t * 16 + ml;
            af[t] = *(const bf16x8*)&lA[(size_t)(m * 4 + (q ^ ((m >> 1) & 3))) * 8];
            int n = wn + t * 16 + ml;
            bfr[t] = *(const bf16x8*)&lB[(size_t)(n * 4 + (q ^ ((n >> 1) & 3))) * 8];
        }
#pragma unroll
        for (int tm = 0; tm < 4; ++tm)
#pragma unroll
            for (int tn = 0; tn < 4; ++tn)
                acc[tm][tn] = __builtin_amdgcn_mfma_f32_16x16x32_bf16(
                    af[tm], bfr[tn], acc[tm][tn], 0, 0, 0);
        __syncthreads();
    }
#pragma unroll
    for (int tm = 0; tm < 4; ++tm) {
        int rbase = row0 + wm + tm * 16 + q * 4;
#pragma unroll
        for (int tn = 0; tn < 4; ++tn) {
            int col = col0 + wn + tn * 16 + ml;
            float bb = bias ? bias[col] : 0.f;
#pragma unroll
            for (int r = 0; r < 4; ++r) {
                int row = rbase + r;
                if (row < M)
                    Cb[(size_t)row * Nc + col] = f2bf(acc[tm][tn][r] + bb);
            }
        }
    }
}

// ---------------------------------------------------------------- CSR build
__global__ void count_kernel(const int* __restrict__ ei, int* __restrict__ indeg, int E) {
    int e = blockIdx.x * blockDim.x + threadIdx.x;
    if (e < E) atomicAdd(&indeg[ei[E + e]], 1);
}

__global__ __launch_bounds__(1024) void scan_kernel(const int* __restrict__ indeg,
                                                    int* __restrict__ offsets,
                                                    int* __restrict__ cursor, int N) {
    __shared__ int partial[1024];
    int tid = threadIdx.x;
    int per = (N + 1023) / 1024;
    int start = tid * per;
    int end = min(start + per, N);
    int sum = 0;
    for (int i = start; i < end; ++i) sum += indeg[i];
    partial[tid] = sum;
    __syncthreads();
    for (int st = 1; st < 1024; st <<= 1) {
        int v = (tid >= st) ? partial[tid - st] : 0;
        __syncthreads();
        partial[tid] += v;
        __syncthreads();
    }
    int run = (tid == 0) ? 0 : partial[tid - 1];
    for (int i = start; i < end; ++i) {
        offsets[i] = run; cursor[i] = run;
        run += indeg[i];
    }
    if (tid == 1023) offsets[N] = run;
}

__global__ void scatter_kernel(const int* __restrict__ ei, int* __restrict__ cursor,
                               int* __restrict__ csr_src, int E) {
    int e = blockIdx.x * blockDim.x + threadIdx.x;
    if (e < E) {
        int d = ei[E + e];
        int p = atomicAdd(&cursor[d], 1);
        csr_src[p] = ei[e];
    }
}

// ---------------------------------------------------------------- e_src/e_dst
__global__ __launch_bounds__(256) void e1_kernel(
    const ushort_t* __restrict__ h1b,
    const float* __restrict__ a_src, const float* __restrict__ a_dst,
    float* __restrict__ e_src, float* __restrict__ e_dst, int N) {
    int node = __builtin_amdgcn_readfirstlane(blockIdx.x * 4 + (threadIdx.x >> 6));
    int lane = threadIdx.x & 63;
    if (node >= N) return;
    float vs[4], vd[4];
#pragma unroll
    for (int h = 0; h < 4; ++h) {
        unsigned u = *(const unsigned*)&h1b[(size_t)node * 512 + h * 128 + lane * 2];
        float2 f = unpack_bf2(u);
        float as0 = a_src[h * 128 + lane * 2], as1 = a_src[h * 128 + lane * 2 + 1];
        float ad0 = a_dst[h * 128 + lane * 2], ad1 = a_dst[h * 128 + lane * 2 + 1];
        vs[h] = f.x * as0 + f.y * as1;
        vd[h] = f.x * ad0 + f.y * ad1;
    }
#pragma unroll
    for (int st = 32; st >= 1; st >>= 1) {
#pragma unroll
        for (int h = 0; h < 4; ++h) {
            vs[h] += __shfl_xor(vs[h], st);
            vd[h] += __shfl_xor(vd[h], st);
        }
    }
    if (lane == 0) {
        *(float4*)&e_src[node * 4] = make_float4(vs[0], vs[1], vs[2], vs[3]);
        *(float4*)&e_dst[node * 4] = make_float4(vd[0], vd[1], vd[2], vd[3]);
    }
}

__global__ __launch_bounds__(256) void e2_kernel(
    const ushort_t* __restrict__ h2b,
    const float* __restrict__ a_src, const float* __restrict__ a_dst,
    float* __restrict__ e_src, float* __restrict__ e_dst, int N) {
    int node = __builtin_amdgcn_readfirstlane(blockIdx.x * 4 + (threadIdx.x >> 6));
    int lane = threadIdx.x & 63;
    if (node >= N) return;
    unsigned u = *(const unsigned*)&h2b[(size_t)node * 128 + lane * 2];
    float2 f = unpack_bf2(u);
    float vs = f.x * a_src[lane * 2] + f.y * a_src[lane * 2 + 1];
    float vd = f.x * a_dst[lane * 2] + f.y * a_dst[lane * 2 + 1];
#pragma unroll
    for (int st = 32; st >= 1; st >>= 1) {
        vs += __shfl_xor(vs, st);
        vd += __shfl_xor(vd, st);
    }
    if (lane == 0) { e_src[node] = vs; e_dst[node] = vd; }
}

// ---------------------------------------------------------------- alpha (softmax)
// layer 1: wave per node; writes normalized alpha EDGE-MAJOR [E] float4.
__global__ __launch_bounds__(256) void alpha1_kernel(
    const float* __restrict__ e_src, const float* __restrict__ e_dst,
    const int* __restrict__ offsets, const int* __restrict__ csr_src,
    float4* __restrict__ alpha, int N) {
    int node = __builtin_amdgcn_readfirstlane(blockIdx.x * 4 + (threadIdx.x >> 6));
    int lane = threadIdx.x & 63;
    if (node >= N) return;
    int beg = offsets[node], end = offsets[node + 1];
    if (beg == end) return;
    float4 ed = *(const float4*)&e_dst[node * 4];
    float m[4] = { -1e30f, -1e30f, -1e30f, -1e30f };
    for (int base = beg; base < end; base += 64) {
        float e[4] = { -1e30f, -1e30f, -1e30f, -1e30f };
        if (base + lane < end) {
            int sid = csr_src[base + lane];
            float4 es = *(const float4*)&e_src[sid * 4];
            float v0 = es.x + ed.x, v1 = es.y + ed.y, v2 = es.z + ed.z, v3 = es.w + ed.w;
            e[0] = (v0 > 0.f) ? v0 : NSLOPE * v0;
            e[1] = (v1 > 0.f) ? v1 : NSLOPE * v1;
            e[2] = (v2 > 0.f) ? v2 : NSLOPE * v2;
            e[3] = (v3 > 0.f) ? v3 : NSLOPE * v3;
        }
#pragma unroll
        for (int st = 32; st >= 1; st >>= 1)
#pragma unroll
            for (int h = 0; h < 4; ++h)
                e[h] = fmaxf(e[h], __shfl_xor(e[h], st));
#pragma unroll
        for (int h = 0; h < 4; ++h) m[h] = fmaxf(m[h], e[h]);
    }
    float s[4] = { 0.f, 0.f, 0.f, 0.f };
    for (int base = beg; base < end; base += 64) {
        float w[4] = { 0.f, 0.f, 0.f, 0.f };
        if (base + lane < end) {
            int sid = csr_src[base + lane];
            float4 es = *(const float4*)&e_src[sid * 4];
            float v0 = es.x + ed.x, v1 = es.y + ed.y, v2 = es.z + ed.z, v3 = es.w + ed.w;
            w[0] = __expf(((v0 > 0.f) ? v0 : NSLOPE * v0) - m[0]);
            w[1] = __expf(((v1 > 0.f) ? v1 : NSLOPE * v1) - m[1]);
            w[2] = __expf(((v2 > 0.f) ? v2 : NSLOPE * v2) - m[2]);
            w[3] = __expf(((v3 > 0.f) ? v3 : NSLOPE * v3) - m[3]);
        }
#pragma unroll
        for (int st = 32; st >= 1; st >>= 1)
#pragma unroll
            for (int h = 0; h < 4; ++h)
                w[h] += __shfl_xor(w[h], st);
#pragma unroll
        for (int h = 0; h < 4; ++h) s[h] += w[h];
    }
    float r[4];
#pragma unroll
    for (int h = 0; h < 4; ++h) r[h] = 1.f / (s[h] + 1e-16f);
    for (int base = beg; base < end; base += 64) {
        if (base + lane < end) {
            int j = base + lane;
            int sid = csr_src[j];
            float4 es = *(const float4*)&e_src[sid * 4];
            float v0 = es.x + ed.x, v1 = es.y + ed.y, v2 = es.z + ed.z, v3 = es.w + ed.w;
            float4 a;
            a.x = __expf(((v0 > 0.f) ? v0 : NSLOPE * v0) - m[0]) * r[0];
            a.y = __expf(((v1 > 0.f) ? v1 : NSLOPE * v1) - m[1]) * r[1];
            a.z = __expf(((v2 > 0.f) ? v2 : NSLOPE * v2) - m[2]) * r[2];
            a.w = __expf(((v3 > 0.f) ? v3 : NSLOPE * v3) - m[3]) * r[3];
            alpha[j] = a;
        }
    }
}

__global__ __launch_bounds__(256) void alpha2_kernel(
    const float* __restrict__ e_src, const float* __restrict__ e_dst,
    const int* __restrict__ offsets, const int* __restrict__ csr_src,
    float* __restrict__ alpha, int N) {
    int node = __builtin_amdgcn_readfirstlane(blockIdx.x * 4 + (threadIdx.x >> 6));
    int lane = threadIdx.x & 63;
    if (node >= N) return;
    int beg = offsets[node], end = offsets[node + 1];
    if (beg == end) return;
    float ed = e_dst[node];
    float m = -1e30f;
    for (int base = beg; base < end; base += 64) {
        float e = -1e30f;
        if (base + lane < end) {
            float v = e_src[csr_src[base + lane]] + ed;
            e = (v > 0.f) ? v : NSLOPE * v;
        }
#pragma unroll
        for (int st = 32; st >= 1; st >>= 1)
            e = fmaxf(e, __shfl_xor(e, st));
        m = fmaxf(m, e);
    }
    float s = 0.f;
    for (int base = beg; base < end; base += 64) {
        float w = 0.f;
        if (base + lane < end) {
            float v = e_src[csr_src[base + lane]] + ed;
            w = __expf(((v > 0.f) ? v : NSLOPE * v) - m);
        }
#pragma unroll
        for (int st = 32; st >= 1; st >>= 1)
            w += __shfl_xor(w, st);
        s += w;
    }
    float rs = 1.f / (s + 1e-16f);
    for (int base = beg; base < end; base += 64) {
        if (base + lane < end) {
            float v = e_src[csr_src[base + lane]] + ed;
            alpha[base + lane] = __expf(((v > 0.f) ? v : NSLOPE * v) - m) * rs;
        }
    }
}

// ---------------------------------------------------------------- gather-agg
// layer 1: wave per node; lane owns 8 contiguous channels (64x16B = full 1KB
// row). Edge loop is wave-uniform: csr/alpha via scalar loads; per-lane head
// alpha via 3 hoisted cndmasks. acc in f32x2 for packed FMA.
__global__ __launch_bounds__(256) void gather1_kernel(
    const ushort_t* __restrict__ h1b, const float4* __restrict__ alpha,
    const int* __restrict__ offsets, const int* __restrict__ csr_src,
    const float* __restrict__ bias, ushort_t* __restrict__ outb, int N)
{
    int node = __builtin_amdgcn_readfirstlane(blockIdx.x * 4 + (threadIdx.x >> 6));
    int lane = threadIdx.x & 63;
    if (node >= N) return;
    int beg = offsets[node], end = offsets[node + 1];
    const int h = lane >> 4;                    // head of this lane's channels
    const bool hb1 = (h & 1), hb2 = (h & 2);
    const ushort_t* hp = h1b + lane * 8;
    f32x2 acc[4] = {};

    int j = beg;
#pragma unroll 2
    for (; j + 2 <= end; j += 2) {
        int s0 = csr_src[j], s1 = csr_src[j + 1];          // scalar
        float4 a0 = alpha[j], a1 = alpha[j + 1];           // scalar
        float w0 = hb2 ? (hb1 ? a0.w : a0.z) : (hb1 ? a0.y : a0.x);
        float w1 = hb2 ? (hb1 ? a1.w : a1.z) : (hb1 ? a1.y : a1.x);
        uint4 u0 = *(const uint4*)&hp[(size_t)s0 * 512];
        uint4 u1 = *(const uint4*)&hp[(size_t)s1 * 512];
        f32x2 w0v = { w0, w0 }, w1v = { w1, w1 };
        acc[0] += unpack2(u0.x) * w0v; acc[1] += unpack2(u0.y) * w0v;
        acc[2] += unpack2(u0.z) * w0v; acc[3] += unpack2(u0.w) * w0v;
        acc[0] += unpack2(u1.x) * w1v; acc[1] += unpack2(u1.y) * w1v;
        acc[2] += unpack2(u1.z) * w1v; acc[3] += unpack2(u1.w) * w1v;
    }
    if (j < end) {
        int s0 = csr_src[j];
        float4 a0 = alpha[j];
        float w0 = hb2 ? (hb1 ? a0.w : a0.z) : (hb1 ? a0.y : a0.x);
        uint4 u0 = *(const uint4*)&hp[(size_t)s0 * 512];
        f32x2 w0v = { w0, w0 };
        acc[0] += unpack2(u0.x) * w0v; acc[1] += unpack2(u0.y) * w0v;
        acc[2] += unpack2(u0.z) * w0v; acc[3] += unpack2(u0.w) * w0v;
    }
    int c = lane * 8;
    ushort_t o[8];
#pragma unroll
    for (int i = 0; i < 4; ++i) {
        float r0 = acc[i].x + bias[c + 2 * i];
        float r1 = acc[i].y + bias[c + 2 * i + 1];
        r0 = (r0 > 0.f) ? r0 : (__expf(r0) - 1.f);
        r1 = (r1 > 0.f) ? r1 : (__expf(r1) - 1.f);
        o[2 * i] = f2bf(r0);
        o[2 * i + 1] = f2bf(r1);
    }
    *(uint4*)&outb[(size_t)node * 512 + c] = *(uint4*)o;
}

// layer 2: wave per node; lane owns 2 channels (64x4B = full 256B row);
// alpha & csr scalar. fp32 output.
__global__ __launch_bounds__(256) void gather2_kernel(
    const ushort_t* __restrict__ h2b, const float* __restrict__ alpha,
    const int* __restrict__ offsets, const int* __restrict__ csr_src,
    const float* __restrict__ bias, float* __restrict__ out, int N)
{
    int node = __builtin_amdgcn_readfirstlane(blockIdx.x * 4 + (threadIdx.x >> 6));
    int lane = threadIdx.x & 63;
    if (node >= N) return;
    int beg = offsets[node], end = offsets[node + 1];
    const ushort_t* hp = h2b + lane * 2;
    f32x2 acc = { 0.f, 0.f };
    int j = beg;
#pragma unroll 2
    for (; j + 4 <= end; j += 4) {
        int s0 = csr_src[j], s1 = csr_src[j + 1];
        int s2 = csr_src[j + 2], s3 = csr_src[j + 3];
        float w0 = alpha[j], w1 = alpha[j + 1], w2 = alpha[j + 2], w3 = alpha[j + 3];
        unsigned u0 = *(const unsigned*)&hp[(size_t)s0 * 128];
        unsigned u1 = *(const unsigned*)&hp[(size_t)s1 * 128];
        unsigned u2 = *(const unsigned*)&hp[(size_t)s2 * 128];
        unsigned u3 = *(const unsigned*)&hp[(size_t)s3 * 128];
        f32x2 w0v = { w0, w0 }, w1v = { w1, w1 }, w2v = { w2, w2 }, w3v = { w3, w3 };
        acc += unpack2(u0) * w0v;
        acc += unpack2(u1) * w1v;
        acc += unpack2(u2) * w2v;
        acc += unpack2(u3) * w3v;
    }
    for (; j < end; ++j) {
        int s0 = csr_src[j];
        float w0 = alpha[j];
        unsigned u0 = *(const unsigned*)&hp[(size_t)s0 * 128];
        f32x2 w0v = { w0, w0 };
        acc += unpack2(u0) * w0v;
    }
    float2 o = make_float2(acc.x + bias[lane * 2], acc.y + bias[lane * 2 + 1]);
    *(float2*)&out[(size_t)node * 128 + lane * 2] = o;
}

// ---------------------------------------------------------------- launch
extern "C" void kernel_launch(void* const* d_in, const int* in_sizes, int n_in,
                              void* d_out, int out_size, void* d_ws, size_t ws_size,
                              hipStream_t stream) {
    const float* x      = (const float*)d_in[0];
    const int*   ei     = (const int*)  d_in[1];
    const float* sent   = (const float*)d_in[2];
    const float* W1     = (const float*)d_in[3];
    const float* a1_src = (const float*)d_in[4];
    const float* a1_dst = (const float*)d_in[5];
    const float* b1     = (const float*)d_in[6];
    const float* W2     = (const float*)d_in[7];
    const float* a2_src = (const float*)d_in[8];
    const float* a2_dst = (const float*)d_in[9];
    const float* b2     = (const float*)d_in[10];
    float* out = (float*)d_out;

    const int N = in_sizes[0] / 768;   // 20000
    const int E = in_sizes[1] / 2;     // 320000

    char* p = (char*)d_ws;
    auto carve = [&](size_t bytes) {
        char* q = p;
        p += (bytes + 255) & ~(size_t)255;
        return q;
    };
    ushort_t* h1b = (ushort_t*)carve((size_t)N * 512 * 2);
    char* shared_region = carve((size_t)N * 768 * 2);   // x_bf16 dead after GEMM1
    ushort_t* x_bf16 = (ushort_t*)shared_region;
    ushort_t* h_elu_b = (ushort_t*)shared_region;
    ushort_t* h2b = (ushort_t*)carve((size_t)N * 128 * 2);
    ushort_t* W1T = (ushort_t*)carve((size_t)512 * 768 * 2);
    ushort_t* W2T = (ushort_t*)carve((size_t)128 * 512 * 2);
    float* svec   = (float*)carve(512 * 4);
    float* e_src1 = (float*)carve((size_t)N * 4 * 4);
    float* e_dst1 = (float*)carve((size_t)N * 4 * 4);
    float* e_src2 = (float*)carve((size_t)N * 4);
    float* e_dst2 = (float*)carve((size_t)N * 4);
    float4* alpha1 = (float4*)carve((size_t)E * 16);    // edge-major [E] float4
    float* alpha2 = (float*)carve((size_t)E * 4);
    int*   indeg  = (int*)carve((size_t)N * 4);
    int*   offs   = (int*)carve((size_t)(N + 1) * 4);
    int*   cursor = (int*)carve((size_t)N * 4);
    int*   csrsrc = (int*)carve((size_t)E * 4);

    size_t nx = (size_t)N * 768;
    int nbCast = (int)((nx / 8 + 255) / 256);
    int nbZero = (N + 255) / 256;
    int nbPrep = nbCast + 384 + 64 + 2 + nbZero;

    // fused prep: cast x, transpose W1/W2, svec, zero indeg
    prep_kernel<<<nbPrep, 256, 0, stream>>>(x, x_bf16, nx, W1, W1T, W2, W2T,
                                            sent, svec, indeg, N, nbCast, nbZero);
    // CSR build
    count_kernel<<<(E + 255) / 256, 256, 0, stream>>>(ei, indeg, E);
    scan_kernel<<<1, 1024, 0, stream>>>(indeg, offs, cursor, N);
    scatter_kernel<<<(E + 255) / 256, 256, 0, stream>>>(ei, cursor, csrsrc, E);

    // GEMM1: h1b = bf16(x @ W1[:768] + svec)   [N,512]
    mfma_gemm_kernel<<<dim3((N + 127) / 128, 4), 256, 0, stream>>>(
        x_bf16, W1T, svec, h1b, N, 768, 512);

    // layer-1 attention
    e1_kernel<<<(N + 3) / 4, 256, 0, stream>>>(h1b, a1_src, a1_dst, e_src1, e_dst1, N);
    alpha1_kernel<<<(N + 3) / 4, 256, 0, stream>>>(e_src1, e_dst1, offs, csrsrc, alpha1, N);
    gather1_kernel<<<(N + 3) / 4, 256, 0, stream>>>(h1b, alpha1, offs, csrsrc, b1, h_elu_b, N);

    // GEMM2: h2b = bf16(h_elu @ W2)   [N,128]
    mfma_gemm_kernel<<<dim3((N + 127) / 128, 1), 256, 0, stream>>>(
        h_elu_b, W2T, nullptr, h2b, N, 512, 128);

    // layer-2 attention
    e2_kernel<<<(N + 3) / 4, 256, 0, stream>>>(h2b, a2_src, a2_dst, e_src2, e_dst2, N);
    alpha2_kernel<<<(N + 3) / 4, 256, 0, stream>>>(e_src2, e_dst2, offs, csrsrc, alpha2, N);
    gather2_kernel<<<(N + 3) / 4, 256, 0, stream>>>(h2b, alpha2, offs, csrsrc, b2, out, N);
}

// Round 7
// 343.738 us; speedup vs baseline: 2.2440x; 1.0620x over previous
//
#include <hip/hip_runtime.h>
#include <cstdint>
#include <cstddef>

#define NSLOPE 0.2f

typedef __attribute__((ext_vector_type(8))) short bf16x8;
typedef __attribute__((ext_vector_type(4))) float f32x4;
typedef __attribute__((ext_vector_type(2))) float f32x2;
typedef unsigned short ushort_t;

// ---------------------------------------------------------------- utilities
__device__ inline ushort_t f2bf(float f) {
    union { float f; unsigned u; } v; v.f = f;
    unsigned u = v.u;
    unsigned r = (u + 0x7fffu + ((u >> 16) & 1u)) >> 16;   // RNE
    return (ushort_t)r;
}
__device__ inline float bf2f(ushort_t u) {
    union { unsigned u; float f; } v; v.u = ((unsigned)u) << 16;
    return v.f;
}
__device__ inline float2 unpack_bf2(unsigned u) {
    return make_float2(bf2f((ushort_t)(u & 0xffffu)), bf2f((ushort_t)(u >> 16)));
}
// optimal 2-op unpack: lo = u<<16, hi = u & 0xffff0000
__device__ inline f32x2 unpack2(unsigned u) {
    union { unsigned u; float f; } lo, hi;
    lo.u = u << 16;
    hi.u = u & 0xffff0000u;
    f32x2 r; r.x = lo.f; r.y = hi.f;
    return r;
}

// ---------------------------------------------------------------- fused prep
// sections: [0,nbCast) cast x->bf16 | [.. +384) transpose W1 | [.. +64)
// transpose W2 | [.. +16) svec partials (2 col-halves x 8 k-chunks) |
// [.. +nbZero) zero indeg
__global__ __launch_bounds__(256) void prep_kernel(
    const float* __restrict__ x, ushort_t* __restrict__ x_bf16, size_t nx,
    const float* __restrict__ W1, ushort_t* __restrict__ W1T,
    const float* __restrict__ W2, ushort_t* __restrict__ W2T,
    const float* __restrict__ sent, float* __restrict__ svec_part,
    int* __restrict__ indeg, int N, int nbCast, int nbZero)
{
    __shared__ float tile[32][33];
    int bid = blockIdx.x;
    int tid = threadIdx.x;
    if (bid < nbCast) {
        size_t i = ((size_t)bid * 256 + tid) * 8;
        if (i < nx) {
            float4 v0 = *(const float4*)(x + i);
            float4 v1 = *(const float4*)(x + i + 4);
            ushort_t r[8] = { f2bf(v0.x), f2bf(v0.y), f2bf(v0.z), f2bf(v0.w),
                              f2bf(v1.x), f2bf(v1.y), f2bf(v1.z), f2bf(v1.w) };
            *(uint4*)(x_bf16 + i) = *(uint4*)r;
        }
        return;
    }
    bid -= nbCast;
    if (bid < 384) {   // W1[768][512] -> W1T[512][768]
        int k0 = (bid % 24) * 32, n0 = (bid / 24) * 32;
        int tx = tid & 31, ty = tid >> 5;
#pragma unroll
        for (int i = 0; i < 4; ++i)
            tile[ty + i * 8][tx] = W1[(size_t)(k0 + ty + i * 8) * 512 + n0 + tx];
        __syncthreads();
#pragma unroll
        for (int i = 0; i < 4; ++i)
            W1T[(size_t)(n0 + ty + i * 8) * 768 + k0 + tx] = f2bf(tile[tx][ty + i * 8]);
        return;
    }
    bid -= 384;
    if (bid < 64) {    // W2[512][128] -> W2T[128][512]
        int k0 = (bid % 16) * 32, n0 = (bid / 16) * 32;
        int tx = tid & 31, ty = tid >> 5;
#pragma unroll
        for (int i = 0; i < 4; ++i)
            tile[ty + i * 8][tx] = W2[(size_t)(k0 + ty + i * 8) * 128 + n0 + tx];
        __syncthreads();
#pragma unroll
        for (int i = 0; i < 4; ++i)
            W2T[(size_t)(n0 + ty + i * 8) * 512 + k0 + tx] = f2bf(tile[tx][ty + i * 8]);
        return;
    }
    bid -= 64;
    if (bid < 16) {    // svec partials: cb = bid&1 (col half), kb = bid>>1 (k chunk)
        int cb = bid & 1, kb = bid >> 1;
        int c = cb * 256 + tid;
        int k0 = kb * 96;
        float acc = 0.f;
#pragma unroll 8
        for (int k = k0; k < k0 + 96; ++k)
            acc += sent[k] * W1[(size_t)(768 + k) * 512 + c];
        svec_part[kb * 512 + c] = acc;
        return;
    }
    bid -= 16;
    {                  // zero indeg
        int i = bid * 256 + tid;
        if (i < N) indeg[i] = 0;
    }
}

// ---------------------------------------------------------------- MFMA GEMM
__device__ inline void async_copy16(const void* g, void* l) {
    __builtin_amdgcn_global_load_lds(
        (const __attribute__((address_space(1))) unsigned int*)g,
        (__attribute__((address_space(3))) unsigned int*)l, 16, 0, 0);
}

__global__ __launch_bounds__(256) void mfma_gemm_kernel(
    const ushort_t* __restrict__ A,   // [M][K] bf16
    const ushort_t* __restrict__ BT,  // [Nc][K] bf16
    const float* __restrict__ bias,   // [Nc] or null
    ushort_t* __restrict__ Cb,        // [M][Nc] bf16
    int M, int K, int Nc)
{
    __shared__ __align__(16) ushort_t lA[128 * 32];
    __shared__ __align__(16) ushort_t lB[128 * 32];
    const int tid = threadIdx.x;
    const int wave = tid >> 6;
    const int lane = tid & 63;
    const int row0 = blockIdx.x * 128;
    const int col0 = blockIdx.y * 128;
    const int wm = (wave & 1) * 64;
    const int wn = (wave >> 1) * 64;
    const int q = lane >> 4;
    const int ml = lane & 15;

    f32x4 acc[4][4] = {};

    int rowS[2], gS[2];
#pragma unroll
    for (int i = 0; i < 2; ++i) {
        int p = wave * 128 + i * 64 + lane;
        int r = p >> 2, s = p & 3;
        rowS[i] = r;
        gS[i] = s ^ ((r >> 1) & 3);
    }

    for (int k0 = 0; k0 < K; k0 += 32) {
#pragma unroll
        for (int i = 0; i < 2; ++i) {
            int pb = wave * 128 + i * 64;
            int r = rowS[i];
            int ga = min(row0 + r, M - 1);
            async_copy16(A + (size_t)ga * K + k0 + gS[i] * 8, &lA[(size_t)pb * 8]);
            async_copy16(BT + (size_t)(col0 + r) * K + k0 + gS[i] * 8, &lB[(size_t)pb * 8]);
        }
        __syncthreads();
        bf16x8 af[4], bfr[4];
#pragma unroll
        for (int t = 0; t < 4; ++t) {
            int m = wm + t * 16 + ml;
            af[t] = *(const bf16x8*)&lA[(size_t)(m * 4 + (q ^ ((m >> 1) & 3))) * 8];
            int n = wn + t * 16 + ml;
            bfr[t] = *(const bf16x8*)&lB[(size_t)(n * 4 + (q ^ ((n >> 1) & 3))) * 8];
        }
#pragma unroll
        for (int tm = 0; tm < 4; ++tm)
#pragma unroll
            for (int tn = 0; tn < 4; ++tn)
                acc[tm][tn] = __builtin_amdgcn_mfma_f32_16x16x32_bf16(
                    af[tm], bfr[tn], acc[tm][tn], 0, 0, 0);
        __syncthreads();
    }
#pragma unroll
    for (int tm = 0; tm < 4; ++tm) {
        int rbase = row0 + wm + tm * 16 + q * 4;
#pragma unroll
        for (int tn = 0; tn < 4; ++tn) {
            int col = col0 + wn + tn * 16 + ml;
            float bb = bias ? bias[col] : 0.f;
#pragma unroll
            for (int r = 0; r < 4; ++r) {
                int row = rbase + r;
                if (row < M)
                    Cb[(size_t)row * Nc + col] = f2bf(acc[tm][tn][r] + bb);
            }
        }
    }
}

// ---------------------------------------------------------------- CSR build
__global__ void count_kernel(const int* __restrict__ ei, int* __restrict__ indeg, int E) {
    int e = blockIdx.x * blockDim.x + threadIdx.x;
    if (e < E) atomicAdd(&indeg[ei[E + e]], 1);
}

// scan + svec reduce (threads 0..511 reduce the 8 svec partials first)
__global__ __launch_bounds__(1024) void scan_kernel(const int* __restrict__ indeg,
                                                    int* __restrict__ offsets,
                                                    int* __restrict__ cursor,
                                                    const float* __restrict__ svec_part,
                                                    float* __restrict__ svec, int N) {
    __shared__ int partial[1024];
    int tid = threadIdx.x;
    if (tid < 512) {
        float s = 0.f;
#pragma unroll
        for (int kb = 0; kb < 8; ++kb) s += svec_part[kb * 512 + tid];
        svec[tid] = s;
    }
    int per = (N + 1023) / 1024;
    int start = tid * per;
    int end = min(start + per, N);
    int sum = 0;
    for (int i = start; i < end; ++i) sum += indeg[i];
    partial[tid] = sum;
    __syncthreads();
    for (int st = 1; st < 1024; st <<= 1) {
        int v = (tid >= st) ? partial[tid - st] : 0;
        __syncthreads();
        partial[tid] += v;
        __syncthreads();
    }
    int run = (tid == 0) ? 0 : partial[tid - 1];
    for (int i = start; i < end; ++i) {
        offsets[i] = run; cursor[i] = run;
        run += indeg[i];
    }
    if (tid == 1023) offsets[N] = run;
}

__global__ void scatter_kernel(const int* __restrict__ ei, int* __restrict__ cursor,
                               int* __restrict__ csr_src, int E) {
    int e = blockIdx.x * blockDim.x + threadIdx.x;
    if (e < E) {
        int d = ei[E + e];
        int p = atomicAdd(&cursor[d], 1);
        csr_src[p] = ei[e];
    }
}

// ---------------------------------------------------------------- e_src/e_dst
__global__ __launch_bounds__(256) void e1_kernel(
    const ushort_t* __restrict__ h1b,
    const float* __restrict__ a_src, const float* __restrict__ a_dst,
    float* __restrict__ e_src, float* __restrict__ e_dst, int N) {
    int node = __builtin_amdgcn_readfirstlane(blockIdx.x * 4 + (threadIdx.x >> 6));
    int lane = threadIdx.x & 63;
    if (node >= N) return;
    float vs[4], vd[4];
#pragma unroll
    for (int h = 0; h < 4; ++h) {
        unsigned u = *(const unsigned*)&h1b[(size_t)node * 512 + h * 128 + lane * 2];
        float2 f = unpack_bf2(u);
        float as0 = a_src[h * 128 + lane * 2], as1 = a_src[h * 128 + lane * 2 + 1];
        float ad0 = a_dst[h * 128 + lane * 2], ad1 = a_dst[h * 128 + lane * 2 + 1];
        vs[h] = f.x * as0 + f.y * as1;
        vd[h] = f.x * ad0 + f.y * ad1;
    }
#pragma unroll
    for (int st = 32; st >= 1; st >>= 1) {
#pragma unroll
        for (int h = 0; h < 4; ++h) {
            vs[h] += __shfl_xor(vs[h], st);
            vd[h] += __shfl_xor(vd[h], st);
        }
    }
    if (lane == 0) {
        *(float4*)&e_src[node * 4] = make_float4(vs[0], vs[1], vs[2], vs[3]);
        *(float4*)&e_dst[node * 4] = make_float4(vd[0], vd[1], vd[2], vd[3]);
    }
}

__global__ __launch_bounds__(256) void e2_kernel(
    const ushort_t* __restrict__ h2b,
    const float* __restrict__ a_src, const float* __restrict__ a_dst,
    float* __restrict__ e_src, float* __restrict__ e_dst, int N) {
    int node = __builtin_amdgcn_readfirstlane(blockIdx.x * 4 + (threadIdx.x >> 6));
    int lane = threadIdx.x & 63;
    if (node >= N) return;
    unsigned u = *(const unsigned*)&h2b[(size_t)node * 128 + lane * 2];
    float2 f = unpack_bf2(u);
    float vs = f.x * a_src[lane * 2] + f.y * a_src[lane * 2 + 1];
    float vd = f.x * a_dst[lane * 2] + f.y * a_dst[lane * 2 + 1];
#pragma unroll
    for (int st = 32; st >= 1; st >>= 1) {
        vs += __shfl_xor(vs, st);
        vd += __shfl_xor(vd, st);
    }
    if (lane == 0) { e_src[node] = vs; e_dst[node] = vd; }
}

// ---------------------------------------------------------------- alpha (softmax)
__global__ __launch_bounds__(256) void alpha1_kernel(
    const float* __restrict__ e_src, const float* __restrict__ e_dst,
    const int* __restrict__ offsets, const int* __restrict__ csr_src,
    float4* __restrict__ alpha, int N) {
    int node = __builtin_amdgcn_readfirstlane(blockIdx.x * 4 + (threadIdx.x >> 6));
    int lane = threadIdx.x & 63;
    if (node >= N) return;
    int beg = offsets[node], end = offsets[node + 1];
    if (beg == end) return;
    float4 ed = *(const float4*)&e_dst[node * 4];
    float m[4] = { -1e30f, -1e30f, -1e30f, -1e30f };
    for (int base = beg; base < end; base += 64) {
        float e[4] = { -1e30f, -1e30f, -1e30f, -1e30f };
        if (base + lane < end) {
            int sid = csr_src[base + lane];
            float4 es = *(const float4*)&e_src[sid * 4];
            float v0 = es.x + ed.x, v1 = es.y + ed.y, v2 = es.z + ed.z, v3 = es.w + ed.w;
            e[0] = (v0 > 0.f) ? v0 : NSLOPE * v0;
            e[1] = (v1 > 0.f) ? v1 : NSLOPE * v1;
            e[2] = (v2 > 0.f) ? v2 : NSLOPE * v2;
            e[3] = (v3 > 0.f) ? v3 : NSLOPE * v3;
        }
#pragma unroll
        for (int st = 32; st >= 1; st >>= 1)
#pragma unroll
            for (int h = 0; h < 4; ++h)
                e[h] = fmaxf(e[h], __shfl_xor(e[h], st));
#pragma unroll
        for (int h = 0; h < 4; ++h) m[h] = fmaxf(m[h], e[h]);
    }
    float s[4] = { 0.f, 0.f, 0.f, 0.f };
    for (int base = beg; base < end; base += 64) {
        float w[4] = { 0.f, 0.f, 0.f, 0.f };
        if (base + lane < end) {
            int sid = csr_src[base + lane];
            float4 es = *(const float4*)&e_src[sid * 4];
            float v0 = es.x + ed.x, v1 = es.y + ed.y, v2 = es.z + ed.z, v3 = es.w + ed.w;
            w[0] = __expf(((v0 > 0.f) ? v0 : NSLOPE * v0) - m[0]);
            w[1] = __expf(((v1 > 0.f) ? v1 : NSLOPE * v1) - m[1]);
            w[2] = __expf(((v2 > 0.f) ? v2 : NSLOPE * v2) - m[2]);
            w[3] = __expf(((v3 > 0.f) ? v3 : NSLOPE * v3) - m[3]);
        }
#pragma unroll
        for (int st = 32; st >= 1; st >>= 1)
#pragma unroll
            for (int h = 0; h < 4; ++h)
                w[h] += __shfl_xor(w[h], st);
#pragma unroll
        for (int h = 0; h < 4; ++h) s[h] += w[h];
    }
    float r[4];
#pragma unroll
    for (int h = 0; h < 4; ++h) r[h] = 1.f / (s[h] + 1e-16f);
    for (int base = beg; base < end; base += 64) {
        if (base + lane < end) {
            int j = base + lane;
            int sid = csr_src[j];
            float4 es = *(const float4*)&e_src[sid * 4];
            float v0 = es.x + ed.x, v1 = es.y + ed.y, v2 = es.z + ed.z, v3 = es.w + ed.w;
            float4 a;
            a.x = __expf(((v0 > 0.f) ? v0 : NSLOPE * v0) - m[0]) * r[0];
            a.y = __expf(((v1 > 0.f) ? v1 : NSLOPE * v1) - m[1]) * r[1];
            a.z = __expf(((v2 > 0.f) ? v2 : NSLOPE * v2) - m[2]) * r[2];
            a.w = __expf(((v3 > 0.f) ? v3 : NSLOPE * v3) - m[3]) * r[3];
            alpha[j] = a;
        }
    }
}

__global__ __launch_bounds__(256) void alpha2_kernel(
    const float* __restrict__ e_src, const float* __restrict__ e_dst,
    const int* __restrict__ offsets, const int* __restrict__ csr_src,
    float* __restrict__ alpha, int N) {
    int node = __builtin_amdgcn_readfirstlane(blockIdx.x * 4 + (threadIdx.x >> 6));
    int lane = threadIdx.x & 63;
    if (node >= N) return;
    int beg = offsets[node], end = offsets[node + 1];
    if (beg == end) return;
    float ed = e_dst[node];
    float m = -1e30f;
    for (int base = beg; base < end; base += 64) {
        float e = -1e30f;
        if (base + lane < end) {
            float v = e_src[csr_src[base + lane]] + ed;
            e = (v > 0.f) ? v : NSLOPE * v;
        }
#pragma unroll
        for (int st = 32; st >= 1; st >>= 1)
            e = fmaxf(e, __shfl_xor(e, st));
        m = fmaxf(m, e);
    }
    float s = 0.f;
    for (int base = beg; base < end; base += 64) {
        float w = 0.f;
        if (base + lane < end) {
            float v = e_src[csr_src[base + lane]] + ed;
            w = __expf(((v > 0.f) ? v : NSLOPE * v) - m);
        }
#pragma unroll
        for (int st = 32; st >= 1; st >>= 1)
            w += __shfl_xor(w, st);
        s += w;
    }
    float rs = 1.f / (s + 1e-16f);
    for (int base = beg; base < end; base += 64) {
        if (base + lane < end) {
            float v = e_src[csr_src[base + lane]] + ed;
            alpha[base + lane] = __expf(((v > 0.f) ? v : NSLOPE * v) - m) * rs;
        }
    }
}

// ---------------------------------------------------------------- gather-agg
__global__ __launch_bounds__(256) void gather1_kernel(
    const ushort_t* __restrict__ h1b, const float4* __restrict__ alpha,
    const int* __restrict__ offsets, const int* __restrict__ csr_src,
    const float* __restrict__ bias, ushort_t* __restrict__ outb, int N)
{
    int node = __builtin_amdgcn_readfirstlane(blockIdx.x * 4 + (threadIdx.x >> 6));
    int lane = threadIdx.x & 63;
    if (node >= N) return;
    int beg = offsets[node], end = offsets[node + 1];
    const int h = lane >> 4;
    const bool hb1 = (h & 1), hb2 = (h & 2);
    const ushort_t* hp = h1b + lane * 8;
    f32x2 acc[4] = {};

    int j = beg;
#pragma unroll 2
    for (; j + 2 <= end; j += 2) {
        int s0 = csr_src[j], s1 = csr_src[j + 1];
        float4 a0 = alpha[j], a1 = alpha[j + 1];
        float w0 = hb2 ? (hb1 ? a0.w : a0.z) : (hb1 ? a0.y : a0.x);
        float w1 = hb2 ? (hb1 ? a1.w : a1.z) : (hb1 ? a1.y : a1.x);
        uint4 u0 = *(const uint4*)&hp[(size_t)s0 * 512];
        uint4 u1 = *(const uint4*)&hp[(size_t)s1 * 512];
        f32x2 w0v = { w0, w0 }, w1v = { w1, w1 };
        acc[0] += unpack2(u0.x) * w0v; acc[1] += unpack2(u0.y) * w0v;
        acc[2] += unpack2(u0.z) * w0v; acc[3] += unpack2(u0.w) * w0v;
        acc[0] += unpack2(u1.x) * w1v; acc[1] += unpack2(u1.y) * w1v;
        acc[2] += unpack2(u1.z) * w1v; acc[3] += unpack2(u1.w) * w1v;
    }
    if (j < end) {
        int s0 = csr_src[j];
        float4 a0 = alpha[j];
        float w0 = hb2 ? (hb1 ? a0.w : a0.z) : (hb1 ? a0.y : a0.x);
        uint4 u0 = *(const uint4*)&hp[(size_t)s0 * 512];
        f32x2 w0v = { w0, w0 };
        acc[0] += unpack2(u0.x) * w0v; acc[1] += unpack2(u0.y) * w0v;
        acc[2] += unpack2(u0.z) * w0v; acc[3] += unpack2(u0.w) * w0v;
    }
    int c = lane * 8;
    ushort_t o[8];
#pragma unroll
    for (int i = 0; i < 4; ++i) {
        float r0 = acc[i].x + bias[c + 2 * i];
        float r1 = acc[i].y + bias[c + 2 * i + 1];
        r0 = (r0 > 0.f) ? r0 : (__expf(r0) - 1.f);
        r1 = (r1 > 0.f) ? r1 : (__expf(r1) - 1.f);
        o[2 * i] = f2bf(r0);
        o[2 * i + 1] = f2bf(r1);
    }
    *(uint4*)&outb[(size_t)node * 512 + c] = *(uint4*)o;
}

__global__ __launch_bounds__(256) void gather2_kernel(
    const ushort_t* __restrict__ h2b, const float* __restrict__ alpha,
    const int* __restrict__ offsets, const int* __restrict__ csr_src,
    const float* __restrict__ bias, float* __restrict__ out, int N)
{
    int node = __builtin_amdgcn_readfirstlane(blockIdx.x * 4 + (threadIdx.x >> 6));
    int lane = threadIdx.x & 63;
    if (node >= N) return;
    int beg = offsets[node], end = offsets[node + 1];
    const ushort_t* hp = h2b + lane * 2;
    f32x2 acc = { 0.f, 0.f };
    int j = beg;
#pragma unroll 2
    for (; j + 4 <= end; j += 4) {
        int s0 = csr_src[j], s1 = csr_src[j + 1];
        int s2 = csr_src[j + 2], s3 = csr_src[j + 3];
        float w0 = alpha[j], w1 = alpha[j + 1], w2 = alpha[j + 2], w3 = alpha[j + 3];
        unsigned u0 = *(const unsigned*)&hp[(size_t)s0 * 128];
        unsigned u1 = *(const unsigned*)&hp[(size_t)s1 * 128];
        unsigned u2 = *(const unsigned*)&hp[(size_t)s2 * 128];
        unsigned u3 = *(const unsigned*)&hp[(size_t)s3 * 128];
        f32x2 w0v = { w0, w0 }, w1v = { w1, w1 }, w2v = { w2, w2 }, w3v = { w3, w3 };
        acc += unpack2(u0) * w0v;
        acc += unpack2(u1) * w1v;
        acc += unpack2(u2) * w2v;
        acc += unpack2(u3) * w3v;
    }
    for (; j < end; ++j) {
        int s0 = csr_src[j];
        float w0 = alpha[j];
        unsigned u0 = *(const unsigned*)&hp[(size_t)s0 * 128];
        f32x2 w0v = { w0, w0 };
        acc += unpack2(u0) * w0v;
    }
    float2 o = make_float2(acc.x + bias[lane * 2], acc.y + bias[lane * 2 + 1]);
    *(float2*)&out[(size_t)node * 128 + lane * 2] = o;
}

// ---------------------------------------------------------------- launch
extern "C" void kernel_launch(void* const* d_in, const int* in_sizes, int n_in,
                              void* d_out, int out_size, void* d_ws, size_t ws_size,
                              hipStream_t stream) {
    const float* x      = (const float*)d_in[0];
    const int*   ei     = (const int*)  d_in[1];
    const float* sent   = (const float*)d_in[2];
    const float* W1     = (const float*)d_in[3];
    const float* a1_src = (const float*)d_in[4];
    const float* a1_dst = (const float*)d_in[5];
    const float* b1     = (const float*)d_in[6];
    const float* W2     = (const float*)d_in[7];
    const float* a2_src = (const float*)d_in[8];
    const float* a2_dst = (const float*)d_in[9];
    const float* b2     = (const float*)d_in[10];
    float* out = (float*)d_out;

    const int N = in_sizes[0] / 768;   // 20000
    const int E = in_sizes[1] / 2;     // 320000

    char* p = (char*)d_ws;
    auto carve = [&](size_t bytes) {
        char* q = p;
        p += (bytes + 255) & ~(size_t)255;
        return q;
    };
    ushort_t* h1b = (ushort_t*)carve((size_t)N * 512 * 2);
    char* shared_region = carve((size_t)N * 768 * 2);   // x_bf16 dead after GEMM1
    ushort_t* x_bf16 = (ushort_t*)shared_region;
    ushort_t* h_elu_b = (ushort_t*)shared_region;
    ushort_t* h2b = (ushort_t*)carve((size_t)N * 128 * 2);
    ushort_t* W1T = (ushort_t*)carve((size_t)512 * 768 * 2);
    ushort_t* W2T = (ushort_t*)carve((size_t)128 * 512 * 2);
    float* svec_part = (float*)carve(8 * 512 * 4);
    float* svec   = (float*)carve(512 * 4);
    float* e_src1 = (float*)carve((size_t)N * 4 * 4);
    float* e_dst1 = (float*)carve((size_t)N * 4 * 4);
    float* e_src2 = (float*)carve((size_t)N * 4);
    float* e_dst2 = (float*)carve((size_t)N * 4);
    float4* alpha1 = (float4*)carve((size_t)E * 16);    // edge-major [E] float4
    float* alpha2 = (float*)carve((size_t)E * 4);
    int*   indeg  = (int*)carve((size_t)N * 4);
    int*   offs   = (int*)carve((size_t)(N + 1) * 4);
    int*   cursor = (int*)carve((size_t)N * 4);
    int*   csrsrc = (int*)carve((size_t)E * 4);

    size_t nx = (size_t)N * 768;
    int nbCast = (int)((nx / 8 + 255) / 256);
    int nbZero = (N + 255) / 256;
    int nbPrep = nbCast + 384 + 64 + 16 + nbZero;

    // fused prep: cast x, transpose W1/W2, svec partials, zero indeg
    prep_kernel<<<nbPrep, 256, 0, stream>>>(x, x_bf16, nx, W1, W1T, W2, W2T,
                                            sent, svec_part, indeg, N, nbCast, nbZero);
    // CSR build (+ svec reduce inside scan)
    count_kernel<<<(E + 255) / 256, 256, 0, stream>>>(ei, indeg, E);
    scan_kernel<<<1, 1024, 0, stream>>>(indeg, offs, cursor, svec_part, svec, N);
    scatter_kernel<<<(E + 255) / 256, 256, 0, stream>>>(ei, cursor, csrsrc, E);

    // GEMM1: h1b = bf16(x @ W1[:768] + svec)   [N,512]
    mfma_gemm_kernel<<<dim3((N + 127) / 128, 4), 256, 0, stream>>>(
        x_bf16, W1T, svec, h1b, N, 768, 512);

    // layer-1 attention
    e1_kernel<<<(N + 3) / 4, 256, 0, stream>>>(h1b, a1_src, a1_dst, e_src1, e_dst1, N);
    alpha1_kernel<<<(N + 3) / 4, 256, 0, stream>>>(e_src1, e_dst1, offs, csrsrc, alpha1, N);
    gather1_kernel<<<(N + 3) / 4, 256, 0, stream>>>(h1b, alpha1, offs, csrsrc, b1, h_elu_b, N);

    // GEMM2: h2b = bf16(h_elu @ W2)   [N,128]
    mfma_gemm_kernel<<<dim3((N + 127) / 128, 1), 256, 0, stream>>>(
        h_elu_b, W2T, nullptr, h2b, N, 512, 128);

    // layer-2 attention
    e2_kernel<<<(N + 3) / 4, 256, 0, stream>>>(h2b, a2_src, a2_dst, e_src2, e_dst2, N);
    alpha2_kernel<<<(N + 3) / 4, 256, 0, stream>>>(e_src2, e_dst2, offs, csrsrc, alpha2, N);
    gather2_kernel<<<(N + 3) / 4, 256, 0, stream>>>(h2b, alpha2, offs, csrsrc, b2, out, N);
}

// Round 8
// 330.094 us; speedup vs baseline: 2.3367x; 1.0413x over previous
//
#include <hip/hip_runtime.h>
#include <cstdint>
#include <cstddef>

#define NSLOPE 0.2f

typedef __attribute__((ext_vector_type(8))) short bf16x8;
typedef __attribute__((ext_vector_type(4))) float f32x4;
typedef __attribute__((ext_vector_type(2))) float f32x2;
typedef unsigned short ushort_t;

// ---------------------------------------------------------------- utilities
__device__ inline ushort_t f2bf(float f) {
    union { float f; unsigned u; } v; v.f = f;
    unsigned u = v.u;
    unsigned r = (u + 0x7fffu + ((u >> 16) & 1u)) >> 16;   // RNE
    return (ushort_t)r;
}
__device__ inline float bf2f(ushort_t u) {
    union { unsigned u; float f; } v; v.u = ((unsigned)u) << 16;
    return v.f;
}
__device__ inline float2 unpack_bf2(unsigned u) {
    return make_float2(bf2f((ushort_t)(u & 0xffffu)), bf2f((ushort_t)(u >> 16)));
}
// optimal 2-op unpack: lo = u<<16, hi = u & 0xffff0000
__device__ inline f32x2 unpack2(unsigned u) {
    union { unsigned u; float f; } lo, hi;
    lo.u = u << 16;
    hi.u = u & 0xffff0000u;
    f32x2 r; r.x = lo.f; r.y = hi.f;
    return r;
}
__device__ inline float leaky(float v) { return (v > 0.f) ? v : NSLOPE * v; }
__device__ inline float sel4(float4 q, bool b1, bool b2) {
    return b2 ? (b1 ? q.w : q.z) : (b1 ? q.y : q.x);
}

// ---------------------------------------------------------------- fused prep
// sections: [0,nbCast) cast x->bf16 | [.. +384) transpose W1 | [.. +64)
// transpose W2 | [.. +16) svec partials | [.. +nbZero) zero indeg
__global__ __launch_bounds__(256) void prep_kernel(
    const float* __restrict__ x, ushort_t* __restrict__ x_bf16, size_t nx,
    const float* __restrict__ W1, ushort_t* __restrict__ W1T,
    const float* __restrict__ W2, ushort_t* __restrict__ W2T,
    const float* __restrict__ sent, float* __restrict__ svec_part,
    int* __restrict__ indeg, int N, int nbCast, int nbZero)
{
    __shared__ float tile[32][33];
    int bid = blockIdx.x;
    int tid = threadIdx.x;
    if (bid < nbCast) {
        size_t i = ((size_t)bid * 256 + tid) * 8;
        if (i < nx) {
            float4 v0 = *(const float4*)(x + i);
            float4 v1 = *(const float4*)(x + i + 4);
            ushort_t r[8] = { f2bf(v0.x), f2bf(v0.y), f2bf(v0.z), f2bf(v0.w),
                              f2bf(v1.x), f2bf(v1.y), f2bf(v1.z), f2bf(v1.w) };
            *(uint4*)(x_bf16 + i) = *(uint4*)r;
        }
        return;
    }
    bid -= nbCast;
    if (bid < 384) {   // W1[768][512] -> W1T[512][768]
        int k0 = (bid % 24) * 32, n0 = (bid / 24) * 32;
        int tx = tid & 31, ty = tid >> 5;
#pragma unroll
        for (int i = 0; i < 4; ++i)
            tile[ty + i * 8][tx] = W1[(size_t)(k0 + ty + i * 8) * 512 + n0 + tx];
        __syncthreads();
#pragma unroll
        for (int i = 0; i < 4; ++i)
            W1T[(size_t)(n0 + ty + i * 8) * 768 + k0 + tx] = f2bf(tile[tx][ty + i * 8]);
        return;
    }
    bid -= 384;
    if (bid < 64) {    // W2[512][128] -> W2T[128][512]
        int k0 = (bid % 16) * 32, n0 = (bid / 16) * 32;
        int tx = tid & 31, ty = tid >> 5;
#pragma unroll
        for (int i = 0; i < 4; ++i)
            tile[ty + i * 8][tx] = W2[(size_t)(k0 + ty + i * 8) * 128 + n0 + tx];
        __syncthreads();
#pragma unroll
        for (int i = 0; i < 4; ++i)
            W2T[(size_t)(n0 + ty + i * 8) * 512 + k0 + tx] = f2bf(tile[tx][ty + i * 8]);
        return;
    }
    bid -= 64;
    if (bid < 16) {    // svec partials
        int cb = bid & 1, kb = bid >> 1;
        int c = cb * 256 + tid;
        int k0 = kb * 96;
        float acc = 0.f;
#pragma unroll 8
        for (int k = k0; k < k0 + 96; ++k)
            acc += sent[k] * W1[(size_t)(768 + k) * 512 + c];
        svec_part[kb * 512 + c] = acc;
        return;
    }
    bid -= 16;
    {                  // zero indeg
        int i = bid * 256 + tid;
        if (i < N) indeg[i] = 0;
    }
}

// ---------------------------------------------------------------- MFMA GEMM
__device__ inline void async_copy16(const void* g, void* l) {
    __builtin_amdgcn_global_load_lds(
        (const __attribute__((address_space(1))) unsigned int*)g,
        (__attribute__((address_space(3))) unsigned int*)l, 16, 0, 0);
}

__global__ __launch_bounds__(256) void mfma_gemm_kernel(
    const ushort_t* __restrict__ A,   // [M][K] bf16
    const ushort_t* __restrict__ BT,  // [Nc][K] bf16
    const float* __restrict__ bias,   // [Nc] or null
    ushort_t* __restrict__ Cb,        // [M][Nc] bf16
    int M, int K, int Nc)
{
    __shared__ __align__(16) ushort_t lA[128 * 32];
    __shared__ __align__(16) ushort_t lB[128 * 32];
    const int tid = threadIdx.x;
    const int wave = tid >> 6;
    const int lane = tid & 63;
    const int row0 = blockIdx.x * 128;
    const int col0 = blockIdx.y * 128;
    const int wm = (wave & 1) * 64;
    const int wn = (wave >> 1) * 64;
    const int q = lane >> 4;
    const int ml = lane & 15;

    f32x4 acc[4][4] = {};

    int rowS[2], gS[2];
#pragma unroll
    for (int i = 0; i < 2; ++i) {
        int p = wave * 128 + i * 64 + lane;
        int r = p >> 2, s = p & 3;
        rowS[i] = r;
        gS[i] = s ^ ((r >> 1) & 3);
    }

    for (int k0 = 0; k0 < K; k0 += 32) {
#pragma unroll
        for (int i = 0; i < 2; ++i) {
            int pb = wave * 128 + i * 64;
            int r = rowS[i];
            int ga = min(row0 + r, M - 1);
            async_copy16(A + (size_t)ga * K + k0 + gS[i] * 8, &lA[(size_t)pb * 8]);
            async_copy16(BT + (size_t)(col0 + r) * K + k0 + gS[i] * 8, &lB[(size_t)pb * 8]);
        }
        __syncthreads();
        bf16x8 af[4], bfr[4];
#pragma unroll
        for (int t = 0; t < 4; ++t) {
            int m = wm + t * 16 + ml;
            af[t] = *(const bf16x8*)&lA[(size_t)(m * 4 + (q ^ ((m >> 1) & 3))) * 8];
            int n = wn + t * 16 + ml;
            bfr[t] = *(const bf16x8*)&lB[(size_t)(n * 4 + (q ^ ((n >> 1) & 3))) * 8];
        }
#pragma unroll
        for (int tm = 0; tm < 4; ++tm)
#pragma unroll
            for (int tn = 0; tn < 4; ++tn)
                acc[tm][tn] = __builtin_amdgcn_mfma_f32_16x16x32_bf16(
                    af[tm], bfr[tn], acc[tm][tn], 0, 0, 0);
        __syncthreads();
    }
#pragma unroll
    for (int tm = 0; tm < 4; ++tm) {
        int rbase = row0 + wm + tm * 16 + q * 4;
#pragma unroll
        for (int tn = 0; tn < 4; ++tn) {
            int col = col0 + wn + tn * 16 + ml;
            float bb = bias ? bias[col] : 0.f;
#pragma unroll
            for (int r = 0; r < 4; ++r) {
                int row = rbase + r;
                if (row < M)
                    Cb[(size_t)row * Nc + col] = f2bf(acc[tm][tn][r] + bb);
            }
        }
    }
}

// ---------------------------------------------------------------- CSR build
__global__ void count_kernel(const int* __restrict__ ei, int* __restrict__ indeg, int E) {
    int e = blockIdx.x * blockDim.x + threadIdx.x;
    if (e < E) atomicAdd(&indeg[ei[E + e]], 1);
}

__global__ __launch_bounds__(1024) void scan_kernel(const int* __restrict__ indeg,
                                                    int* __restrict__ offsets,
                                                    int* __restrict__ cursor,
                                                    const float* __restrict__ svec_part,
                                                    float* __restrict__ svec, int N) {
    __shared__ int partial[1024];
    int tid = threadIdx.x;
    if (tid < 512) {
        float s = 0.f;
#pragma unroll
        for (int kb = 0; kb < 8; ++kb) s += svec_part[kb * 512 + tid];
        svec[tid] = s;
    }
    int per = (N + 1023) / 1024;
    int start = tid * per;
    int end = min(start + per, N);
    int sum = 0;
    for (int i = start; i < end; ++i) sum += indeg[i];
    partial[tid] = sum;
    __syncthreads();
    for (int st = 1; st < 1024; st <<= 1) {
        int v = (tid >= st) ? partial[tid - st] : 0;
        __syncthreads();
        partial[tid] += v;
        __syncthreads();
    }
    int run = (tid == 0) ? 0 : partial[tid - 1];
    for (int i = start; i < end; ++i) {
        offsets[i] = run; cursor[i] = run;
        run += indeg[i];
    }
    if (tid == 1023) offsets[N] = run;
}

__global__ void scatter_kernel(const int* __restrict__ ei, int* __restrict__ cursor,
                               int* __restrict__ csr_src, int E) {
    int e = blockIdx.x * blockDim.x + threadIdx.x;
    if (e < E) {
        int d = ei[E + e];
        int p = atomicAdd(&cursor[d], 1);
        csr_src[p] = ei[e];
    }
}

// ---------------------------------------------------------------- e_src/e_dst
__global__ __launch_bounds__(256) void e1_kernel(
    const ushort_t* __restrict__ h1b,
    const float* __restrict__ a_src, const float* __restrict__ a_dst,
    float* __restrict__ e_src, float* __restrict__ e_dst, int N) {
    int node = __builtin_amdgcn_readfirstlane(blockIdx.x * 4 + (threadIdx.x >> 6));
    int lane = threadIdx.x & 63;
    if (node >= N) return;
    float vs[4], vd[4];
#pragma unroll
    for (int h = 0; h < 4; ++h) {
        unsigned u = *(const unsigned*)&h1b[(size_t)node * 512 + h * 128 + lane * 2];
        float2 f = unpack_bf2(u);
        float as0 = a_src[h * 128 + lane * 2], as1 = a_src[h * 128 + lane * 2 + 1];
        float ad0 = a_dst[h * 128 + lane * 2], ad1 = a_dst[h * 128 + lane * 2 + 1];
        vs[h] = f.x * as0 + f.y * as1;
        vd[h] = f.x * ad0 + f.y * ad1;
    }
#pragma unroll
    for (int st = 32; st >= 1; st >>= 1) {
#pragma unroll
        for (int h = 0; h < 4; ++h) {
            vs[h] += __shfl_xor(vs[h], st);
            vd[h] += __shfl_xor(vd[h], st);
        }
    }
    if (lane == 0) {
        *(float4*)&e_src[node * 4] = make_float4(vs[0], vs[1], vs[2], vs[3]);
        *(float4*)&e_dst[node * 4] = make_float4(vd[0], vd[1], vd[2], vd[3]);
    }
}

__global__ __launch_bounds__(256) void e2_kernel(
    const ushort_t* __restrict__ h2b,
    const float* __restrict__ a_src, const float* __restrict__ a_dst,
    float* __restrict__ e_src, float* __restrict__ e_dst, int N) {
    int node = __builtin_amdgcn_readfirstlane(blockIdx.x * 4 + (threadIdx.x >> 6));
    int lane = threadIdx.x & 63;
    if (node >= N) return;
    unsigned u = *(const unsigned*)&h2b[(size_t)node * 128 + lane * 2];
    float2 f = unpack_bf2(u);
    float vs = f.x * a_src[lane * 2] + f.y * a_src[lane * 2 + 1];
    float vd = f.x * a_dst[lane * 2] + f.y * a_dst[lane * 2 + 1];
#pragma unroll
    for (int st = 32; st >= 1; st >>= 1) {
        vs += __shfl_xor(vs, st);
        vd += __shfl_xor(vd, st);
    }
    if (lane == 0) { e_src[node] = vs; e_dst[node] = vd; }
}

// ---------------------------------------------------------------- gather+softmax
// layer 1: wave per node. Phase A: per-lane online softmax (m,s per head) over
// strided edges + butterfly merge. Gather loop: wave-uniform edge index ->
// scalar csr/e_src loads, w computed inline; lane owns 8 contiguous channels.
__global__ __launch_bounds__(256) void gather1_kernel(
    const ushort_t* __restrict__ h1b, const float* __restrict__ e_src,
    const float* __restrict__ e_dst, const int* __restrict__ offsets,
    const int* __restrict__ csr_src, const float* __restrict__ bias,
    ushort_t* __restrict__ outb, int N)
{
    int node = __builtin_amdgcn_readfirstlane(blockIdx.x * 4 + (threadIdx.x >> 6));
    int lane = threadIdx.x & 63;
    if (node >= N) return;
    int beg = offsets[node], end = offsets[node + 1];
    float4 ed = *(const float4*)&e_dst[node * 4];

    // phase A: online softmax stats per head
    float m[4] = { -1e30f, -1e30f, -1e30f, -1e30f };
    float s[4] = { 0.f, 0.f, 0.f, 0.f };
    for (int j = beg + lane; j < end; j += 64) {
        int sid = csr_src[j];
        float4 es = *(const float4*)&e_src[sid * 4];
        float e[4] = { leaky(es.x + ed.x), leaky(es.y + ed.y),
                       leaky(es.z + ed.z), leaky(es.w + ed.w) };
#pragma unroll
        for (int hh = 0; hh < 4; ++hh) {
            float nm = fmaxf(m[hh], e[hh]);
            s[hh] = s[hh] * __expf(m[hh] - nm) + __expf(e[hh] - nm);
            m[hh] = nm;
        }
    }
#pragma unroll
    for (int st = 32; st >= 1; st >>= 1) {
#pragma unroll
        for (int hh = 0; hh < 4; ++hh) {
            float om = __shfl_xor(m[hh], st);
            float os = __shfl_xor(s[hh], st);
            float nm = fmaxf(m[hh], om);
            s[hh] = s[hh] * __expf(m[hh] - nm) + os * __expf(om - nm);
            m[hh] = nm;
        }
    }
    // per-lane head constants
    const int h = lane >> 4;
    const bool b1 = (h & 1), b2 = (h & 2);
    float mh  = b2 ? (b1 ? m[3] : m[2]) : (b1 ? m[1] : m[0]);
    float sh  = b2 ? (b1 ? s[3] : s[2]) : (b1 ? s[1] : s[0]);
    float rsh = 1.f / (sh + 1e-16f);
    float edh = sel4(ed, b1, b2);

    const ushort_t* hp = h1b + lane * 8;
    f32x2 acc[4] = {};
    int j = beg;
#pragma unroll 2
    for (; j + 4 <= end; j += 4) {
        int s0 = csr_src[j], s1 = csr_src[j + 1];          // scalar
        int s2 = csr_src[j + 2], s3 = csr_src[j + 3];
        float4 q0 = *(const float4*)&e_src[s0 * 4];        // scalar 16B
        float4 q1 = *(const float4*)&e_src[s1 * 4];
        float4 q2 = *(const float4*)&e_src[s2 * 4];
        float4 q3 = *(const float4*)&e_src[s3 * 4];
        float w0 = __expf(leaky(sel4(q0, b1, b2) + edh) - mh) * rsh;
        float w1 = __expf(leaky(sel4(q1, b1, b2) + edh) - mh) * rsh;
        float w2 = __expf(leaky(sel4(q2, b1, b2) + edh) - mh) * rsh;
        float w3 = __expf(leaky(sel4(q3, b1, b2) + edh) - mh) * rsh;
        uint4 u0 = *(const uint4*)&hp[(size_t)s0 * 512];
        uint4 u1 = *(const uint4*)&hp[(size_t)s1 * 512];
        uint4 u2 = *(const uint4*)&hp[(size_t)s2 * 512];
        uint4 u3 = *(const uint4*)&hp[(size_t)s3 * 512];
        f32x2 wv;
        wv.x = w0; wv.y = w0;
        acc[0] += unpack2(u0.x) * wv; acc[1] += unpack2(u0.y) * wv;
        acc[2] += unpack2(u0.z) * wv; acc[3] += unpack2(u0.w) * wv;
        wv.x = w1; wv.y = w1;
        acc[0] += unpack2(u1.x) * wv; acc[1] += unpack2(u1.y) * wv;
        acc[2] += unpack2(u1.z) * wv; acc[3] += unpack2(u1.w) * wv;
        wv.x = w2; wv.y = w2;
        acc[0] += unpack2(u2.x) * wv; acc[1] += unpack2(u2.y) * wv;
        acc[2] += unpack2(u2.z) * wv; acc[3] += unpack2(u2.w) * wv;
        wv.x = w3; wv.y = w3;
        acc[0] += unpack2(u3.x) * wv; acc[1] += unpack2(u3.y) * wv;
        acc[2] += unpack2(u3.z) * wv; acc[3] += unpack2(u3.w) * wv;
    }
    for (; j < end; ++j) {
        int s0 = csr_src[j];
        float4 q0 = *(const float4*)&e_src[s0 * 4];
        float w0 = __expf(leaky(sel4(q0, b1, b2) + edh) - mh) * rsh;
        uint4 u0 = *(const uint4*)&hp[(size_t)s0 * 512];
        f32x2 wv; wv.x = w0; wv.y = w0;
        acc[0] += unpack2(u0.x) * wv; acc[1] += unpack2(u0.y) * wv;
        acc[2] += unpack2(u0.z) * wv; acc[3] += unpack2(u0.w) * wv;
    }
    int c = lane * 8;
    ushort_t o[8];
#pragma unroll
    for (int i = 0; i < 4; ++i) {
        float r0 = acc[i].x + bias[c + 2 * i];
        float r1 = acc[i].y + bias[c + 2 * i + 1];
        r0 = (r0 > 0.f) ? r0 : (__expf(r0) - 1.f);
        r1 = (r1 > 0.f) ? r1 : (__expf(r1) - 1.f);
        o[2 * i] = f2bf(r0);
        o[2 * i + 1] = f2bf(r1);
    }
    *(uint4*)&outb[(size_t)node * 512 + c] = *(uint4*)o;
}

// layer 2: wave per node, 1 head; same fused structure; fp32 output.
__global__ __launch_bounds__(256) void gather2_kernel(
    const ushort_t* __restrict__ h2b, const float* __restrict__ e_src,
    const float* __restrict__ e_dst, const int* __restrict__ offsets,
    const int* __restrict__ csr_src, const float* __restrict__ bias,
    float* __restrict__ out, int N)
{
    int node = __builtin_amdgcn_readfirstlane(blockIdx.x * 4 + (threadIdx.x >> 6));
    int lane = threadIdx.x & 63;
    if (node >= N) return;
    int beg = offsets[node], end = offsets[node + 1];
    float ed = e_dst[node];

    // phase A
    float m = -1e30f, s = 0.f;
    for (int j = beg + lane; j < end; j += 64) {
        float e = leaky(e_src[csr_src[j]] + ed);
        float nm = fmaxf(m, e);
        s = s * __expf(m - nm) + __expf(e - nm);
        m = nm;
    }
#pragma unroll
    for (int st = 32; st >= 1; st >>= 1) {
        float om = __shfl_xor(m, st);
        float os = __shfl_xor(s, st);
        float nm = fmaxf(m, om);
        s = s * __expf(m - nm) + os * __expf(om - nm);
        m = nm;
    }
    float rs = 1.f / (s + 1e-16f);

    const ushort_t* hp = h2b + lane * 2;
    f32x2 acc = { 0.f, 0.f };
    int j = beg;
#pragma unroll 2
    for (; j + 4 <= end; j += 4) {
        int s0 = csr_src[j], s1 = csr_src[j + 1];
        int s2 = csr_src[j + 2], s3 = csr_src[j + 3];
        float w0 = __expf(leaky(e_src[s0] + ed) - m) * rs;
        float w1 = __expf(leaky(e_src[s1] + ed) - m) * rs;
        float w2 = __expf(leaky(e_src[s2] + ed) - m) * rs;
        float w3 = __expf(leaky(e_src[s3] + ed) - m) * rs;
        unsigned u0 = *(const unsigned*)&hp[(size_t)s0 * 128];
        unsigned u1 = *(const unsigned*)&hp[(size_t)s1 * 128];
        unsigned u2 = *(const unsigned*)&hp[(size_t)s2 * 128];
        unsigned u3 = *(const unsigned*)&hp[(size_t)s3 * 128];
        f32x2 w0v = { w0, w0 }, w1v = { w1, w1 }, w2v = { w2, w2 }, w3v = { w3, w3 };
        acc += unpack2(u0) * w0v;
        acc += unpack2(u1) * w1v;
        acc += unpack2(u2) * w2v;
        acc += unpack2(u3) * w3v;
    }
    for (; j < end; ++j) {
        int s0 = csr_src[j];
        float w0 = __expf(leaky(e_src[s0] + ed) - m) * rs;
        unsigned u0 = *(const unsigned*)&hp[(size_t)s0 * 128];
        f32x2 w0v = { w0, w0 };
        acc += unpack2(u0) * w0v;
    }
    float2 o = make_float2(acc.x + bias[lane * 2], acc.y + bias[lane * 2 + 1]);
    *(float2*)&out[(size_t)node * 128 + lane * 2] = o;
}

// ---------------------------------------------------------------- launch
extern "C" void kernel_launch(void* const* d_in, const int* in_sizes, int n_in,
                              void* d_out, int out_size, void* d_ws, size_t ws_size,
                              hipStream_t stream) {
    const float* x      = (const float*)d_in[0];
    const int*   ei     = (const int*)  d_in[1];
    const float* sent   = (const float*)d_in[2];
    const float* W1     = (const float*)d_in[3];
    const float* a1_src = (const float*)d_in[4];
    const float* a1_dst = (const float*)d_in[5];
    const float* b1     = (const float*)d_in[6];
    const float* W2     = (const float*)d_in[7];
    const float* a2_src = (const float*)d_in[8];
    const float* a2_dst = (const float*)d_in[9];
    const float* b2     = (const float*)d_in[10];
    float* out = (float*)d_out;

    const int N = in_sizes[0] / 768;   // 20000
    const int E = in_sizes[1] / 2;     // 320000

    char* p = (char*)d_ws;
    auto carve = [&](size_t bytes) {
        char* q = p;
        p += (bytes + 255) & ~(size_t)255;
        return q;
    };
    ushort_t* h1b = (ushort_t*)carve((size_t)N * 512 * 2);
    char* shared_region = carve((size_t)N * 768 * 2);   // x_bf16 dead after GEMM1
    ushort_t* x_bf16 = (ushort_t*)shared_region;
    ushort_t* h_elu_b = (ushort_t*)shared_region;
    ushort_t* h2b = (ushort_t*)carve((size_t)N * 128 * 2);
    ushort_t* W1T = (ushort_t*)carve((size_t)512 * 768 * 2);
    ushort_t* W2T = (ushort_t*)carve((size_t)128 * 512 * 2);
    float* svec_part = (float*)carve(8 * 512 * 4);
    float* svec   = (float*)carve(512 * 4);
    float* e_src1 = (float*)carve((size_t)N * 4 * 4);
    float* e_dst1 = (float*)carve((size_t)N * 4 * 4);
    float* e_src2 = (float*)carve((size_t)N * 4);
    float* e_dst2 = (float*)carve((size_t)N * 4);
    int*   indeg  = (int*)carve((size_t)N * 4);
    int*   offs   = (int*)carve((size_t)(N + 1) * 4);
    int*   cursor = (int*)carve((size_t)N * 4);
    int*   csrsrc = (int*)carve((size_t)E * 4);

    size_t nx = (size_t)N * 768;
    int nbCast = (int)((nx / 8 + 255) / 256);
    int nbZero = (N + 255) / 256;
    int nbPrep = nbCast + 384 + 64 + 16 + nbZero;

    // fused prep: cast x, transpose W1/W2, svec partials, zero indeg
    prep_kernel<<<nbPrep, 256, 0, stream>>>(x, x_bf16, nx, W1, W1T, W2, W2T,
                                            sent, svec_part, indeg, N, nbCast, nbZero);
    // CSR build (+ svec reduce inside scan)
    count_kernel<<<(E + 255) / 256, 256, 0, stream>>>(ei, indeg, E);
    scan_kernel<<<1, 1024, 0, stream>>>(indeg, offs, cursor, svec_part, svec, N);
    scatter_kernel<<<(E + 255) / 256, 256, 0, stream>>>(ei, cursor, csrsrc, E);

    // GEMM1: h1b = bf16(x @ W1[:768] + svec)   [N,512]
    mfma_gemm_kernel<<<dim3((N + 127) / 128, 4), 256, 0, stream>>>(
        x_bf16, W1T, svec, h1b, N, 768, 512);

    // layer-1 attention (softmax fused into gather)
    e1_kernel<<<(N + 3) / 4, 256, 0, stream>>>(h1b, a1_src, a1_dst, e_src1, e_dst1, N);
    gather1_kernel<<<(N + 3) / 4, 256, 0, stream>>>(
        h1b, e_src1, e_dst1, offs, csrsrc, b1, h_elu_b, N);

    // GEMM2: h2b = bf16(h_elu @ W2)   [N,128]
    mfma_gemm_kernel<<<dim3((N + 127) / 128, 1), 256, 0, stream>>>(
        h_elu_b, W2T, nullptr, h2b, N, 512, 128);

    // layer-2 attention (fused)
    e2_kernel<<<(N + 3) / 4, 256, 0, stream>>>(h2b, a2_src, a2_dst, e_src2, e_dst2, N);
    gather2_kernel<<<(N + 3) / 4, 256, 0, stream>>>(
        h2b, e_src2, e_dst2, offs, csrsrc, b2, out, N);
}

// Round 9
// 295.397 us; speedup vs baseline: 2.6112x; 1.1175x over previous
//
#include <hip/hip_runtime.h>
#include <cstdint>
#include <cstddef>

#define NSLOPE 0.2f

typedef __attribute__((ext_vector_type(8))) short bf16x8;
typedef __attribute__((ext_vector_type(4))) float f32x4;
typedef __attribute__((ext_vector_type(2))) float f32x2;
typedef unsigned short ushort_t;

// ---------------------------------------------------------------- utilities
__device__ inline ushort_t f2bf(float f) {
    union { float f; unsigned u; } v; v.f = f;
    unsigned u = v.u;
    unsigned r = (u + 0x7fffu + ((u >> 16) & 1u)) >> 16;   // RNE
    return (ushort_t)r;
}
__device__ inline float bf2f(ushort_t u) {
    union { unsigned u; float f; } v; v.u = ((unsigned)u) << 16;
    return v.f;
}
__device__ inline float2 unpack_bf2(unsigned u) {
    return make_float2(bf2f((ushort_t)(u & 0xffffu)), bf2f((ushort_t)(u >> 16)));
}
// optimal 2-op unpack: lo = u<<16, hi = u & 0xffff0000
__device__ inline f32x2 unpack2(unsigned u) {
    union { unsigned u; float f; } lo, hi;
    lo.u = u << 16;
    hi.u = u & 0xffff0000u;
    f32x2 r; r.x = lo.f; r.y = hi.f;
    return r;
}
__device__ inline float leaky(float v) { return (v > 0.f) ? v : NSLOPE * v; }
__device__ inline float sel4(float4 q, bool b1, bool b2) {
    return b2 ? (b1 ? q.w : q.z) : (b1 ? q.y : q.x);
}

// ---------------------------------------------------------------- fused prep
// sections: [0,nbCast) cast x->bf16 | [.. +384) transpose W1 | [.. +64)
// transpose W2 | [.. +16) svec partials | [.. +nbZero) zero indeg
__global__ __launch_bounds__(256) void prep_kernel(
    const float* __restrict__ x, ushort_t* __restrict__ x_bf16, size_t nx,
    const float* __restrict__ W1, ushort_t* __restrict__ W1T,
    const float* __restrict__ W2, ushort_t* __restrict__ W2T,
    const float* __restrict__ sent, float* __restrict__ svec_part,
    int* __restrict__ indeg, int N, int nbCast, int nbZero)
{
    __shared__ float tile[32][33];
    int bid = blockIdx.x;
    int tid = threadIdx.x;
    if (bid < nbCast) {
        size_t i = ((size_t)bid * 256 + tid) * 8;
        if (i < nx) {
            float4 v0 = *(const float4*)(x + i);
            float4 v1 = *(const float4*)(x + i + 4);
            ushort_t r[8] = { f2bf(v0.x), f2bf(v0.y), f2bf(v0.z), f2bf(v0.w),
                              f2bf(v1.x), f2bf(v1.y), f2bf(v1.z), f2bf(v1.w) };
            *(uint4*)(x_bf16 + i) = *(uint4*)r;
        }
        return;
    }
    bid -= nbCast;
    if (bid < 384) {   // W1[768][512] -> W1T[512][768]
        int k0 = (bid % 24) * 32, n0 = (bid / 24) * 32;
        int tx = tid & 31, ty = tid >> 5;
#pragma unroll
        for (int i = 0; i < 4; ++i)
            tile[ty + i * 8][tx] = W1[(size_t)(k0 + ty + i * 8) * 512 + n0 + tx];
        __syncthreads();
#pragma unroll
        for (int i = 0; i < 4; ++i)
            W1T[(size_t)(n0 + ty + i * 8) * 768 + k0 + tx] = f2bf(tile[tx][ty + i * 8]);
        return;
    }
    bid -= 384;
    if (bid < 64) {    // W2[512][128] -> W2T[128][512]
        int k0 = (bid % 16) * 32, n0 = (bid / 16) * 32;
        int tx = tid & 31, ty = tid >> 5;
#pragma unroll
        for (int i = 0; i < 4; ++i)
            tile[ty + i * 8][tx] = W2[(size_t)(k0 + ty + i * 8) * 128 + n0 + tx];
        __syncthreads();
#pragma unroll
        for (int i = 0; i < 4; ++i)
            W2T[(size_t)(n0 + ty + i * 8) * 512 + k0 + tx] = f2bf(tile[tx][ty + i * 8]);
        return;
    }
    bid -= 64;
    if (bid < 16) {    // svec partials
        int cb = bid & 1, kb = bid >> 1;
        int c = cb * 256 + tid;
        int k0 = kb * 96;
        float acc = 0.f;
#pragma unroll 8
        for (int k = k0; k < k0 + 96; ++k)
            acc += sent[k] * W1[(size_t)(768 + k) * 512 + c];
        svec_part[kb * 512 + c] = acc;
        return;
    }
    bid -= 16;
    {                  // zero indeg
        int i = bid * 256 + tid;
        if (i < N) indeg[i] = 0;
    }
}

// ---------------------------------------------------------------- MFMA GEMM
// + fused attention-coefficient epilogue: for col-block y, computes
// e_src[row*eStride+y] = sum_cols val*asrc[col]  (asrc flat-indexed by global
// col; for layer1 col == head*128+c so a1_src flat works directly).
__device__ inline void async_copy16(const void* g, void* l) {
    __builtin_amdgcn_global_load_lds(
        (const __attribute__((address_space(1))) unsigned int*)g,
        (__attribute__((address_space(3))) unsigned int*)l, 16, 0, 0);
}

__global__ __launch_bounds__(256) void mfma_gemm_kernel(
    const ushort_t* __restrict__ A,   // [M][K] bf16
    const ushort_t* __restrict__ BT,  // [Nc][K] bf16
    const float* __restrict__ bias,   // [Nc] or null
    ushort_t* __restrict__ Cb,        // [M][Nc] bf16
    const float* __restrict__ asrc,   // [Nc] flat attention vec (src)
    const float* __restrict__ adst,   // [Nc] flat attention vec (dst)
    float* __restrict__ e_src,        // [M*eStride]
    float* __restrict__ e_dst,
    int eStride,
    int M, int K, int Nc)
{
    __shared__ __align__(16) ushort_t lA[128 * 32];
    __shared__ __align__(16) ushort_t lB[128 * 32];
    __shared__ float e_lds[128][2][2];   // [row_local][col_half][src/dst]
    const int tid = threadIdx.x;
    const int wave = tid >> 6;
    const int lane = tid & 63;
    const int row0 = blockIdx.x * 128;
    const int col0 = blockIdx.y * 128;
    const int wm = (wave & 1) * 64;
    const int wn = (wave >> 1) * 64;
    const int q = lane >> 4;
    const int ml = lane & 15;

    f32x4 acc[4][4] = {};

    int rowS[2], gS[2];
#pragma unroll
    for (int i = 0; i < 2; ++i) {
        int p = wave * 128 + i * 64 + lane;
        int r = p >> 2, s = p & 3;
        rowS[i] = r;
        gS[i] = s ^ ((r >> 1) & 3);
    }

    for (int k0 = 0; k0 < K; k0 += 32) {
#pragma unroll
        for (int i = 0; i < 2; ++i) {
            int pb = wave * 128 + i * 64;
            int r = rowS[i];
            int ga = min(row0 + r, M - 1);
            async_copy16(A + (size_t)ga * K + k0 + gS[i] * 8, &lA[(size_t)pb * 8]);
            async_copy16(BT + (size_t)(col0 + r) * K + k0 + gS[i] * 8, &lB[(size_t)pb * 8]);
        }
        __syncthreads();
        bf16x8 af[4], bfr[4];
#pragma unroll
        for (int t = 0; t < 4; ++t) {
            int m = wm + t * 16 + ml;
            af[t] = *(const bf16x8*)&lA[(size_t)(m * 4 + (q ^ ((m >> 1) & 3))) * 8];
            int n = wn + t * 16 + ml;
            bfr[t] = *(const bf16x8*)&lB[(size_t)(n * 4 + (q ^ ((n >> 1) & 3))) * 8];
        }
#pragma unroll
        for (int tm = 0; tm < 4; ++tm)
#pragma unroll
            for (int tn = 0; tn < 4; ++tn)
                acc[tm][tn] = __builtin_amdgcn_mfma_f32_16x16x32_bf16(
                    af[tm], bfr[tn], acc[tm][tn], 0, 0, 0);
        __syncthreads();
    }

    float es_acc[4][4] = {};   // [tm][r]
    float ed_acc[4][4] = {};
#pragma unroll
    for (int tm = 0; tm < 4; ++tm) {
        int rbase = row0 + wm + tm * 16 + q * 4;
#pragma unroll
        for (int tn = 0; tn < 4; ++tn) {
            int col = col0 + wn + tn * 16 + ml;
            float bb = bias ? bias[col] : 0.f;
            float av = asrc[col];
            float dv = adst[col];
#pragma unroll
            for (int r = 0; r < 4; ++r) {
                int row = rbase + r;
                float val = acc[tm][tn][r] + bb;
                if (row < M)
                    Cb[(size_t)row * Nc + col] = f2bf(val);
                es_acc[tm][r] += val * av;
                ed_acc[tm][r] += val * dv;
            }
        }
    }
    // reduce over the 16-lane col groups (xor 1,2,4,8 keeps q fixed)
    const int colhalf = wave >> 1;
#pragma unroll
    for (int tm = 0; tm < 4; ++tm) {
#pragma unroll
        for (int r = 0; r < 4; ++r) {
            float es = es_acc[tm][r], ed2 = ed_acc[tm][r];
#pragma unroll
            for (int st = 1; st < 16; st <<= 1) {
                es += __shfl_xor(es, st);
                ed2 += __shfl_xor(ed2, st);
            }
            if (ml == 0) {
                int rl = wm + tm * 16 + q * 4 + r;
                e_lds[rl][colhalf][0] = es;
                e_lds[rl][colhalf][1] = ed2;
            }
        }
    }
    __syncthreads();
    if (tid < 128) {
        int row = row0 + tid;
        if (row < M) {
            float es = e_lds[tid][0][0] + e_lds[tid][1][0];
            float ed2 = e_lds[tid][0][1] + e_lds[tid][1][1];
            e_src[(size_t)row * eStride + blockIdx.y] = es;
            e_dst[(size_t)row * eStride + blockIdx.y] = ed2;
        }
    }
}

// ---------------------------------------------------------------- CSR build
__global__ void count_kernel(const int* __restrict__ ei, int* __restrict__ indeg, int E) {
    int e = blockIdx.x * blockDim.x + threadIdx.x;
    if (e < E) atomicAdd(&indeg[ei[E + e]], 1);
}

__global__ __launch_bounds__(1024) void scan_kernel(const int* __restrict__ indeg,
                                                    int* __restrict__ offsets,
                                                    int* __restrict__ cursor,
                                                    const float* __restrict__ svec_part,
                                                    float* __restrict__ svec, int N) {
    __shared__ int partial[1024];
    int tid = threadIdx.x;
    if (tid < 512) {
        float s = 0.f;
#pragma unroll
        for (int kb = 0; kb < 8; ++kb) s += svec_part[kb * 512 + tid];
        svec[tid] = s;
    }
    int per = (N + 1023) / 1024;
    int start = tid * per;
    int end = min(start + per, N);
    int sum = 0;
    if (start + per <= N && (per & 3) == 0) {
        for (int i = 0; i < per; i += 4) {
            int4 v = *(const int4*)(indeg + start + i);
            sum += v.x + v.y + v.z + v.w;
        }
    } else {
        for (int i = start; i < end; ++i) sum += indeg[i];
    }
    partial[tid] = sum;
    __syncthreads();
    for (int st = 1; st < 1024; st <<= 1) {
        int v = (tid >= st) ? partial[tid - st] : 0;
        __syncthreads();
        partial[tid] += v;
        __syncthreads();
    }
    int run = (tid == 0) ? 0 : partial[tid - 1];
    if (start + per <= N && (per & 3) == 0) {
        for (int i = 0; i < per; i += 4) {
            int4 v = *(const int4*)(indeg + start + i);
            int4 o;
            o.x = run;
            o.y = o.x + v.x;
            o.z = o.y + v.y;
            o.w = o.z + v.z;
            run = o.w + v.w;
            *(int4*)(offsets + start + i) = o;
            *(int4*)(cursor + start + i) = o;
        }
    } else {
        for (int i = start; i < end; ++i) {
            offsets[i] = run; cursor[i] = run;
            run += indeg[i];
        }
    }
    if (tid == 1023) offsets[N] = run;
}

__global__ void scatter_kernel(const int* __restrict__ ei, int* __restrict__ cursor,
                               int* __restrict__ csr_src, int E) {
    int e = blockIdx.x * blockDim.x + threadIdx.x;
    if (e < E) {
        int d = ei[E + e];
        int p = atomicAdd(&cursor[d], 1);
        csr_src[p] = ei[e];
    }
}

// ---------------------------------------------------------------- gather+softmax
// layer 1: wave per node. Phase A: per-lane online softmax (m,s per head) over
// strided edges + butterfly merge. Gather loop: wave-uniform edge index ->
// scalar csr/e_src loads, w computed inline; lane owns 8 contiguous channels.
__global__ __launch_bounds__(256) void gather1_kernel(
    const ushort_t* __restrict__ h1b, const float* __restrict__ e_src,
    const float* __restrict__ e_dst, const int* __restrict__ offsets,
    const int* __restrict__ csr_src, const float* __restrict__ bias,
    ushort_t* __restrict__ outb, int N)
{
    int node = __builtin_amdgcn_readfirstlane(blockIdx.x * 4 + (threadIdx.x >> 6));
    int lane = threadIdx.x & 63;
    if (node >= N) return;
    int beg = offsets[node], end = offsets[node + 1];
    float4 ed = *(const float4*)&e_dst[node * 4];

    // phase A: online softmax stats per head
    float m[4] = { -1e30f, -1e30f, -1e30f, -1e30f };
    float s[4] = { 0.f, 0.f, 0.f, 0.f };
    for (int j = beg + lane; j < end; j += 64) {
        int sid = csr_src[j];
        float4 es = *(const float4*)&e_src[sid * 4];
        float e[4] = { leaky(es.x + ed.x), leaky(es.y + ed.y),
                       leaky(es.z + ed.z), leaky(es.w + ed.w) };
#pragma unroll
        for (int hh = 0; hh < 4; ++hh) {
            float nm = fmaxf(m[hh], e[hh]);
            s[hh] = s[hh] * __expf(m[hh] - nm) + __expf(e[hh] - nm);
            m[hh] = nm;
        }
    }
#pragma unroll
    for (int st = 32; st >= 1; st >>= 1) {
#pragma unroll
        for (int hh = 0; hh < 4; ++hh) {
            float om = __shfl_xor(m[hh], st);
            float os = __shfl_xor(s[hh], st);
            float nm = fmaxf(m[hh], om);
            s[hh] = s[hh] * __expf(m[hh] - nm) + os * __expf(om - nm);
            m[hh] = nm;
        }
    }
    // per-lane head constants
    const int h = lane >> 4;
    const bool b1 = (h & 1), b2 = (h & 2);
    float mh  = b2 ? (b1 ? m[3] : m[2]) : (b1 ? m[1] : m[0]);
    float sh  = b2 ? (b1 ? s[3] : s[2]) : (b1 ? s[1] : s[0]);
    float rsh = 1.f / (sh + 1e-16f);
    float edh = sel4(ed, b1, b2);

    const ushort_t* hp = h1b + lane * 8;
    f32x2 acc[4] = {};
    int j = beg;
#pragma unroll 2
    for (; j + 4 <= end; j += 4) {
        int s0 = csr_src[j], s1 = csr_src[j + 1];          // scalar
        int s2 = csr_src[j + 2], s3 = csr_src[j + 3];
        float4 q0 = *(const float4*)&e_src[s0 * 4];        // scalar 16B
        float4 q1 = *(const float4*)&e_src[s1 * 4];
        float4 q2 = *(const float4*)&e_src[s2 * 4];
        float4 q3 = *(const float4*)&e_src[s3 * 4];
        float w0 = __expf(leaky(sel4(q0, b1, b2) + edh) - mh) * rsh;
        float w1 = __expf(leaky(sel4(q1, b1, b2) + edh) - mh) * rsh;
        float w2 = __expf(leaky(sel4(q2, b1, b2) + edh) - mh) * rsh;
        float w3 = __expf(leaky(sel4(q3, b1, b2) + edh) - mh) * rsh;
        uint4 u0 = *(const uint4*)&hp[(size_t)s0 * 512];
        uint4 u1 = *(const uint4*)&hp[(size_t)s1 * 512];
        uint4 u2 = *(const uint4*)&hp[(size_t)s2 * 512];
        uint4 u3 = *(const uint4*)&hp[(size_t)s3 * 512];
        f32x2 wv;
        wv.x = w0; wv.y = w0;
        acc[0] += unpack2(u0.x) * wv; acc[1] += unpack2(u0.y) * wv;
        acc[2] += unpack2(u0.z) * wv; acc[3] += unpack2(u0.w) * wv;
        wv.x = w1; wv.y = w1;
        acc[0] += unpack2(u1.x) * wv; acc[1] += unpack2(u1.y) * wv;
        acc[2] += unpack2(u1.z) * wv; acc[3] += unpack2(u1.w) * wv;
        wv.x = w2; wv.y = w2;
        acc[0] += unpack2(u2.x) * wv; acc[1] += unpack2(u2.y) * wv;
        acc[2] += unpack2(u2.z) * wv; acc[3] += unpack2(u2.w) * wv;
        wv.x = w3; wv.y = w3;
        acc[0] += unpack2(u3.x) * wv; acc[1] += unpack2(u3.y) * wv;
        acc[2] += unpack2(u3.z) * wv; acc[3] += unpack2(u3.w) * wv;
    }
    for (; j < end; ++j) {
        int s0 = csr_src[j];
        float4 q0 = *(const float4*)&e_src[s0 * 4];
        float w0 = __expf(leaky(sel4(q0, b1, b2) + edh) - mh) * rsh;
        uint4 u0 = *(const uint4*)&hp[(size_t)s0 * 512];
        f32x2 wv; wv.x = w0; wv.y = w0;
        acc[0] += unpack2(u0.x) * wv; acc[1] += unpack2(u0.y) * wv;
        acc[2] += unpack2(u0.z) * wv; acc[3] += unpack2(u0.w) * wv;
    }
    int c = lane * 8;
    ushort_t o[8];
#pragma unroll
    for (int i = 0; i < 4; ++i) {
        float r0 = acc[i].x + bias[c + 2 * i];
        float r1 = acc[i].y + bias[c + 2 * i + 1];
        r0 = (r0 > 0.f) ? r0 : (__expf(r0) - 1.f);
        r1 = (r1 > 0.f) ? r1 : (__expf(r1) - 1.f);
        o[2 * i] = f2bf(r0);
        o[2 * i + 1] = f2bf(r1);
    }
    *(uint4*)&outb[(size_t)node * 512 + c] = *(uint4*)o;
}

// layer 2: wave per node, 1 head; same fused structure; fp32 output.
__global__ __launch_bounds__(256) void gather2_kernel(
    const ushort_t* __restrict__ h2b, const float* __restrict__ e_src,
    const float* __restrict__ e_dst, const int* __restrict__ offsets,
    const int* __restrict__ csr_src, const float* __restrict__ bias,
    float* __restrict__ out, int N)
{
    int node = __builtin_amdgcn_readfirstlane(blockIdx.x * 4 + (threadIdx.x >> 6));
    int lane = threadIdx.x & 63;
    if (node >= N) return;
    int beg = offsets[node], end = offsets[node + 1];
    float ed = e_dst[node];

    // phase A
    float m = -1e30f, s = 0.f;
    for (int j = beg + lane; j < end; j += 64) {
        float e = leaky(e_src[csr_src[j]] + ed);
        float nm = fmaxf(m, e);
        s = s * __expf(m - nm) + __expf(e - nm);
        m = nm;
    }
#pragma unroll
    for (int st = 32; st >= 1; st >>= 1) {
        float om = __shfl_xor(m, st);
        float os = __shfl_xor(s, st);
        float nm = fmaxf(m, om);
        s = s * __expf(m - nm) + os * __expf(om - nm);
        m = nm;
    }
    float rs = 1.f / (s + 1e-16f);

    const ushort_t* hp = h2b + lane * 2;
    f32x2 acc = { 0.f, 0.f };
    int j = beg;
#pragma unroll 2
    for (; j + 4 <= end; j += 4) {
        int s0 = csr_src[j], s1 = csr_src[j + 1];
        int s2 = csr_src[j + 2], s3 = csr_src[j + 3];
        float w0 = __expf(leaky(e_src[s0] + ed) - m) * rs;
        float w1 = __expf(leaky(e_src[s1] + ed) - m) * rs;
        float w2 = __expf(leaky(e_src[s2] + ed) - m) * rs;
        float w3 = __expf(leaky(e_src[s3] + ed) - m) * rs;
        unsigned u0 = *(const unsigned*)&hp[(size_t)s0 * 128];
        unsigned u1 = *(const unsigned*)&hp[(size_t)s1 * 128];
        unsigned u2 = *(const unsigned*)&hp[(size_t)s2 * 128];
        unsigned u3 = *(const unsigned*)&hp[(size_t)s3 * 128];
        f32x2 w0v = { w0, w0 }, w1v = { w1, w1 }, w2v = { w2, w2 }, w3v = { w3, w3 };
        acc += unpack2(u0) * w0v;
        acc += unpack2(u1) * w1v;
        acc += unpack2(u2) * w2v;
        acc += unpack2(u3) * w3v;
    }
    for (; j < end; ++j) {
        int s0 = csr_src[j];
        float w0 = __expf(leaky(e_src[s0] + ed) - m) * rs;
        unsigned u0 = *(const unsigned*)&hp[(size_t)s0 * 128];
        f32x2 w0v = { w0, w0 };
        acc += unpack2(u0) * w0v;
    }
    float2 o = make_float2(acc.x + bias[lane * 2], acc.y + bias[lane * 2 + 1]);
    *(float2*)&out[(size_t)node * 128 + lane * 2] = o;
}

// ---------------------------------------------------------------- launch
extern "C" void kernel_launch(void* const* d_in, const int* in_sizes, int n_in,
                              void* d_out, int out_size, void* d_ws, size_t ws_size,
                              hipStream_t stream) {
    const float* x      = (const float*)d_in[0];
    const int*   ei     = (const int*)  d_in[1];
    const float* sent   = (const float*)d_in[2];
    const float* W1     = (const float*)d_in[3];
    const float* a1_src = (const float*)d_in[4];
    const float* a1_dst = (const float*)d_in[5];
    const float* b1     = (const float*)d_in[6];
    const float* W2     = (const float*)d_in[7];
    const float* a2_src = (const float*)d_in[8];
    const float* a2_dst = (const float*)d_in[9];
    const float* b2     = (const float*)d_in[10];
    float* out = (float*)d_out;

    const int N = in_sizes[0] / 768;   // 20000
    const int E = in_sizes[1] / 2;     // 320000

    char* p = (char*)d_ws;
    auto carve = [&](size_t bytes) {
        char* q = p;
        p += (bytes + 255) & ~(size_t)255;
        return q;
    };
    ushort_t* h1b = (ushort_t*)carve((size_t)N * 512 * 2);
    char* shared_region = carve((size_t)N * 768 * 2);   // x_bf16 dead after GEMM1
    ushort_t* x_bf16 = (ushort_t*)shared_region;
    ushort_t* h_elu_b = (ushort_t*)shared_region;
    ushort_t* h2b = (ushort_t*)carve((size_t)N * 128 * 2);
    ushort_t* W1T = (ushort_t*)carve((size_t)512 * 768 * 2);
    ushort_t* W2T = (ushort_t*)carve((size_t)128 * 512 * 2);
    float* svec_part = (float*)carve(8 * 512 * 4);
    float* svec   = (float*)carve(512 * 4);
    float* e_src1 = (float*)carve((size_t)N * 4 * 4);
    float* e_dst1 = (float*)carve((size_t)N * 4 * 4);
    float* e_src2 = (float*)carve((size_t)N * 4);
    float* e_dst2 = (float*)carve((size_t)N * 4);
    int*   indeg  = (int*)carve((size_t)N * 4);
    int*   offs   = (int*)carve((size_t)(N + 1) * 4);
    int*   cursor = (int*)carve((size_t)N * 4);
    int*   csrsrc = (int*)carve((size_t)E * 4);

    size_t nx = (size_t)N * 768;
    int nbCast = (int)((nx / 8 + 255) / 256);
    int nbZero = (N + 255) / 256;
    int nbPrep = nbCast + 384 + 64 + 16 + nbZero;

    // fused prep: cast x, transpose W1/W2, svec partials, zero indeg
    prep_kernel<<<nbPrep, 256, 0, stream>>>(x, x_bf16, nx, W1, W1T, W2, W2T,
                                            sent, svec_part, indeg, N, nbCast, nbZero);
    // CSR build (+ svec reduce inside scan)
    count_kernel<<<(E + 255) / 256, 256, 0, stream>>>(ei, indeg, E);
    scan_kernel<<<1, 1024, 0, stream>>>(indeg, offs, cursor, svec_part, svec, N);
    scatter_kernel<<<(E + 255) / 256, 256, 0, stream>>>(ei, cursor, csrsrc, E);

    // GEMM1: h1b = bf16(x @ W1[:768] + svec), fused e1  [N,512]
    mfma_gemm_kernel<<<dim3((N + 127) / 128, 4), 256, 0, stream>>>(
        x_bf16, W1T, svec, h1b, a1_src, a1_dst, e_src1, e_dst1, 4, N, 768, 512);

    // layer-1 attention (softmax fused into gather)
    gather1_kernel<<<(N + 3) / 4, 256, 0, stream>>>(
        h1b, e_src1, e_dst1, offs, csrsrc, b1, h_elu_b, N);

    // GEMM2: h2b = bf16(h_elu @ W2), fused e2  [N,128]
    mfma_gemm_kernel<<<dim3((N + 127) / 128, 1), 256, 0, stream>>>(
        h_elu_b, W2T, nullptr, h2b, a2_src, a2_dst, e_src2, e_dst2, 1, N, 512, 128);

    // layer-2 attention (fused)
    gather2_kernel<<<(N + 3) / 4, 256, 0, stream>>>(
        h2b, e_src2, e_dst2, offs, csrsrc, b2, out, N);
}

// Round 10
// 295.219 us; speedup vs baseline: 2.6128x; 1.0006x over previous
//
#include <hip/hip_runtime.h>
#include <cstdint>
#include <cstddef>

#define NSLOPE 0.2f

typedef __attribute__((ext_vector_type(8))) short bf16x8;
typedef __attribute__((ext_vector_type(4))) float f32x4;
typedef __attribute__((ext_vector_type(2))) float f32x2;
typedef unsigned short ushort_t;

// ---------------------------------------------------------------- utilities
__device__ inline ushort_t f2bf(float f) {
    union { float f; unsigned u; } v; v.f = f;
    unsigned u = v.u;
    unsigned r = (u + 0x7fffu + ((u >> 16) & 1u)) >> 16;   // RNE
    return (ushort_t)r;
}
__device__ inline float bf2f(ushort_t u) {
    union { unsigned u; float f; } v; v.u = ((unsigned)u) << 16;
    return v.f;
}
__device__ inline float2 unpack_bf2(unsigned u) {
    return make_float2(bf2f((ushort_t)(u & 0xffffu)), bf2f((ushort_t)(u >> 16)));
}
// optimal 2-op unpack: lo = u<<16, hi = u & 0xffff0000
__device__ inline f32x2 unpack2(unsigned u) {
    union { unsigned u; float f; } lo, hi;
    lo.u = u << 16;
    hi.u = u & 0xffff0000u;
    f32x2 r; r.x = lo.f; r.y = hi.f;
    return r;
}
__device__ inline float leaky(float v) { return (v > 0.f) ? v : NSLOPE * v; }
__device__ inline float sel4(float4 q, bool b1, bool b2) {
    return b2 ? (b1 ? q.w : q.z) : (b1 ? q.y : q.x);
}

// ---------------------------------------------------------------- fused prep
// sections: [0,nbCast) cast x->bf16 | [.. +384) transpose W1 | [.. +64)
// transpose W2 | [.. +16) svec partials | [.. +nbZero) zero indeg
__global__ __launch_bounds__(256) void prep_kernel(
    const float* __restrict__ x, ushort_t* __restrict__ x_bf16, size_t nx,
    const float* __restrict__ W1, ushort_t* __restrict__ W1T,
    const float* __restrict__ W2, ushort_t* __restrict__ W2T,
    const float* __restrict__ sent, float* __restrict__ svec_part,
    int* __restrict__ indeg, int N, int nbCast, int nbZero)
{
    __shared__ float tile[32][33];
    int bid = blockIdx.x;
    int tid = threadIdx.x;
    if (bid < nbCast) {
        size_t i = ((size_t)bid * 256 + tid) * 8;
        if (i < nx) {
            float4 v0 = *(const float4*)(x + i);
            float4 v1 = *(const float4*)(x + i + 4);
            ushort_t r[8] = { f2bf(v0.x), f2bf(v0.y), f2bf(v0.z), f2bf(v0.w),
                              f2bf(v1.x), f2bf(v1.y), f2bf(v1.z), f2bf(v1.w) };
            *(uint4*)(x_bf16 + i) = *(uint4*)r;
        }
        return;
    }
    bid -= nbCast;
    if (bid < 384) {   // W1[768][512] -> W1T[512][768]
        int k0 = (bid % 24) * 32, n0 = (bid / 24) * 32;
        int tx = tid & 31, ty = tid >> 5;
#pragma unroll
        for (int i = 0; i < 4; ++i)
            tile[ty + i * 8][tx] = W1[(size_t)(k0 + ty + i * 8) * 512 + n0 + tx];
        __syncthreads();
#pragma unroll
        for (int i = 0; i < 4; ++i)
            W1T[(size_t)(n0 + ty + i * 8) * 768 + k0 + tx] = f2bf(tile[tx][ty + i * 8]);
        return;
    }
    bid -= 384;
    if (bid < 64) {    // W2[512][128] -> W2T[128][512]
        int k0 = (bid % 16) * 32, n0 = (bid / 16) * 32;
        int tx = tid & 31, ty = tid >> 5;
#pragma unroll
        for (int i = 0; i < 4; ++i)
            tile[ty + i * 8][tx] = W2[(size_t)(k0 + ty + i * 8) * 128 + n0 + tx];
        __syncthreads();
#pragma unroll
        for (int i = 0; i < 4; ++i)
            W2T[(size_t)(n0 + ty + i * 8) * 512 + k0 + tx] = f2bf(tile[tx][ty + i * 8]);
        return;
    }
    bid -= 64;
    if (bid < 16) {    // svec partials
        int cb = bid & 1, kb = bid >> 1;
        int c = cb * 256 + tid;
        int k0 = kb * 96;
        float acc = 0.f;
#pragma unroll 8
        for (int k = k0; k < k0 + 96; ++k)
            acc += sent[k] * W1[(size_t)(768 + k) * 512 + c];
        svec_part[kb * 512 + c] = acc;
        return;
    }
    bid -= 16;
    {                  // zero indeg
        int i = bid * 256 + tid;
        if (i < N) indeg[i] = 0;
    }
}

// ---------------------------------------------------------------- MFMA GEMM
// Double-buffered LDS staging; grid is (col_blocks, row_blocks) so consecutive
// blocks share the A-row panel (L2 reuse of A). Fused attention-coefficient
// epilogue writes e_src/e_dst[row*eStride + blockIdx.x].
__device__ inline void async_copy16(const void* g, void* l) {
    __builtin_amdgcn_global_load_lds(
        (const __attribute__((address_space(1))) unsigned int*)g,
        (__attribute__((address_space(3))) unsigned int*)l, 16, 0, 0);
}

__global__ __launch_bounds__(256) void mfma_gemm_kernel(
    const ushort_t* __restrict__ A,   // [M][K] bf16
    const ushort_t* __restrict__ BT,  // [Nc][K] bf16
    const float* __restrict__ bias,   // [Nc] or null
    ushort_t* __restrict__ Cb,        // [M][Nc] bf16
    const float* __restrict__ asrc,   // [Nc] flat attention vec (src)
    const float* __restrict__ adst,   // [Nc] flat attention vec (dst)
    float* __restrict__ e_src,        // [M*eStride]
    float* __restrict__ e_dst,
    int eStride,
    int M, int K, int Nc)
{
    __shared__ __align__(16) ushort_t lA[2][128 * 32];
    __shared__ __align__(16) ushort_t lB[2][128 * 32];
    __shared__ float e_lds[128][2][2];   // [row_local][col_half][src/dst]
    const int tid = threadIdx.x;
    const int wave = tid >> 6;
    const int lane = tid & 63;
    const int col0 = blockIdx.x * 128;
    const int row0 = blockIdx.y * 128;
    const int wm = (wave & 1) * 64;
    const int wn = (wave >> 1) * 64;
    const int q = lane >> 4;
    const int ml = lane & 15;

    f32x4 acc[4][4] = {};

    int rowS[2], gS[2];
#pragma unroll
    for (int i = 0; i < 2; ++i) {
        int p = wave * 128 + i * 64 + lane;
        int r = p >> 2, s = p & 3;
        rowS[i] = r;
        gS[i] = s ^ ((r >> 1) & 3);
    }

    auto stage = [&](int k0, int buf) {
#pragma unroll
        for (int i = 0; i < 2; ++i) {
            int pb = wave * 128 + i * 64;
            int r = rowS[i];
            int ga = min(row0 + r, M - 1);
            async_copy16(A + (size_t)ga * K + k0 + gS[i] * 8, &lA[buf][(size_t)pb * 8]);
            async_copy16(BT + (size_t)(col0 + r) * K + k0 + gS[i] * 8, &lB[buf][(size_t)pb * 8]);
        }
    };

    stage(0, 0);
    __syncthreads();               // drain prologue loads
    int pb = 0;
    for (int k0 = 0; k0 < K; k0 += 32) {
        if (k0 + 32 < K) stage(k0 + 32, pb ^ 1);   // overlap next tile's latency
        bf16x8 af[4], bfr[4];
#pragma unroll
        for (int t = 0; t < 4; ++t) {
            int m = wm + t * 16 + ml;
            af[t] = *(const bf16x8*)&lA[pb][(size_t)(m * 4 + (q ^ ((m >> 1) & 3))) * 8];
            int n = wn + t * 16 + ml;
            bfr[t] = *(const bf16x8*)&lB[pb][(size_t)(n * 4 + (q ^ ((n >> 1) & 3))) * 8];
        }
#pragma unroll
        for (int tm = 0; tm < 4; ++tm)
#pragma unroll
            for (int tn = 0; tn < 4; ++tn)
                acc[tm][tn] = __builtin_amdgcn_mfma_f32_16x16x32_bf16(
                    af[tm], bfr[tn], acc[tm][tn], 0, 0, 0);
        __syncthreads();           // waves done reading pb; next-tile loads drained
        pb ^= 1;
    }

    float es_acc[4][4] = {};   // [tm][r]
    float ed_acc[4][4] = {};
#pragma unroll
    for (int tm = 0; tm < 4; ++tm) {
        int rbase = row0 + wm + tm * 16 + q * 4;
#pragma unroll
        for (int tn = 0; tn < 4; ++tn) {
            int col = col0 + wn + tn * 16 + ml;
            float bb = bias ? bias[col] : 0.f;
            float av = asrc[col];
            float dv = adst[col];
#pragma unroll
            for (int r = 0; r < 4; ++r) {
                int row = rbase + r;
                float val = acc[tm][tn][r] + bb;
                if (row < M)
                    Cb[(size_t)row * Nc + col] = f2bf(val);
                es_acc[tm][r] += val * av;
                ed_acc[tm][r] += val * dv;
            }
        }
    }
    // reduce over the 16-lane col groups (xor 1,2,4,8 keeps q fixed)
    const int colhalf = wave >> 1;
#pragma unroll
    for (int tm = 0; tm < 4; ++tm) {
#pragma unroll
        for (int r = 0; r < 4; ++r) {
            float es = es_acc[tm][r], ed2 = ed_acc[tm][r];
#pragma unroll
            for (int st = 1; st < 16; st <<= 1) {
                es += __shfl_xor(es, st);
                ed2 += __shfl_xor(ed2, st);
            }
            if (ml == 0) {
                int rl = wm + tm * 16 + q * 4 + r;
                e_lds[rl][colhalf][0] = es;
                e_lds[rl][colhalf][1] = ed2;
            }
        }
    }
    __syncthreads();
    if (tid < 128) {
        int row = row0 + tid;
        if (row < M) {
            float es = e_lds[tid][0][0] + e_lds[tid][1][0];
            float ed2 = e_lds[tid][0][1] + e_lds[tid][1][1];
            e_src[(size_t)row * eStride + blockIdx.x] = es;
            e_dst[(size_t)row * eStride + blockIdx.x] = ed2;
        }
    }
}

// ---------------------------------------------------------------- CSR build
__global__ void count_kernel(const int* __restrict__ ei, int* __restrict__ indeg, int E) {
    int e = blockIdx.x * blockDim.x + threadIdx.x;
    if (e < E) atomicAdd(&indeg[ei[E + e]], 1);
}

__global__ __launch_bounds__(1024) void scan_kernel(const int* __restrict__ indeg,
                                                    int* __restrict__ offsets,
                                                    int* __restrict__ cursor,
                                                    const float* __restrict__ svec_part,
                                                    float* __restrict__ svec, int N) {
    __shared__ int partial[1024];
    int tid = threadIdx.x;
    if (tid < 512) {
        float s = 0.f;
#pragma unroll
        for (int kb = 0; kb < 8; ++kb) s += svec_part[kb * 512 + tid];
        svec[tid] = s;
    }
    int per = (N + 1023) / 1024;
    int start = tid * per;
    int end = min(start + per, N);
    int sum = 0;
    if (start + per <= N && (per & 3) == 0) {
        for (int i = 0; i < per; i += 4) {
            int4 v = *(const int4*)(indeg + start + i);
            sum += v.x + v.y + v.z + v.w;
        }
    } else {
        for (int i = start; i < end; ++i) sum += indeg[i];
    }
    partial[tid] = sum;
    __syncthreads();
    for (int st = 1; st < 1024; st <<= 1) {
        int v = (tid >= st) ? partial[tid - st] : 0;
        __syncthreads();
        partial[tid] += v;
        __syncthreads();
    }
    int run = (tid == 0) ? 0 : partial[tid - 1];
    if (start + per <= N && (per & 3) == 0) {
        for (int i = 0; i < per; i += 4) {
            int4 v = *(const int4*)(indeg + start + i);
            int4 o;
            o.x = run;
            o.y = o.x + v.x;
            o.z = o.y + v.y;
            o.w = o.z + v.z;
            run = o.w + v.w;
            *(int4*)(offsets + start + i) = o;
            *(int4*)(cursor + start + i) = o;
        }
    } else {
        for (int i = start; i < end; ++i) {
            offsets[i] = run; cursor[i] = run;
            run += indeg[i];
        }
    }
    if (tid == 1023) offsets[N] = run;
}

__global__ void scatter_kernel(const int* __restrict__ ei, int* __restrict__ cursor,
                               int* __restrict__ csr_src, int E) {
    int e = blockIdx.x * blockDim.x + threadIdx.x;
    if (e < E) {
        int d = ei[E + e];
        int p = atomicAdd(&cursor[d], 1);
        csr_src[p] = ei[e];
    }
}

// ---------------------------------------------------------------- gather+softmax
// layer 1: wave per node. Phase A: per-lane online softmax (m,s per head) over
// strided edges + butterfly merge. Gather loop: wave-uniform edge index ->
// scalar csr/e_src loads, w computed inline; lane owns 8 contiguous channels.
__global__ __launch_bounds__(256) void gather1_kernel(
    const ushort_t* __restrict__ h1b, const float* __restrict__ e_src,
    const float* __restrict__ e_dst, const int* __restrict__ offsets,
    const int* __restrict__ csr_src, const float* __restrict__ bias,
    ushort_t* __restrict__ outb, int N)
{
    int node = __builtin_amdgcn_readfirstlane(blockIdx.x * 4 + (threadIdx.x >> 6));
    int lane = threadIdx.x & 63;
    if (node >= N) return;
    int beg = offsets[node], end = offsets[node + 1];
    float4 ed = *(const float4*)&e_dst[node * 4];

    // phase A: online softmax stats per head
    float m[4] = { -1e30f, -1e30f, -1e30f, -1e30f };
    float s[4] = { 0.f, 0.f, 0.f, 0.f };
    for (int j = beg + lane; j < end; j += 64) {
        int sid = csr_src[j];
        float4 es = *(const float4*)&e_src[sid * 4];
        float e[4] = { leaky(es.x + ed.x), leaky(es.y + ed.y),
                       leaky(es.z + ed.z), leaky(es.w + ed.w) };
#pragma unroll
        for (int hh = 0; hh < 4; ++hh) {
            float nm = fmaxf(m[hh], e[hh]);
            s[hh] = s[hh] * __expf(m[hh] - nm) + __expf(e[hh] - nm);
            m[hh] = nm;
        }
    }
#pragma unroll
    for (int st = 32; st >= 1; st >>= 1) {
#pragma unroll
        for (int hh = 0; hh < 4; ++hh) {
            float om = __shfl_xor(m[hh], st);
            float os = __shfl_xor(s[hh], st);
            float nm = fmaxf(m[hh], om);
            s[hh] = s[hh] * __expf(m[hh] - nm) + os * __expf(om - nm);
            m[hh] = nm;
        }
    }
    // per-lane head constants
    const int h = lane >> 4;
    const bool b1 = (h & 1), b2 = (h & 2);
    float mh  = b2 ? (b1 ? m[3] : m[2]) : (b1 ? m[1] : m[0]);
    float sh  = b2 ? (b1 ? s[3] : s[2]) : (b1 ? s[1] : s[0]);
    float rsh = 1.f / (sh + 1e-16f);
    float edh = sel4(ed, b1, b2);

    const ushort_t* hp = h1b + lane * 8;
    f32x2 acc[4] = {};
    int j = beg;
#pragma unroll 2
    for (; j + 4 <= end; j += 4) {
        int s0 = csr_src[j], s1 = csr_src[j + 1];          // scalar
        int s2 = csr_src[j + 2], s3 = csr_src[j + 3];
        float4 q0 = *(const float4*)&e_src[s0 * 4];        // scalar 16B
        float4 q1 = *(const float4*)&e_src[s1 * 4];
        float4 q2 = *(const float4*)&e_src[s2 * 4];
        float4 q3 = *(const float4*)&e_src[s3 * 4];
        float w0 = __expf(leaky(sel4(q0, b1, b2) + edh) - mh) * rsh;
        float w1 = __expf(leaky(sel4(q1, b1, b2) + edh) - mh) * rsh;
        float w2 = __expf(leaky(sel4(q2, b1, b2) + edh) - mh) * rsh;
        float w3 = __expf(leaky(sel4(q3, b1, b2) + edh) - mh) * rsh;
        uint4 u0 = *(const uint4*)&hp[(size_t)s0 * 512];
        uint4 u1 = *(const uint4*)&hp[(size_t)s1 * 512];
        uint4 u2 = *(const uint4*)&hp[(size_t)s2 * 512];
        uint4 u3 = *(const uint4*)&hp[(size_t)s3 * 512];
        f32x2 wv;
        wv.x = w0; wv.y = w0;
        acc[0] += unpack2(u0.x) * wv; acc[1] += unpack2(u0.y) * wv;
        acc[2] += unpack2(u0.z) * wv; acc[3] += unpack2(u0.w) * wv;
        wv.x = w1; wv.y = w1;
        acc[0] += unpack2(u1.x) * wv; acc[1] += unpack2(u1.y) * wv;
        acc[2] += unpack2(u1.z) * wv; acc[3] += unpack2(u1.w) * wv;
        wv.x = w2; wv.y = w2;
        acc[0] += unpack2(u2.x) * wv; acc[1] += unpack2(u2.y) * wv;
        acc[2] += unpack2(u2.z) * wv; acc[3] += unpack2(u2.w) * wv;
        wv.x = w3; wv.y = w3;
        acc[0] += unpack2(u3.x) * wv; acc[1] += unpack2(u3.y) * wv;
        acc[2] += unpack2(u3.z) * wv; acc[3] += unpack2(u3.w) * wv;
    }
    for (; j < end; ++j) {
        int s0 = csr_src[j];
        float4 q0 = *(const float4*)&e_src[s0 * 4];
        float w0 = __expf(leaky(sel4(q0, b1, b2) + edh) - mh) * rsh;
        uint4 u0 = *(const uint4*)&hp[(size_t)s0 * 512];
        f32x2 wv; wv.x = w0; wv.y = w0;
        acc[0] += unpack2(u0.x) * wv; acc[1] += unpack2(u0.y) * wv;
        acc[2] += unpack2(u0.z) * wv; acc[3] += unpack2(u0.w) * wv;
    }
    int c = lane * 8;
    ushort_t o[8];
#pragma unroll
    for (int i = 0; i < 4; ++i) {
        float r0 = acc[i].x + bias[c + 2 * i];
        float r1 = acc[i].y + bias[c + 2 * i + 1];
        r0 = (r0 > 0.f) ? r0 : (__expf(r0) - 1.f);
        r1 = (r1 > 0.f) ? r1 : (__expf(r1) - 1.f);
        o[2 * i] = f2bf(r0);
        o[2 * i + 1] = f2bf(r1);
    }
    *(uint4*)&outb[(size_t)node * 512 + c] = *(uint4*)o;
}

// layer 2: wave per node, 1 head; same fused structure; fp32 output.
__global__ __launch_bounds__(256) void gather2_kernel(
    const ushort_t* __restrict__ h2b, const float* __restrict__ e_src,
    const float* __restrict__ e_dst, const int* __restrict__ offsets,
    const int* __restrict__ csr_src, const float* __restrict__ bias,
    float* __restrict__ out, int N)
{
    int node = __builtin_amdgcn_readfirstlane(blockIdx.x * 4 + (threadIdx.x >> 6));
    int lane = threadIdx.x & 63;
    if (node >= N) return;
    int beg = offsets[node], end = offsets[node + 1];
    float ed = e_dst[node];

    // phase A
    float m = -1e30f, s = 0.f;
    for (int j = beg + lane; j < end; j += 64) {
        float e = leaky(e_src[csr_src[j]] + ed);
        float nm = fmaxf(m, e);
        s = s * __expf(m - nm) + __expf(e - nm);
        m = nm;
    }
#pragma unroll
    for (int st = 32; st >= 1; st >>= 1) {
        float om = __shfl_xor(m, st);
        float os = __shfl_xor(s, st);
        float nm = fmaxf(m, om);
        s = s * __expf(m - nm) + os * __expf(om - nm);
        m = nm;
    }
    float rs = 1.f / (s + 1e-16f);

    const ushort_t* hp = h2b + lane * 2;
    f32x2 acc = { 0.f, 0.f };
    int j = beg;
#pragma unroll 2
    for (; j + 4 <= end; j += 4) {
        int s0 = csr_src[j], s1 = csr_src[j + 1];
        int s2 = csr_src[j + 2], s3 = csr_src[j + 3];
        float w0 = __expf(leaky(e_src[s0] + ed) - m) * rs;
        float w1 = __expf(leaky(e_src[s1] + ed) - m) * rs;
        float w2 = __expf(leaky(e_src[s2] + ed) - m) * rs;
        float w3 = __expf(leaky(e_src[s3] + ed) - m) * rs;
        unsigned u0 = *(const unsigned*)&hp[(size_t)s0 * 128];
        unsigned u1 = *(const unsigned*)&hp[(size_t)s1 * 128];
        unsigned u2 = *(const unsigned*)&hp[(size_t)s2 * 128];
        unsigned u3 = *(const unsigned*)&hp[(size_t)s3 * 128];
        f32x2 w0v = { w0, w0 }, w1v = { w1, w1 }, w2v = { w2, w2 }, w3v = { w3, w3 };
        acc += unpack2(u0) * w0v;
        acc += unpack2(u1) * w1v;
        acc += unpack2(u2) * w2v;
        acc += unpack2(u3) * w3v;
    }
    for (; j < end; ++j) {
        int s0 = csr_src[j];
        float w0 = __expf(leaky(e_src[s0] + ed) - m) * rs;
        unsigned u0 = *(const unsigned*)&hp[(size_t)s0 * 128];
        f32x2 w0v = { w0, w0 };
        acc += unpack2(u0) * w0v;
    }
    float2 o = make_float2(acc.x + bias[lane * 2], acc.y + bias[lane * 2 + 1]);
    *(float2*)&out[(size_t)node * 128 + lane * 2] = o;
}

// ---------------------------------------------------------------- launch
extern "C" void kernel_launch(void* const* d_in, const int* in_sizes, int n_in,
                              void* d_out, int out_size, void* d_ws, size_t ws_size,
                              hipStream_t stream) {
    const float* x      = (const float*)d_in[0];
    const int*   ei     = (const int*)  d_in[1];
    const float* sent   = (const float*)d_in[2];
    const float* W1     = (const float*)d_in[3];
    const float* a1_src = (const float*)d_in[4];
    const float* a1_dst = (const float*)d_in[5];
    const float* b1     = (const float*)d_in[6];
    const float* W2     = (const float*)d_in[7];
    const float* a2_src = (const float*)d_in[8];
    const float* a2_dst = (const float*)d_in[9];
    const float* b2     = (const float*)d_in[10];
    float* out = (float*)d_out;

    const int N = in_sizes[0] / 768;   // 20000
    const int E = in_sizes[1] / 2;     // 320000

    char* p = (char*)d_ws;
    auto carve = [&](size_t bytes) {
        char* q = p;
        p += (bytes + 255) & ~(size_t)255;
        return q;
    };
    ushort_t* h1b = (ushort_t*)carve((size_t)N * 512 * 2);
    char* shared_region = carve((size_t)N * 768 * 2);   // x_bf16 dead after GEMM1
    ushort_t* x_bf16 = (ushort_t*)shared_region;
    ushort_t* h_elu_b = (ushort_t*)shared_region;
    ushort_t* h2b = (ushort_t*)carve((size_t)N * 128 * 2);
    ushort_t* W1T = (ushort_t*)carve((size_t)512 * 768 * 2);
    ushort_t* W2T = (ushort_t*)carve((size_t)128 * 512 * 2);
    float* svec_part = (float*)carve(8 * 512 * 4);
    float* svec   = (float*)carve(512 * 4);
    float* e_src1 = (float*)carve((size_t)N * 4 * 4);
    float* e_dst1 = (float*)carve((size_t)N * 4 * 4);
    float* e_src2 = (float*)carve((size_t)N * 4);
    float* e_dst2 = (float*)carve((size_t)N * 4);
    int*   indeg  = (int*)carve((size_t)N * 4);
    int*   offs   = (int*)carve((size_t)(N + 1) * 4);
    int*   cursor = (int*)carve((size_t)N * 4);
    int*   csrsrc = (int*)carve((size_t)E * 4);

    size_t nx = (size_t)N * 768;
    int nbCast = (int)((nx / 8 + 255) / 256);
    int nbZero = (N + 255) / 256;
    int nbPrep = nbCast + 384 + 64 + 16 + nbZero;

    // fused prep: cast x, transpose W1/W2, svec partials, zero indeg
    prep_kernel<<<nbPrep, 256, 0, stream>>>(x, x_bf16, nx, W1, W1T, W2, W2T,
                                            sent, svec_part, indeg, N, nbCast, nbZero);
    // CSR build (+ svec reduce inside scan)
    count_kernel<<<(E + 255) / 256, 256, 0, stream>>>(ei, indeg, E);
    scan_kernel<<<1, 1024, 0, stream>>>(indeg, offs, cursor, svec_part, svec, N);
    scatter_kernel<<<(E + 255) / 256, 256, 0, stream>>>(ei, cursor, csrsrc, E);

    // GEMM1: h1b = bf16(x @ W1[:768] + svec), fused e1  [N,512]
    mfma_gemm_kernel<<<dim3(4, (N + 127) / 128), 256, 0, stream>>>(
        x_bf16, W1T, svec, h1b, a1_src, a1_dst, e_src1, e_dst1, 4, N, 768, 512);

    // layer-1 attention (softmax fused into gather)
    gather1_kernel<<<(N + 3) / 4, 256, 0, stream>>>(
        h1b, e_src1, e_dst1, offs, csrsrc, b1, h_elu_b, N);

    // GEMM2: h2b = bf16(h_elu @ W2), fused e2  [N,128]
    mfma_gemm_kernel<<<dim3(1, (N + 127) / 128), 256, 0, stream>>>(
        h_elu_b, W2T, nullptr, h2b, a2_src, a2_dst, e_src2, e_dst2, 1, N, 512, 128);

    // layer-2 attention (fused)
    gather2_kernel<<<(N + 3) / 4, 256, 0, stream>>>(
        h2b, e_src2, e_dst2, offs, csrsrc, b2, out, N);
}